// Round 1
// 1203.676 us; speedup vs baseline: 1.3150x; 1.3150x over previous
//
#include <hip/hip_runtime.h>
#include <hip/hip_bf16.h>

using bf16 = __hip_bfloat16;

constexpr int Bd  = 8;
constexpr int Ld  = 4096;
constexpr int Dd  = 512;
constexpr int Hd  = 8;
constexpr int DHd = 64;
constexpr int DFFd= 2048;
constexpr int Ud  = 128;           // TOP_U
constexpr int MLd = Bd * Ld;       // 32768 rows
constexpr int KSd = 16;            // attention K-split (256 keys per block)

typedef short          bf16x8 __attribute__((ext_vector_type(8)));
typedef unsigned short u16x8  __attribute__((ext_vector_type(8)));
typedef float          f32x4  __attribute__((ext_vector_type(4)));

__device__ __forceinline__ float bf2float(bf16 v) { return __bfloat162float(v); }

__device__ __forceinline__ float wred_sum(float v) {
    #pragma unroll
    for (int o = 32; o > 0; o >>= 1) v += __shfl_xor(v, o);
    return v;
}
__device__ __forceinline__ float wred_max(float v) {
    #pragma unroll
    for (int o = 32; o > 0; o >>= 1) v = fmaxf(v, __shfl_xor(v, o));
    return v;
}
__device__ __forceinline__ float scrub(float v) {       // NaN/Inf -> 0
    return (fabsf(v) < 1e20f) ? v : 0.0f;
}
__device__ __forceinline__ short f2bs(float f) {        // float -> bf16 bits
    bf16 h = __float2bfloat16(f);
    return *reinterpret_cast<short*>(&h);
}

// async global->LDS, 16B per lane; LDS dest = wave-uniform base + lane*16
__device__ __forceinline__ void gload_lds16(const bf16* g, bf16* lds_base) {
    __builtin_amdgcn_global_load_lds((const __attribute__((address_space(1))) void*)g,
                                     (__attribute__((address_space(3))) void*)lds_base,
                                     16, 0, 0);
}

// ---------------------------------------------------------------- dtype detector
__global__ void detect_kernel(const void* xraw, int* flags) {
    const unsigned short* u = (const unsigned short*)xraw;
    __shared__ int cnt;
    if (threadIdx.x == 0) cnt = 0;
    __syncthreads();
    int local = 0;
    for (int i = threadIdx.x; i < 1024; i += 256) {
        int e = (u[2 * i] >> 7) & 0xFF;
        if (e >= 96 && e <= 142) local++;
    }
    atomicAdd(&cnt, local);
    __syncthreads();
    if (threadIdx.x == 0) flags[0] = (cnt < 512) ? 1 : 0;
}

// canonicalize any float tensor to bf16
__global__ void conv_kernel(const void* raw, bf16* dst, int n, const int* flags) {
    int i = blockIdx.x * 256 + threadIdx.x;
    if (i >= n) return;
    if (flags[0]) dst[i] = __float2bfloat16(((const float*)raw)[i]);
    else          dst[i] = ((const bf16*)raw)[i];
}

// canonicalize + transpose weight: in W[K][N] -> out WT[N][K] (bf16)
__global__ void convT_kernel(const void* raw, bf16* dst, int K, int N, const int* flags) {
    __shared__ bf16 tile[32][33];
    const int k0 = blockIdx.y * 32, n0 = blockIdx.x * 32;
    const int tx = threadIdx.x & 31, ty = threadIdx.x >> 5;     // 32 x 8
    #pragma unroll
    for (int p = 0; p < 4; ++p) {
        int k = k0 + ty + p * 8, n = n0 + tx;
        float v = flags[0] ? ((const float*)raw)[(size_t)k * N + n]
                           : bf2float(((const bf16*)raw)[(size_t)k * N + n]);
        tile[ty + p * 8][tx] = __float2bfloat16(v);
    }
    __syncthreads();
    #pragma unroll
    for (int p = 0; p < 4; ++p) {
        int n = n0 + ty + p * 8, k = k0 + tx;
        dst[(size_t)n * K + k] = tile[tx][ty + p * 8];
    }
}

__global__ void zero_kernel(int* p, int n) {
    int i = blockIdx.x * 256 + threadIdx.x;
    if (i < n) p[i] = 0;
}

// sample_idx: int32 or int64 device layout; clamped to [0, Ld)
__global__ void idx_kernel(const void* raw, int* out) {
    const int* r32 = (const int*)raw;
    __shared__ int is64;
    int t = threadIdx.x;                       // 128 threads
    if (t == 0) is64 = 1;
    __syncthreads();
    if (t < 64 && r32[2 * t + 1] != 0) is64 = 0;
    __syncthreads();
    int v = is64 ? r32[2 * t] : r32[t];
    out[t] = min(max(v, 0), Ld - 1);
}

// ---------------------------------------------------------------- MFMA GEMM (m97 recipe)
// C[m,n] = sum_k X[m,k]*WT[n,k] + bias[n]; 128x128 tile, BK=32, 4 waves.
template<bool RELU>
__launch_bounds__(256)
__global__ void mfma_gemm(const bf16* __restrict__ X, const bf16* __restrict__ WT,
                          const bf16* __restrict__ bias, bf16* __restrict__ C,
                          int M, int N, int K)
{
    __shared__ bf16 As[128 * 32];
    __shared__ bf16 Bs[128 * 32];
    const int t = threadIdx.x;
    const int lane = t & 63, wave = t >> 6;
    const int wr = wave >> 1, wc = wave & 1;    // 2x2 wave grid
    const int quad = lane >> 4, l15 = lane & 15;
    const int m0 = blockIdx.y * 128, n0 = blockIdx.x * 128;
    const int lrow = lane >> 2, lcol = (lane & 3) * 8;   // 16 rows x 4x8 cols per wave-load

    f32x4 acc[4][4] = {};

    for (int k0 = 0; k0 < K; k0 += 32) {
        #pragma unroll
        for (int p = 0; p < 2; ++p) {
            int r0 = wave * 16 + p * 64;
            gload_lds16(&X [(size_t)(m0 + r0 + lrow) * K + k0 + lcol], &As[r0 * 32]);
            gload_lds16(&WT[(size_t)(n0 + r0 + lrow) * K + k0 + lcol], &Bs[r0 * 32]);
        }
        __syncthreads();
        bf16x8 a[4], b[4];
        #pragma unroll
        for (int i = 0; i < 4; ++i) {
            a[i] = *(const bf16x8*)&As[(wr * 64 + i * 16 + l15) * 32 + quad * 8];
            b[i] = *(const bf16x8*)&Bs[(wc * 64 + i * 16 + l15) * 32 + quad * 8];
        }
        #pragma unroll
        for (int i = 0; i < 4; ++i)
            #pragma unroll
            for (int j = 0; j < 4; ++j)
                acc[i][j] = __builtin_amdgcn_mfma_f32_16x16x32_bf16(a[i], b[j], acc[i][j], 0, 0, 0);
        __syncthreads();
    }
    // epilogue: D elem (m = quad*4+reg, n = lane&15) within each 16x16 tile
    #pragma unroll
    for (int j = 0; j < 4; ++j) {
        int n = n0 + wc * 64 + j * 16 + l15;
        float bi = bf2float(bias[n]);
        #pragma unroll
        for (int i = 0; i < 4; ++i) {
            #pragma unroll
            for (int r = 0; r < 4; ++r) {
                int m = m0 + wr * 64 + i * 16 + quad * 4 + r;
                float v = acc[i][j][r] + bi;
                if (RELU) v = fmaxf(v, 0.0f);
                C[(size_t)m * N + n] = __float2bfloat16(v);
            }
        }
    }
}

// ---------------------------------------------------------------- M = max-mean of sampled scores
__launch_bounds__(256)
__global__ void m_kernel(const bf16* __restrict__ Q, const bf16* __restrict__ Kg,
                         const int* __restrict__ sidx, float* __restrict__ Mv)
{
    __shared__ float Qs[64][68];
    __shared__ float Ks[64][132];
    __shared__ float redM[64][16];
    __shared__ float redS[64][16];
    const int t  = threadIdx.x;
    const int bh = blockIdx.y, b = bh >> 3, h = bh & 7;
    const int l0 = blockIdx.x * 64;

    int dl = t & 63, r4 = t >> 6;
    #pragma unroll
    for (int p = 0; p < 16; ++p) {
        int lr = r4 + p * 4;
        Qs[dl][lr] = bf2float(Q[((size_t)(b * Ld + l0 + lr)) * Dd + h * 64 + dl]);
    }
    #pragma unroll
    for (int p = 0; p < 32; ++p) {
        int j = r4 + p * 4;
        Ks[dl][j] = bf2float(Kg[((size_t)(b * Ld + sidx[j])) * Dd + h * 64 + dl]);
    }
    __syncthreads();

    const int tx = t & 15, ty = t >> 4;
    float acc[4][8] = {};
    for (int d = 0; d < 64; ++d) {
        float4 a4  = *(const float4*)&Qs[d][ty * 4];
        float4 b4a = *(const float4*)&Ks[d][tx * 8];
        float4 b4b = *(const float4*)&Ks[d][tx * 8 + 4];
        float av[4] = {a4.x, a4.y, a4.z, a4.w};
        float bv[8] = {b4a.x, b4a.y, b4a.z, b4a.w, b4b.x, b4b.y, b4b.z, b4b.w};
        #pragma unroll
        for (int i = 0; i < 4; ++i)
            #pragma unroll
            for (int j = 0; j < 8; ++j)
                acc[i][j] = fmaf(av[i], bv[j], acc[i][j]);
    }
    #pragma unroll
    for (int i = 0; i < 4; ++i) {
        float rmax = -1e30f, rsum = 0.0f;
        #pragma unroll
        for (int j = 0; j < 8; ++j) { rmax = fmaxf(rmax, acc[i][j]); rsum += acc[i][j]; }
        redM[ty * 4 + i][tx] = rmax;
        redS[ty * 4 + i][tx] = rsum;
    }
    __syncthreads();
    if (t < 64) {
        float m = -1e30f, s = 0.0f;
        #pragma unroll
        for (int q = 0; q < 16; ++q) { m = fmaxf(m, redM[t][q]); s += redS[t][q]; }
        Mv[(size_t)bh * Ld + l0 + t] = m - s * (1.0f / 128.0f);
    }
}

// ---------------------------------------------------------------- top-128 via bitonic sort (desc)
__launch_bounds__(256)
__global__ void topk_kernel(const float* __restrict__ Mv, int* __restrict__ topIdx)
{
    __shared__ float val[4096];
    __shared__ int   idx[4096];
    const int bh = blockIdx.x, t = threadIdx.x;
    for (int i = t; i < 4096; i += 256) { val[i] = Mv[(size_t)bh * Ld + i]; idx[i] = i; }
    __syncthreads();
    for (int k = 2; k <= 4096; k <<= 1) {
        for (int j = k >> 1; j > 0; j >>= 1) {
            for (int i = t; i < 4096; i += 256) {
                int ixj = i ^ j;
                if (ixj > i) {
                    bool up = ((i & k) == 0);
                    float vi = val[i], vj = val[ixj];
                    bool sw = up ? (vi < vj) : (vi > vj);
                    if (sw) {
                        val[i] = vj; val[ixj] = vi;
                        int tmp = idx[i]; idx[i] = idx[ixj]; idx[ixj] = tmp;
                    }
                }
            }
            __syncthreads();
        }
    }
    if (t < Ud) topIdx[bh * Ud + t] = idx[t];
}

// ---------------------------------------------------------------- per-row sparse-entry list
__global__ void rows_kernel(const int* __restrict__ topIdx, int* __restrict__ rowCnt,
                            int* __restrict__ rowEnt)
{
    const int bh = blockIdx.x, u = threadIdx.x, b = bh >> 3;
    const int lq = topIdx[bh * Ud + u];
    const int row = b * Ld + lq;
    int slot = atomicAdd(&rowCnt[row], 1) & 7;
    rowEnt[row * 8 + slot] = bh * Ud + u;
}

// ---------------------------------------------------------------- meanV over L per (b,h,d)
__launch_bounds__(256)
__global__ void meanv_kernel(const bf16* __restrict__ V, float* __restrict__ meanV)
{
    const int bh = blockIdx.x, b = bh >> 3, h = bh & 7, t = threadIdx.x;
    const int d = t & 63, part = t >> 6;
    float s = 0.0f;
    for (int l = part; l < Ld; l += 4)
        s += bf2float(V[((size_t)(b * Ld + l)) * Dd + h * 64 + d]);
    __shared__ float red[256];
    red[t] = s;
    __syncthreads();
    if (t < 64) {
        float tot = red[t] + red[64 + t] + red[128 + t] + red[192 + t];
        meanV[bh * 64 + t] = tot * (1.0f / 4096.0f);
    }
}

// ---------------------------------------------------------------- MFMA flash attention (K-split partials)
// Grid (bh, ks): each block = all 128 top-U queries x 256 keys (4 kv-tiles of 64).
// QK^T: A = Q frags (regs), B = K rows from LDS (natural [key][d] == B layout).
// K LDS is XOR-swizzled (16B-chunk ^ row&7) with pre-swizzled global_load_lds src.
// Softmax on D-layout acc (row=quad*4+r, col=l15): 4-step shfl over quad group.
// PV: P round-trips per-wave LDS [32][72] (144B rows, conflict-free b128);
// V reg-staged transposed into [d][key] stride-72 so B reads are contiguous.
__launch_bounds__(256, 3)
__global__ void attn_kernel(const bf16* __restrict__ Qg, const bf16* __restrict__ Kg,
                            const bf16* __restrict__ Vg, const int* __restrict__ topIdx,
                            bf16* __restrict__ pO, float* __restrict__ pM, float* __restrict__ pL)
{
    __shared__ __align__(16) short KsS[2][64 * 64];   // [key][d], swizzled, 16 KiB
    __shared__ __align__(16) short VsS[2][64 * 72];   // [d][key], padded, 18 KiB
    __shared__ __align__(16) short PsS[4][32 * 72];   // per-wave [q][key], 18 KiB

    const int t = threadIdx.x, lane = t & 63, w = t >> 6;
    const int l15 = lane & 15, quad = lane >> 4;
    const int bh = blockIdx.x, ks = blockIdx.y;
    const int b = bh >> 3, h = bh & 7;
    const int key0 = ks * (Ld / KSd);
    constexpr int NT = (Ld / KSd) / 64;               // 4 kv-tiles

    // Q fragments (A operand): row = l15 (+16m), k = quad*8 within 32-wide kk step
    bf16x8 qf[2][2];
    #pragma unroll
    for (int m = 0; m < 2; ++m) {
        const int u  = w * 32 + m * 16 + l15;
        const int lq = topIdx[bh * Ud + u];
        const bf16* qr = Qg + ((size_t)(b * Ld + lq)) * Dd + h * 64;
        qf[m][0] = *(const bf16x8*)(qr + quad * 8);
        qf[m][1] = *(const bf16x8*)(qr + 32 + quad * 8);
    }

    const int vkey = t >> 2, vd0 = (t & 3) * 16;
    u16x8 vr0, vr1;

    auto loadV = [&](int tt) {   // V tile -> regs (issued early, coalesced 16B)
        const bf16* vs = Vg + ((size_t)(b * Ld + key0 + tt * 64 + vkey)) * Dd + h * 64 + vd0;
        vr0 = *(const u16x8*)vs;
        vr1 = *(const u16x8*)(vs + 8);
    };
    auto stageK = [&](int buf, int tt) {  // K tile -> LDS via gload_lds, src pre-swizzled
        const int kb0 = key0 + tt * 64;
        #pragma unroll
        for (int sz = 0; sz < 2; ++sz) {
            const int sg = w * 2 + sz;                  // 8-row segment
            const int r  = sg * 8 + (lane >> 3);
            const int cs = (lane & 7) ^ (lane >> 3);    // inverse swizzle on source
            gload_lds16(Kg + ((size_t)(b * Ld + kb0 + r)) * Dd + h * 64 + cs * 8,
                        (bf16*)&KsS[buf][sg * 512]);
        }
    };
    auto writeV = [&](int buf) {  // regs -> transposed LDS
        #pragma unroll
        for (int j = 0; j < 8; ++j) {
            VsS[buf][(vd0 + j) * 72 + vkey]     = (short)vr0[j];
            VsS[buf][(vd0 + 8 + j) * 72 + vkey] = (short)vr1[j];
        }
    };

    float mrun[2][4], lrun[2][4];
    f32x4 o[2][4] = {};
    #pragma unroll
    for (int m = 0; m < 2; ++m)
        #pragma unroll
        for (int r = 0; r < 4; ++r) { mrun[m][r] = -1e30f; lrun[m][r] = 0.0f; }

    loadV(0); stageK(0, 0); writeV(0);
    __syncthreads();

    short* PsW = &PsS[w][0];
    for (int tt = 0; tt < NT; ++tt) {
        const int cur = tt & 1;
        if (tt + 1 < NT) { loadV(tt + 1); stageK(cur ^ 1, tt + 1); }

        // ---- QK^T -> S (f32), 16 MFMA
        const short* KsB = &KsS[cur][0];
        f32x4 s[2][4] = {};
        #pragma unroll
        for (int kk = 0; kk < 2; ++kk) {
            bf16x8 kb[4];
            #pragma unroll
            for (int n = 0; n < 4; ++n)
                kb[n] = *(const bf16x8*)&KsB[(n * 16 + l15) * 64 +
                                             (((kk * 4 + quad) ^ (l15 & 7)) * 8)];
            #pragma unroll
            for (int m = 0; m < 2; ++m)
                #pragma unroll
                for (int n = 0; n < 4; ++n)
                    s[m][n] = __builtin_amdgcn_mfma_f32_16x16x32_bf16(qf[m][kk], kb[n], s[m][n], 0, 0, 0);
        }

        // ---- online softmax; rows = quad*4+r (+16m), cols = l15 (+16n)
        #pragma unroll
        for (int m = 0; m < 2; ++m) {
            #pragma unroll
            for (int r = 0; r < 4; ++r) {
                float sv[4];
                #pragma unroll
                for (int n = 0; n < 4; ++n) sv[n] = s[m][n][r] * 0.125f;
                float vm = fmaxf(fmaxf(sv[0], sv[1]), fmaxf(sv[2], sv[3]));
                #pragma unroll
                for (int off = 1; off < 16; off <<= 1) vm = fmaxf(vm, __shfl_xor(vm, off));
                const float mn = fmaxf(mrun[m][r], vm);
                const float al = __expf(mrun[m][r] - mn);
                float ps = 0.0f;
                #pragma unroll
                for (int n = 0; n < 4; ++n) { sv[n] = __expf(sv[n] - mn); ps += sv[n]; }
                #pragma unroll
                for (int off = 1; off < 16; off <<= 1) ps += __shfl_xor(ps, off);
                lrun[m][r] = lrun[m][r] * al + ps;
                mrun[m][r] = mn;
                const int qrow = m * 16 + quad * 4 + r;
                #pragma unroll
                for (int n = 0; n < 4; ++n) {
                    PsW[qrow * 72 + n * 16 + l15] = f2bs(sv[n]);
                    o[m][n][r] *= al;
                }
            }
        }

        if (tt + 1 < NT) writeV(cur ^ 1);   // into other buffer; hides under PV

        // ---- PV: O += P * V, 16 MFMA
        const short* VsB = &VsS[cur][0];
        #pragma unroll
        for (int kk = 0; kk < 2; ++kk) {
            bf16x8 pa[2], vb[4];
            #pragma unroll
            for (int m = 0; m < 2; ++m)
                pa[m] = *(const bf16x8*)&PsW[(m * 16 + l15) * 72 + kk * 32 + quad * 8];
            #pragma unroll
            for (int n = 0; n < 4; ++n)
                vb[n] = *(const bf16x8*)&VsB[(n * 16 + l15) * 72 + kk * 32 + quad * 8];
            #pragma unroll
            for (int m = 0; m < 2; ++m)
                #pragma unroll
                for (int n = 0; n < 4; ++n)
                    o[m][n] = __builtin_amdgcn_mfma_f32_16x16x32_bf16(pa[m], vb[n], o[m][n], 0, 0, 0);
        }
        __syncthreads();
    }

    const size_t pbase = ((size_t)(ks * 64 + bh)) * Ud;
    #pragma unroll
    for (int m = 0; m < 2; ++m) {
        #pragma unroll
        for (int r = 0; r < 4; ++r) {
            const int u = w * 32 + m * 16 + quad * 4 + r;
            #pragma unroll
            for (int n = 0; n < 4; ++n)
                pO[(pbase + u) * 64 + n * 16 + l15] = __float2bfloat16(o[m][n][r]);
            if (l15 == 0) { pM[pbase + u] = mrun[m][r]; pL[pbase + u] = lrun[m][r]; }
        }
    }
}

// combine K-split partials -> ctxTop
__global__ void combine_kernel(const bf16* __restrict__ pO, const float* __restrict__ pM,
                               const float* __restrict__ pL, float* __restrict__ ctxTop)
{
    const int u = blockIdx.x & 127, bh = blockIdx.x >> 7, c = threadIdx.x;
    float mstar = -1e30f;
    #pragma unroll
    for (int ks = 0; ks < KSd; ++ks)
        mstar = fmaxf(mstar, pM[(ks * 64 + bh) * Ud + u]);
    float lsum = 0.0f, osum = 0.0f;
    #pragma unroll
    for (int ks = 0; ks < KSd; ++ks) {
        float wgt = __expf(pM[(ks * 64 + bh) * Ud + u] - mstar);
        lsum += pL[(ks * 64 + bh) * Ud + u] * wgt;
        osum += bf2float(pO[(((size_t)ks * 64 + bh) * Ud + u) * 64 + c]) * wgt;
    }
    ctxTop[((size_t)bh * Ud + u) * 64 + c] = scrub(osum / lsum);
}

// ---------------------------------------------------------------- base row: concat(meanV) @ Wo + bo
__launch_bounds__(512)
__global__ void baseout_kernel(const float* __restrict__ meanV, const bf16* __restrict__ Wo,
                               const bf16* __restrict__ bo, float* __restrict__ baseOut)
{
    const int b = blockIdx.x, t = threadIdx.x;
    __shared__ float mv[512];
    mv[t] = meanV[b * 512 + t];
    __syncthreads();
    float acc = bf2float(bo[t]);
    for (int d = 0; d < 512; ++d)
        acc = fmaf(mv[d], bf2float(Wo[(size_t)d * 512 + t]), acc);
    baseOut[b * 512 + t] = acc;
}

// ---------------------------------------------------------------- per-(bh,u) delta rows (bf16 out)
__launch_bounds__(256)
__global__ void delta_kernel(const float* __restrict__ ctxTop, const float* __restrict__ meanV,
                             const bf16* __restrict__ Wo, bf16* __restrict__ deltaOut)
{
    const int u = blockIdx.x, bh = blockIdx.y, h = bh & 7, t = threadIdx.x;
    __shared__ float diff[64];
    if (t < 64) diff[t] = ctxTop[((size_t)bh * Ud + u) * 64 + t] - meanV[bh * 64 + t];
    __syncthreads();
    for (int n = t; n < 512; n += 256) {
        float acc = 0.0f;
        #pragma unroll 8
        for (int dd = 0; dd < 64; ++dd)
            acc = fmaf(diff[dd], bf2float(Wo[(size_t)(h * 64 + dd) * 512 + n]), acc);
        deltaOut[((size_t)bh * Ud + u) * 512 + n] = __float2bfloat16(acc);
    }
}

// ---------------------------------------------------------------- LayerNorms
__launch_bounds__(256)
__global__ void ln1_kernel(const bf16* __restrict__ x, const float* __restrict__ baseOut,
                           const int* __restrict__ rowCnt, const int* __restrict__ rowEnt,
                           const bf16* __restrict__ deltaOut,
                           const bf16* __restrict__ g, const bf16* __restrict__ bb,
                           bf16* __restrict__ x1)
{
    const int row = blockIdx.x, t = threadIdx.x;
    const int b = row >> 12;
    const size_t base = (size_t)row * 512;
    float v0 = bf2float(x[base + t])       + baseOut[b * 512 + t];
    float v1 = bf2float(x[base + t + 256]) + baseOut[b * 512 + t + 256];
    const int cnt = min(rowCnt[row], 8);
    for (int e = 0; e < cnt; ++e) {
        const bf16* dr = &deltaOut[(size_t)rowEnt[row * 8 + e] * 512];
        v0 += bf2float(dr[t]);
        v1 += bf2float(dr[t + 256]);
    }
    v0 = scrub(v0); v1 = scrub(v1);
    float s = v0 + v1, q = v0 * v0 + v1 * v1;
    s = wred_sum(s); q = wred_sum(q);
    __shared__ float sred[4], qred[4];
    int lane = t & 63, w = t >> 6;
    if (lane == 0) { sred[w] = s; qred[w] = q; }
    __syncthreads();
    float tot  = sred[0] + sred[1] + sred[2] + sred[3];
    float totq = qred[0] + qred[1] + qred[2] + qred[3];
    float mean = tot * (1.0f / 512.0f);
    float var  = fmaxf(totq * (1.0f / 512.0f) - mean * mean, 0.0f);
    float rstd = rsqrtf(var + 1e-6f);
    x1[base + t]       = __float2bfloat16((v0 - mean) * rstd * bf2float(g[t])       + bf2float(bb[t]));
    x1[base + t + 256] = __float2bfloat16((v1 - mean) * rstd * bf2float(g[t + 256]) + bf2float(bb[t + 256]));
}

__launch_bounds__(256)
__global__ void ln2_kernel(const bf16* __restrict__ x1, const bf16* __restrict__ ffn,
                           const bf16* __restrict__ g, const bf16* __restrict__ bb,
                           void* __restrict__ out, const int* __restrict__ flags)
{
    const int row = blockIdx.x, t = threadIdx.x;
    const size_t base = (size_t)row * 512;
    float v0 = bf2float(x1[base + t])       + bf2float(ffn[base + t]);
    float v1 = bf2float(x1[base + t + 256]) + bf2float(ffn[base + t + 256]);
    v0 = scrub(v0); v1 = scrub(v1);
    float s = v0 + v1, q = v0 * v0 + v1 * v1;
    s = wred_sum(s); q = wred_sum(q);
    __shared__ float sred[4], qred[4];
    int lane = t & 63, w = t >> 6;
    if (lane == 0) { sred[w] = s; qred[w] = q; }
    __syncthreads();
    float tot  = sred[0] + sred[1] + sred[2] + sred[3];
    float totq = qred[0] + qred[1] + qred[2] + qred[3];
    float mean = tot * (1.0f / 512.0f);
    float var  = fmaxf(totq * (1.0f / 512.0f) - mean * mean, 0.0f);
    float rstd = rsqrtf(var + 1e-6f);
    float o0 = (v0 - mean) * rstd * bf2float(g[t])       + bf2float(bb[t]);
    float o1 = (v1 - mean) * rstd * bf2float(g[t + 256]) + bf2float(bb[t + 256]);
    if (flags[0]) {
        ((float*)out)[base + t]       = o0;
        ((float*)out)[base + t + 256] = o1;
    } else {
        ((bf16*)out)[base + t]       = __float2bfloat16(o0);
        ((bf16*)out)[base + t + 256] = __float2bfloat16(o1);
    }
}

// ================================================================ launcher
extern "C" void kernel_launch(void* const* d_in, const int* in_sizes, int n_in,
                              void* d_out, int out_size, void* d_ws, size_t ws_size,
                              hipStream_t stream)
{
    const void* sraw = d_in[17];

    const size_t NQ = (size_t)MLd * Dd;          // 16,777,216 elements
    char* w = (char*)d_ws;
    size_t off = 0;
    auto alloc = [&](size_t bytes) { void* p = w + off; off += (bytes + 63) & ~size_t(63); return p; };
    bf16*  Qb   = (bf16*)alloc(NQ * 2);                       // 32 MiB
    bf16*  Kb   = (bf16*)alloc(NQ * 2);                       // 32 MiB (contiguous after Qb)
    bf16*  Vb   = (bf16*)alloc(NQ * 2);                       // 32 MiB
    bf16*  xc   = (bf16*)alloc(NQ * 2);                       // 32 MiB
    bf16*  WTq  = (bf16*)alloc(Dd * Dd * 2);
    bf16*  WTk  = (bf16*)alloc(Dd * Dd * 2);
    bf16*  WTv  = (bf16*)alloc(Dd * Dd * 2);
    bf16*  Woc  = (bf16*)alloc(Dd * Dd * 2);                  // untransposed
    bf16*  WT1f = (bf16*)alloc((size_t)Dd * DFFd * 2);        // [2048][512]
    bf16*  WT2f = (bf16*)alloc((size_t)DFFd * Dd * 2);        // [512][2048]
    bf16* bqc = (bf16*)alloc(Dd * 2);
    bf16* bkc = (bf16*)alloc(Dd * 2);
    bf16* bvc = (bf16*)alloc(Dd * 2);
    bf16* boc = (bf16*)alloc(Dd * 2);
    bf16* g1c = (bf16*)alloc(Dd * 2);
    bf16* b1c = (bf16*)alloc(Dd * 2);
    bf16* b1fc= (bf16*)alloc(DFFd * 2);
    bf16* b2fc= (bf16*)alloc(Dd * 2);
    bf16* g2c = (bf16*)alloc(Dd * 2);
    bf16* b2c = (bf16*)alloc(Dd * 2);
    bf16*  pOb     = (bf16*)alloc((size_t)KSd * 64 * Ud * 64 * 2);   // 16 MiB
    float* Mv      = (float*)alloc((size_t)Bd * Hd * Ld * 4);        // 1 MiB
    float* ctxTop  = (float*)alloc((size_t)Bd * Hd * Ud * DHd * 4);  // 2 MiB
    float* meanV   = (float*)alloc(Bd * Hd * DHd * 4);
    float* baseOut = (float*)alloc(Bd * Dd * 4);
    int*   topIdx  = (int*)alloc(Bd * Hd * Ud * 4);
    int*   sidx    = (int*)alloc(128 * 4);
    int*   rowCnt  = (int*)alloc(MLd * 4);
    int*   rowEnt  = (int*)alloc(MLd * 8 * 4);
    int*   flags   = (int*)alloc(64);
    // aliases (lifetimes disjoint, stream-serialized):
    bf16*  x1b  = Vb;                 // ln1 output (V dead)
    bf16*  h1b  = Qb;                 // FFN hidden chunk 16384x2048 spans Qb+Kb (both dead)
    bf16*  ffnb = xc;                 // FFN out (xc dead after ln1)
    bf16*  deltaOut = pOb;            // after combine_kernel, pO dead
    float* pM = Mv;                   // Mv dead after topk
    float* pL = Mv + KSd * 64 * Ud;

    if (off > ws_size) return;

    detect_kernel<<<1, 256, 0, stream>>>(d_in[0], flags);

    auto conv = [&](int i, bf16* dst, int n) {
        conv_kernel<<<(n + 255) / 256, 256, 0, stream>>>(d_in[i], dst, n, flags);
    };
    conv(0,  xc, (int)NQ);
    convT_kernel<<<dim3(Dd / 32, Dd / 32), 256, 0, stream>>>(d_in[1], WTq, Dd, Dd, flags);
    convT_kernel<<<dim3(Dd / 32, Dd / 32), 256, 0, stream>>>(d_in[3], WTk, Dd, Dd, flags);
    convT_kernel<<<dim3(Dd / 32, Dd / 32), 256, 0, stream>>>(d_in[5], WTv, Dd, Dd, flags);
    convT_kernel<<<dim3(DFFd / 32, Dd / 32), 256, 0, stream>>>(d_in[11], WT1f, Dd, DFFd, flags);
    convT_kernel<<<dim3(Dd / 32, DFFd / 32), 256, 0, stream>>>(d_in[13], WT2f, DFFd, Dd, flags);
    conv(7,  Woc, Dd * Dd);
    conv(2,  bqc, Dd);  conv(4,  bkc, Dd);  conv(6,  bvc, Dd);  conv(8,  boc, Dd);
    conv(9,  g1c, Dd);  conv(10, b1c, Dd);
    conv(12, b1fc, DFFd); conv(14, b2fc, Dd);
    conv(15, g2c, Dd);  conv(16, b2c, Dd);

    zero_kernel<<<(MLd + 255) / 256, 256, 0, stream>>>(rowCnt, MLd);
    idx_kernel<<<1, 128, 0, stream>>>(sraw, sidx);

    // QKV projections (MFMA, async-staged)
    mfma_gemm<false><<<dim3(4, 256), 256, 0, stream>>>(xc, WTq, bqc, Qb, MLd, Dd, Dd);
    mfma_gemm<false><<<dim3(4, 256), 256, 0, stream>>>(xc, WTk, bkc, Kb, MLd, Dd, Dd);
    mfma_gemm<false><<<dim3(4, 256), 256, 0, stream>>>(xc, WTv, bvc, Vb, MLd, Dd, Dd);

    m_kernel<<<dim3(Ld / 64, Bd * Hd), 256, 0, stream>>>(Qb, Kb, sidx, Mv);
    topk_kernel<<<Bd * Hd, 256, 0, stream>>>(Mv, topIdx);
    rows_kernel<<<Bd * Hd, 128, 0, stream>>>(topIdx, rowCnt, rowEnt);
    meanv_kernel<<<Bd * Hd, 256, 0, stream>>>(Vb, meanV);

    attn_kernel<<<dim3(Bd * Hd, KSd), 256, 0, stream>>>(Qb, Kb, Vb, topIdx, pOb, pM, pL);
    combine_kernel<<<Bd * Hd * Ud, 64, 0, stream>>>(pOb, pM, pL, ctxTop);

    baseout_kernel<<<Bd, 512, 0, stream>>>(meanV, Woc, boc, baseOut);
    delta_kernel<<<dim3(Ud, Bd * Hd), 256, 0, stream>>>(ctxTop, meanV, Woc, deltaOut);

    ln1_kernel<<<MLd, 256, 0, stream>>>(xc, baseOut, rowCnt, rowEnt, deltaOut, g1c, b1c, x1b);

    // FFN, chunked over rows (2 chunks of 16384: h1 = 64 MiB spanning Qb+Kb)
    for (int c = 0; c < 2; ++c) {
        mfma_gemm<true ><<<dim3(16, 128), 256, 0, stream>>>(
            x1b + (size_t)c * 16384 * 512, WT1f, b1fc, h1b, 16384, DFFd, Dd);
        mfma_gemm<false><<<dim3(4, 128), 256, 0, stream>>>(
            h1b, WT2f, b2fc, ffnb + (size_t)c * 16384 * 512, 16384, Dd, DFFd);
    }

    ln2_kernel<<<MLd, 256, 0, stream>>>(x1b, ffnb, g2c, b2c, d_out, flags);
}

// Round 2
// 945.670 us; speedup vs baseline: 1.6737x; 1.2728x over previous
//
#include <hip/hip_runtime.h>
#include <hip/hip_bf16.h>

using bf16 = __hip_bfloat16;

constexpr int Bd  = 8;
constexpr int Ld  = 4096;
constexpr int Dd  = 512;
constexpr int Hd  = 8;
constexpr int DHd = 64;
constexpr int DFFd= 2048;
constexpr int Ud  = 128;           // TOP_U
constexpr int MLd = Bd * Ld;       // 32768 rows
constexpr int KSd = 16;            // attention K-split (256 keys per block)

typedef short          bf16x8 __attribute__((ext_vector_type(8)));
typedef unsigned short u16x8  __attribute__((ext_vector_type(8)));
typedef float          f32x4  __attribute__((ext_vector_type(4)));

__device__ __forceinline__ float bf2float(bf16 v) { return __bfloat162float(v); }

__device__ __forceinline__ float wred_sum(float v) {
    #pragma unroll
    for (int o = 32; o > 0; o >>= 1) v += __shfl_xor(v, o);
    return v;
}
__device__ __forceinline__ float wred_max(float v) {
    #pragma unroll
    for (int o = 32; o > 0; o >>= 1) v = fmaxf(v, __shfl_xor(v, o));
    return v;
}
__device__ __forceinline__ float scrub(float v) {       // NaN/Inf -> 0
    return (fabsf(v) < 1e20f) ? v : 0.0f;
}
__device__ __forceinline__ short f2bs(float f) {        // float -> bf16 bits
    bf16 h = __float2bfloat16(f);
    return *reinterpret_cast<short*>(&h);
}

// async global->LDS, 16B per lane; LDS dest = wave-uniform base + lane*16
__device__ __forceinline__ void gload_lds16(const bf16* g, bf16* lds_base) {
    __builtin_amdgcn_global_load_lds((const __attribute__((address_space(1))) void*)g,
                                     (__attribute__((address_space(3))) void*)lds_base,
                                     16, 0, 0);
}

// ---------------------------------------------------------------- dtype detector
__global__ void detect_kernel(const void* xraw, int* flags) {
    const unsigned short* u = (const unsigned short*)xraw;
    __shared__ int cnt;
    if (threadIdx.x == 0) cnt = 0;
    __syncthreads();
    int local = 0;
    for (int i = threadIdx.x; i < 1024; i += 256) {
        int e = (u[2 * i] >> 7) & 0xFF;
        if (e >= 96 && e <= 142) local++;
    }
    atomicAdd(&cnt, local);
    __syncthreads();
    if (threadIdx.x == 0) flags[0] = (cnt < 512) ? 1 : 0;
}

// canonicalize any float tensor to bf16
__global__ void conv_kernel(const void* raw, bf16* dst, int n, const int* flags) {
    int i = blockIdx.x * 256 + threadIdx.x;
    if (i >= n) return;
    if (flags[0]) dst[i] = __float2bfloat16(((const float*)raw)[i]);
    else          dst[i] = ((const bf16*)raw)[i];
}

// canonicalize + transpose weight: in W[K][N] -> out WT[N][K] (bf16)
__global__ void convT_kernel(const void* raw, bf16* dst, int K, int N, const int* flags) {
    __shared__ bf16 tile[32][33];
    const int k0 = blockIdx.y * 32, n0 = blockIdx.x * 32;
    const int tx = threadIdx.x & 31, ty = threadIdx.x >> 5;     // 32 x 8
    #pragma unroll
    for (int p = 0; p < 4; ++p) {
        int k = k0 + ty + p * 8, n = n0 + tx;
        float v = flags[0] ? ((const float*)raw)[(size_t)k * N + n]
                           : bf2float(((const bf16*)raw)[(size_t)k * N + n]);
        tile[ty + p * 8][tx] = __float2bfloat16(v);
    }
    __syncthreads();
    #pragma unroll
    for (int p = 0; p < 4; ++p) {
        int n = n0 + ty + p * 8, k = k0 + tx;
        dst[(size_t)n * K + k] = tile[tx][ty + p * 8];
    }
}

__global__ void zero_kernel(int* p, int n) {
    int i = blockIdx.x * 256 + threadIdx.x;
    if (i < n) p[i] = 0;
}

// sample_idx: int32 or int64 device layout; clamped to [0, Ld)
__global__ void idx_kernel(const void* raw, int* out) {
    const int* r32 = (const int*)raw;
    __shared__ int is64;
    int t = threadIdx.x;                       // 128 threads
    if (t == 0) is64 = 1;
    __syncthreads();
    if (t < 64 && r32[2 * t + 1] != 0) is64 = 0;
    __syncthreads();
    int v = is64 ? r32[2 * t] : r32[t];
    out[t] = min(max(v, 0), Ld - 1);
}

// ---------------------------------------------------------------- MFMA GEMM (m97 recipe)
// C[m,n] = sum_k X[m,k]*WT[n,k] + bias[n]; 128x128 tile, BK=32, 4 waves.
template<bool RELU>
__launch_bounds__(256)
__global__ void mfma_gemm(const bf16* __restrict__ X, const bf16* __restrict__ WT,
                          const bf16* __restrict__ bias, bf16* __restrict__ C,
                          int M, int N, int K)
{
    __shared__ bf16 As[128 * 32];
    __shared__ bf16 Bs[128 * 32];
    const int t = threadIdx.x;
    const int lane = t & 63, wave = t >> 6;
    const int wr = wave >> 1, wc = wave & 1;    // 2x2 wave grid
    const int quad = lane >> 4, l15 = lane & 15;
    const int m0 = blockIdx.y * 128, n0 = blockIdx.x * 128;
    const int lrow = lane >> 2, lcol = (lane & 3) * 8;   // 16 rows x 4x8 cols per wave-load

    f32x4 acc[4][4] = {};

    for (int k0 = 0; k0 < K; k0 += 32) {
        #pragma unroll
        for (int p = 0; p < 2; ++p) {
            int r0 = wave * 16 + p * 64;
            gload_lds16(&X [(size_t)(m0 + r0 + lrow) * K + k0 + lcol], &As[r0 * 32]);
            gload_lds16(&WT[(size_t)(n0 + r0 + lrow) * K + k0 + lcol], &Bs[r0 * 32]);
        }
        __syncthreads();
        bf16x8 a[4], b[4];
        #pragma unroll
        for (int i = 0; i < 4; ++i) {
            a[i] = *(const bf16x8*)&As[(wr * 64 + i * 16 + l15) * 32 + quad * 8];
            b[i] = *(const bf16x8*)&Bs[(wc * 64 + i * 16 + l15) * 32 + quad * 8];
        }
        #pragma unroll
        for (int i = 0; i < 4; ++i)
            #pragma unroll
            for (int j = 0; j < 4; ++j)
                acc[i][j] = __builtin_amdgcn_mfma_f32_16x16x32_bf16(a[i], b[j], acc[i][j], 0, 0, 0);
        __syncthreads();
    }
    // epilogue: D elem (m = quad*4+reg, n = lane&15) within each 16x16 tile
    #pragma unroll
    for (int j = 0; j < 4; ++j) {
        int n = n0 + wc * 64 + j * 16 + l15;
        float bi = bf2float(bias[n]);
        #pragma unroll
        for (int i = 0; i < 4; ++i) {
            #pragma unroll
            for (int r = 0; r < 4; ++r) {
                int m = m0 + wr * 64 + i * 16 + quad * 4 + r;
                float v = acc[i][j][r] + bi;
                if (RELU) v = fmaxf(v, 0.0f);
                C[(size_t)m * N + n] = __float2bfloat16(v);
            }
        }
    }
}

// ---------------------------------------------------------------- M = max-mean of sampled scores
__launch_bounds__(256)
__global__ void m_kernel(const bf16* __restrict__ Q, const bf16* __restrict__ Kg,
                         const int* __restrict__ sidx, float* __restrict__ Mv)
{
    __shared__ float Qs[64][68];
    __shared__ float Ks[64][132];
    __shared__ float redM[64][16];
    __shared__ float redS[64][16];
    const int t  = threadIdx.x;
    const int bh = blockIdx.y, b = bh >> 3, h = bh & 7;
    const int l0 = blockIdx.x * 64;

    int dl = t & 63, r4 = t >> 6;
    #pragma unroll
    for (int p = 0; p < 16; ++p) {
        int lr = r4 + p * 4;
        Qs[dl][lr] = bf2float(Q[((size_t)(b * Ld + l0 + lr)) * Dd + h * 64 + dl]);
    }
    #pragma unroll
    for (int p = 0; p < 32; ++p) {
        int j = r4 + p * 4;
        Ks[dl][j] = bf2float(Kg[((size_t)(b * Ld + sidx[j])) * Dd + h * 64 + dl]);
    }
    __syncthreads();

    const int tx = t & 15, ty = t >> 4;
    float acc[4][8] = {};
    for (int d = 0; d < 64; ++d) {
        float4 a4  = *(const float4*)&Qs[d][ty * 4];
        float4 b4a = *(const float4*)&Ks[d][tx * 8];
        float4 b4b = *(const float4*)&Ks[d][tx * 8 + 4];
        float av[4] = {a4.x, a4.y, a4.z, a4.w};
        float bv[8] = {b4a.x, b4a.y, b4a.z, b4a.w, b4b.x, b4b.y, b4b.z, b4b.w};
        #pragma unroll
        for (int i = 0; i < 4; ++i)
            #pragma unroll
            for (int j = 0; j < 8; ++j)
                acc[i][j] = fmaf(av[i], bv[j], acc[i][j]);
    }
    #pragma unroll
    for (int i = 0; i < 4; ++i) {
        float rmax = -1e30f, rsum = 0.0f;
        #pragma unroll
        for (int j = 0; j < 8; ++j) { rmax = fmaxf(rmax, acc[i][j]); rsum += acc[i][j]; }
        redM[ty * 4 + i][tx] = rmax;
        redS[ty * 4 + i][tx] = rsum;
    }
    __syncthreads();
    if (t < 64) {
        float m = -1e30f, s = 0.0f;
        #pragma unroll
        for (int q = 0; q < 16; ++q) { m = fmaxf(m, redM[t][q]); s += redS[t][q]; }
        Mv[(size_t)bh * Ld + l0 + t] = m - s * (1.0f / 128.0f);
    }
}

// ---------------------------------------------------------------- top-128 via bitonic sort (desc)
__launch_bounds__(256)
__global__ void topk_kernel(const float* __restrict__ Mv, int* __restrict__ topIdx)
{
    __shared__ float val[4096];
    __shared__ int   idx[4096];
    const int bh = blockIdx.x, t = threadIdx.x;
    for (int i = t; i < 4096; i += 256) { val[i] = Mv[(size_t)bh * Ld + i]; idx[i] = i; }
    __syncthreads();
    for (int k = 2; k <= 4096; k <<= 1) {
        for (int j = k >> 1; j > 0; j >>= 1) {
            for (int i = t; i < 4096; i += 256) {
                int ixj = i ^ j;
                if (ixj > i) {
                    bool up = ((i & k) == 0);
                    float vi = val[i], vj = val[ixj];
                    bool sw = up ? (vi < vj) : (vi > vj);
                    if (sw) {
                        val[i] = vj; val[ixj] = vi;
                        int tmp = idx[i]; idx[i] = idx[ixj]; idx[ixj] = tmp;
                    }
                }
            }
            __syncthreads();
        }
    }
    if (t < Ud) topIdx[bh * Ud + t] = idx[t];
}

// ---------------------------------------------------------------- per-row sparse-entry list
__global__ void rows_kernel(const int* __restrict__ topIdx, int* __restrict__ rowCnt,
                            int* __restrict__ rowEnt)
{
    const int bh = blockIdx.x, u = threadIdx.x, b = bh >> 3;
    const int lq = topIdx[bh * Ud + u];
    const int row = b * Ld + lq;
    int slot = atomicAdd(&rowCnt[row], 1) & 7;
    rowEnt[row * 8 + slot] = bh * Ud + u;
}

// ---------------------------------------------------------------- meanV over L per (b,h,d)
// grid (bh=64, chunk=64): 4096 blocks; each reduces 64 rows, atomicAdd partial.
__launch_bounds__(256)
__global__ void meanv_kernel(const bf16* __restrict__ V, float* __restrict__ meanV)
{
    const int bh = blockIdx.x, b = bh >> 3, h = bh & 7;
    const int l0 = blockIdx.y * 64;
    const int t = threadIdx.x;
    const int d = t & 63, part = t >> 6;
    float s = 0.0f;
    #pragma unroll
    for (int p = 0; p < 16; ++p) {
        int l = l0 + part + p * 4;
        s += bf2float(V[((size_t)(b * Ld + l)) * Dd + h * 64 + d]);
    }
    __shared__ float red[256];
    red[t] = s;
    __syncthreads();
    if (t < 64) {
        float tot = red[t] + red[64 + t] + red[128 + t] + red[192 + t];
        atomicAdd(&meanV[bh * 64 + t], tot * (1.0f / 4096.0f));
    }
}

// ---------------------------------------------------------------- MFMA flash attention (K-split partials)
// Grid (bh, ks): each block = all 128 top-U queries x 256 keys (4 kv-tiles of 64).
// QK^T: A = Q frags (regs), B = K rows from LDS (natural [key][d] == B layout).
// K LDS is XOR-swizzled (16B-chunk ^ row&7) with pre-swizzled global_load_lds src.
// Softmax on D-layout acc (row=quad*4+r, col=l15): 4-step shfl over quad group.
// PV: P round-trips per-wave LDS [32][72] (144B rows, conflict-free b128);
// V reg-staged transposed into [d][key] stride-72 so B reads are contiguous.
__launch_bounds__(256, 3)
__global__ void attn_kernel(const bf16* __restrict__ Qg, const bf16* __restrict__ Kg,
                            const bf16* __restrict__ Vg, const int* __restrict__ topIdx,
                            bf16* __restrict__ pO, float* __restrict__ pM, float* __restrict__ pL)
{
    __shared__ __align__(16) short KsS[2][64 * 64];   // [key][d], swizzled, 16 KiB
    __shared__ __align__(16) short VsS[2][64 * 72];   // [d][key], padded, 18 KiB
    __shared__ __align__(16) short PsS[4][32 * 72];   // per-wave [q][key], 18 KiB

    const int t = threadIdx.x, lane = t & 63, w = t >> 6;
    const int l15 = lane & 15, quad = lane >> 4;
    const int bh = blockIdx.x, ks = blockIdx.y;
    const int b = bh >> 3, h = bh & 7;
    const int key0 = ks * (Ld / KSd);
    constexpr int NT = (Ld / KSd) / 64;               // 4 kv-tiles

    // Q fragments (A operand): row = l15 (+16m), k = quad*8 within 32-wide kk step
    bf16x8 qf[2][2];
    #pragma unroll
    for (int m = 0; m < 2; ++m) {
        const int u  = w * 32 + m * 16 + l15;
        const int lq = topIdx[bh * Ud + u];
        const bf16* qr = Qg + ((size_t)(b * Ld + lq)) * Dd + h * 64;
        qf[m][0] = *(const bf16x8*)(qr + quad * 8);
        qf[m][1] = *(const bf16x8*)(qr + 32 + quad * 8);
    }

    const int vkey = t >> 2, vd0 = (t & 3) * 16;
    u16x8 vr0, vr1;

    auto loadV = [&](int tt) {   // V tile -> regs (issued early, coalesced 16B)
        const bf16* vs = Vg + ((size_t)(b * Ld + key0 + tt * 64 + vkey)) * Dd + h * 64 + vd0;
        vr0 = *(const u16x8*)vs;
        vr1 = *(const u16x8*)(vs + 8);
    };
    auto stageK = [&](int buf, int tt) {  // K tile -> LDS via gload_lds, src pre-swizzled
        const int kb0 = key0 + tt * 64;
        #pragma unroll
        for (int sz = 0; sz < 2; ++sz) {
            const int sg = w * 2 + sz;                  // 8-row segment
            const int r  = sg * 8 + (lane >> 3);
            const int cs = (lane & 7) ^ (lane >> 3);    // inverse swizzle on source
            gload_lds16(Kg + ((size_t)(b * Ld + kb0 + r)) * Dd + h * 64 + cs * 8,
                        (bf16*)&KsS[buf][sg * 512]);
        }
    };
    auto writeV = [&](int buf) {  // regs -> transposed LDS
        #pragma unroll
        for (int j = 0; j < 8; ++j) {
            VsS[buf][(vd0 + j) * 72 + vkey]     = (short)vr0[j];
            VsS[buf][(vd0 + 8 + j) * 72 + vkey] = (short)vr1[j];
        }
    };

    float mrun[2][4], lrun[2][4];
    f32x4 o[2][4] = {};
    #pragma unroll
    for (int m = 0; m < 2; ++m)
        #pragma unroll
        for (int r = 0; r < 4; ++r) { mrun[m][r] = -1e30f; lrun[m][r] = 0.0f; }

    loadV(0); stageK(0, 0); writeV(0);
    __syncthreads();

    short* PsW = &PsS[w][0];
    for (int tt = 0; tt < NT; ++tt) {
        const int cur = tt & 1;
        if (tt + 1 < NT) { loadV(tt + 1); stageK(cur ^ 1, tt + 1); }

        // ---- QK^T -> S (f32), 16 MFMA
        const short* KsB = &KsS[cur][0];
        f32x4 s[2][4] = {};
        #pragma unroll
        for (int kk = 0; kk < 2; ++kk) {
            bf16x8 kb[4];
            #pragma unroll
            for (int n = 0; n < 4; ++n)
                kb[n] = *(const bf16x8*)&KsB[(n * 16 + l15) * 64 +
                                             (((kk * 4 + quad) ^ (l15 & 7)) * 8)];
            #pragma unroll
            for (int m = 0; m < 2; ++m)
                #pragma unroll
                for (int n = 0; n < 4; ++n)
                    s[m][n] = __builtin_amdgcn_mfma_f32_16x16x32_bf16(qf[m][kk], kb[n], s[m][n], 0, 0, 0);
        }

        // ---- online softmax; rows = quad*4+r (+16m), cols = l15 (+16n)
        #pragma unroll
        for (int m = 0; m < 2; ++m) {
            #pragma unroll
            for (int r = 0; r < 4; ++r) {
                float sv[4];
                #pragma unroll
                for (int n = 0; n < 4; ++n) sv[n] = s[m][n][r] * 0.125f;
                float vm = fmaxf(fmaxf(sv[0], sv[1]), fmaxf(sv[2], sv[3]));
                #pragma unroll
                for (int off = 1; off < 16; off <<= 1) vm = fmaxf(vm, __shfl_xor(vm, off));
                const float mn = fmaxf(mrun[m][r], vm);
                const float al = __expf(mrun[m][r] - mn);
                float ps = 0.0f;
                #pragma unroll
                for (int n = 0; n < 4; ++n) { sv[n] = __expf(sv[n] - mn); ps += sv[n]; }
                #pragma unroll
                for (int off = 1; off < 16; off <<= 1) ps += __shfl_xor(ps, off);
                lrun[m][r] = lrun[m][r] * al + ps;
                mrun[m][r] = mn;
                const int qrow = m * 16 + quad * 4 + r;
                #pragma unroll
                for (int n = 0; n < 4; ++n) {
                    PsW[qrow * 72 + n * 16 + l15] = f2bs(sv[n]);
                    o[m][n][r] *= al;
                }
            }
        }

        if (tt + 1 < NT) writeV(cur ^ 1);   // into other buffer; hides under PV

        // ---- PV: O += P * V, 16 MFMA
        const short* VsB = &VsS[cur][0];
        #pragma unroll
        for (int kk = 0; kk < 2; ++kk) {
            bf16x8 pa[2], vb[4];
            #pragma unroll
            for (int m = 0; m < 2; ++m)
                pa[m] = *(const bf16x8*)&PsW[(m * 16 + l15) * 72 + kk * 32 + quad * 8];
            #pragma unroll
            for (int n = 0; n < 4; ++n)
                vb[n] = *(const bf16x8*)&VsB[(n * 16 + l15) * 72 + kk * 32 + quad * 8];
            #pragma unroll
            for (int m = 0; m < 2; ++m)
                #pragma unroll
                for (int n = 0; n < 4; ++n)
                    o[m][n] = __builtin_amdgcn_mfma_f32_16x16x32_bf16(pa[m], vb[n], o[m][n], 0, 0, 0);
        }
        __syncthreads();
    }

    const size_t pbase = ((size_t)(ks * 64 + bh)) * Ud;
    #pragma unroll
    for (int m = 0; m < 2; ++m) {
        #pragma unroll
        for (int r = 0; r < 4; ++r) {
            const int u = w * 32 + m * 16 + quad * 4 + r;
            #pragma unroll
            for (int n = 0; n < 4; ++n)
                pO[(pbase + u) * 64 + n * 16 + l15] = __float2bfloat16(o[m][n][r]);
            if (l15 == 0) { pM[pbase + u] = mrun[m][r]; pL[pbase + u] = lrun[m][r]; }
        }
    }
}

// combine K-split partials -> ctxTop
__global__ void combine_kernel(const bf16* __restrict__ pO, const float* __restrict__ pM,
                               const float* __restrict__ pL, float* __restrict__ ctxTop)
{
    const int u = blockIdx.x & 127, bh = blockIdx.x >> 7, c = threadIdx.x;
    float mstar = -1e30f;
    #pragma unroll
    for (int ks = 0; ks < KSd; ++ks)
        mstar = fmaxf(mstar, pM[(ks * 64 + bh) * Ud + u]);
    float lsum = 0.0f, osum = 0.0f;
    #pragma unroll
    for (int ks = 0; ks < KSd; ++ks) {
        float wgt = __expf(pM[(ks * 64 + bh) * Ud + u] - mstar);
        lsum += pL[(ks * 64 + bh) * Ud + u] * wgt;
        osum += bf2float(pO[(((size_t)ks * 64 + bh) * Ud + u) * 64 + c]) * wgt;
    }
    ctxTop[((size_t)bh * Ud + u) * 64 + c] = scrub(osum / lsum);
}

// ---------------------------------------------------------------- base row: concat(meanV) @ Wo + bo
__launch_bounds__(512)
__global__ void baseout_kernel(const float* __restrict__ meanV, const bf16* __restrict__ Wo,
                               const bf16* __restrict__ bo, float* __restrict__ baseOut)
{
    const int b = blockIdx.x, t = threadIdx.x;
    __shared__ float mv[512];
    mv[t] = meanV[b * 512 + t];
    __syncthreads();
    float acc = bf2float(bo[t]);
    for (int d = 0; d < 512; ++d)
        acc = fmaf(mv[d], bf2float(Wo[(size_t)d * 512 + t]), acc);
    baseOut[b * 512 + t] = acc;
}

// ---------------------------------------------------------------- per-(bh,u) delta rows (bf16 out)
__launch_bounds__(256)
__global__ void delta_kernel(const float* __restrict__ ctxTop, const float* __restrict__ meanV,
                             const bf16* __restrict__ Wo, bf16* __restrict__ deltaOut)
{
    const int u = blockIdx.x, bh = blockIdx.y, h = bh & 7, t = threadIdx.x;
    __shared__ float diff[64];
    if (t < 64) diff[t] = ctxTop[((size_t)bh * Ud + u) * 64 + t] - meanV[bh * 64 + t];
    __syncthreads();
    for (int n = t; n < 512; n += 256) {
        float acc = 0.0f;
        #pragma unroll 8
        for (int dd = 0; dd < 64; ++dd)
            acc = fmaf(diff[dd], bf2float(Wo[(size_t)(h * 64 + dd) * 512 + n]), acc);
        deltaOut[((size_t)bh * Ud + u) * 512 + n] = __float2bfloat16(acc);
    }
}

// ---------------------------------------------------------------- LayerNorms
__launch_bounds__(256)
__global__ void ln1_kernel(const bf16* __restrict__ x, const float* __restrict__ baseOut,
                           const int* __restrict__ rowCnt, const int* __restrict__ rowEnt,
                           const bf16* __restrict__ deltaOut,
                           const bf16* __restrict__ g, const bf16* __restrict__ bb,
                           bf16* __restrict__ x1)
{
    const int row = blockIdx.x, t = threadIdx.x;
    const int b = row >> 12;
    const size_t base = (size_t)row * 512;
    float v0 = bf2float(x[base + t])       + baseOut[b * 512 + t];
    float v1 = bf2float(x[base + t + 256]) + baseOut[b * 512 + t + 256];
    const int cnt = min(rowCnt[row], 8);
    for (int e = 0; e < cnt; ++e) {
        const bf16* dr = &deltaOut[(size_t)rowEnt[row * 8 + e] * 512];
        v0 += bf2float(dr[t]);
        v1 += bf2float(dr[t + 256]);
    }
    v0 = scrub(v0); v1 = scrub(v1);
    float s = v0 + v1, q = v0 * v0 + v1 * v1;
    s = wred_sum(s); q = wred_sum(q);
    __shared__ float sred[4], qred[4];
    int lane = t & 63, w = t >> 6;
    if (lane == 0) { sred[w] = s; qred[w] = q; }
    __syncthreads();
    float tot  = sred[0] + sred[1] + sred[2] + sred[3];
    float totq = qred[0] + qred[1] + qred[2] + qred[3];
    float mean = tot * (1.0f / 512.0f);
    float var  = fmaxf(totq * (1.0f / 512.0f) - mean * mean, 0.0f);
    float rstd = rsqrtf(var + 1e-6f);
    x1[base + t]       = __float2bfloat16((v0 - mean) * rstd * bf2float(g[t])       + bf2float(bb[t]));
    x1[base + t + 256] = __float2bfloat16((v1 - mean) * rstd * bf2float(g[t + 256]) + bf2float(bb[t + 256]));
}

__launch_bounds__(256)
__global__ void ln2_kernel(const bf16* __restrict__ x1, const bf16* __restrict__ ffn,
                           const bf16* __restrict__ g, const bf16* __restrict__ bb,
                           void* __restrict__ out, const int* __restrict__ flags)
{
    const int row = blockIdx.x, t = threadIdx.x;
    const size_t base = (size_t)row * 512;
    float v0 = bf2float(x1[base + t])       + bf2float(ffn[base + t]);
    float v1 = bf2float(x1[base + t + 256]) + bf2float(ffn[base + t + 256]);
    v0 = scrub(v0); v1 = scrub(v1);
    float s = v0 + v1, q = v0 * v0 + v1 * v1;
    s = wred_sum(s); q = wred_sum(q);
    __shared__ float sred[4], qred[4];
    int lane = t & 63, w = t >> 6;
    if (lane == 0) { sred[w] = s; qred[w] = q; }
    __syncthreads();
    float tot  = sred[0] + sred[1] + sred[2] + sred[3];
    float totq = qred[0] + qred[1] + qred[2] + qred[3];
    float mean = tot * (1.0f / 512.0f);
    float var  = fmaxf(totq * (1.0f / 512.0f) - mean * mean, 0.0f);
    float rstd = rsqrtf(var + 1e-6f);
    float o0 = (v0 - mean) * rstd * bf2float(g[t])       + bf2float(bb[t]);
    float o1 = (v1 - mean) * rstd * bf2float(g[t + 256]) + bf2float(bb[t + 256]);
    if (flags[0]) {
        ((float*)out)[base + t]       = o0;
        ((float*)out)[base + t + 256] = o1;
    } else {
        ((bf16*)out)[base + t]       = __float2bfloat16(o0);
        ((bf16*)out)[base + t + 256] = __float2bfloat16(o1);
    }
}

// ================================================================ launcher
extern "C" void kernel_launch(void* const* d_in, const int* in_sizes, int n_in,
                              void* d_out, int out_size, void* d_ws, size_t ws_size,
                              hipStream_t stream)
{
    const void* sraw = d_in[17];

    const size_t NQ = (size_t)MLd * Dd;          // 16,777,216 elements
    char* w = (char*)d_ws;
    size_t off = 0;
    auto alloc = [&](size_t bytes) { void* p = w + off; off += (bytes + 63) & ~size_t(63); return p; };
    bf16*  Qb   = (bf16*)alloc(NQ * 2);                       // 32 MiB
    bf16*  Kb   = (bf16*)alloc(NQ * 2);                       // 32 MiB (contiguous after Qb)
    bf16*  Vb   = (bf16*)alloc(NQ * 2);                       // 32 MiB
    bf16*  xc   = (bf16*)alloc(NQ * 2);                       // 32 MiB
    bf16*  WTq  = (bf16*)alloc(Dd * Dd * 2);
    bf16*  WTk  = (bf16*)alloc(Dd * Dd * 2);
    bf16*  WTv  = (bf16*)alloc(Dd * Dd * 2);
    bf16*  Woc  = (bf16*)alloc(Dd * Dd * 2);                  // untransposed
    bf16*  WT1f = (bf16*)alloc((size_t)Dd * DFFd * 2);        // [2048][512]
    bf16*  WT2f = (bf16*)alloc((size_t)DFFd * Dd * 2);        // [512][2048]
    bf16* bqc = (bf16*)alloc(Dd * 2);
    bf16* bkc = (bf16*)alloc(Dd * 2);
    bf16* bvc = (bf16*)alloc(Dd * 2);
    bf16* boc = (bf16*)alloc(Dd * 2);
    bf16* g1c = (bf16*)alloc(Dd * 2);
    bf16* b1c = (bf16*)alloc(Dd * 2);
    bf16* b1fc= (bf16*)alloc(DFFd * 2);
    bf16* b2fc= (bf16*)alloc(Dd * 2);
    bf16* g2c = (bf16*)alloc(Dd * 2);
    bf16* b2c = (bf16*)alloc(Dd * 2);
    bf16*  pOb     = (bf16*)alloc((size_t)KSd * 64 * Ud * 64 * 2);   // 16 MiB
    float* Mv      = (float*)alloc((size_t)Bd * Hd * Ld * 4);        // 1 MiB
    float* ctxTop  = (float*)alloc((size_t)Bd * Hd * Ud * DHd * 4);  // 2 MiB
    float* meanV   = (float*)alloc(Bd * Hd * DHd * 4);
    float* baseOut = (float*)alloc(Bd * Dd * 4);
    int*   topIdx  = (int*)alloc(Bd * Hd * Ud * 4);
    int*   sidx    = (int*)alloc(128 * 4);
    int*   rowCnt  = (int*)alloc(MLd * 4);
    int*   rowEnt  = (int*)alloc(MLd * 8 * 4);
    int*   flags   = (int*)alloc(64);
    // aliases (lifetimes disjoint, stream-serialized):
    bf16*  x1b  = Vb;                 // ln1 output (V dead)
    bf16*  h1b  = Qb;                 // FFN hidden chunk 16384x2048 spans Qb+Kb (both dead)
    bf16*  ffnb = xc;                 // FFN out (xc dead after ln1)
    bf16*  deltaOut = pOb;            // after combine_kernel, pO dead
    float* pM = Mv;                   // Mv dead after topk
    float* pL = Mv + KSd * 64 * Ud;

    if (off > ws_size) return;

    detect_kernel<<<1, 256, 0, stream>>>(d_in[0], flags);

    auto conv = [&](int i, bf16* dst, int n) {
        conv_kernel<<<(n + 255) / 256, 256, 0, stream>>>(d_in[i], dst, n, flags);
    };
    conv(0,  xc, (int)NQ);
    convT_kernel<<<dim3(Dd / 32, Dd / 32), 256, 0, stream>>>(d_in[1], WTq, Dd, Dd, flags);
    convT_kernel<<<dim3(Dd / 32, Dd / 32), 256, 0, stream>>>(d_in[3], WTk, Dd, Dd, flags);
    convT_kernel<<<dim3(Dd / 32, Dd / 32), 256, 0, stream>>>(d_in[5], WTv, Dd, Dd, flags);
    convT_kernel<<<dim3(DFFd / 32, Dd / 32), 256, 0, stream>>>(d_in[11], WT1f, Dd, DFFd, flags);
    convT_kernel<<<dim3(Dd / 32, DFFd / 32), 256, 0, stream>>>(d_in[13], WT2f, DFFd, Dd, flags);
    conv(7,  Woc, Dd * Dd);
    conv(2,  bqc, Dd);  conv(4,  bkc, Dd);  conv(6,  bvc, Dd);  conv(8,  boc, Dd);
    conv(9,  g1c, Dd);  conv(10, b1c, Dd);
    conv(12, b1fc, DFFd); conv(14, b2fc, Dd);
    conv(15, g2c, Dd);  conv(16, b2c, Dd);

    zero_kernel<<<(MLd + 255) / 256, 256, 0, stream>>>(rowCnt, MLd);
    zero_kernel<<<(Bd * Hd * DHd + 255) / 256, 256, 0, stream>>>((int*)meanV, Bd * Hd * DHd);
    idx_kernel<<<1, 128, 0, stream>>>(sraw, sidx);

    // QKV projections (MFMA, async-staged)
    mfma_gemm<false><<<dim3(4, 256), 256, 0, stream>>>(xc, WTq, bqc, Qb, MLd, Dd, Dd);
    mfma_gemm<false><<<dim3(4, 256), 256, 0, stream>>>(xc, WTk, bkc, Kb, MLd, Dd, Dd);
    mfma_gemm<false><<<dim3(4, 256), 256, 0, stream>>>(xc, WTv, bvc, Vb, MLd, Dd, Dd);

    m_kernel<<<dim3(Ld / 64, Bd * Hd), 256, 0, stream>>>(Qb, Kb, sidx, Mv);
    topk_kernel<<<Bd * Hd, 256, 0, stream>>>(Mv, topIdx);
    rows_kernel<<<Bd * Hd, 128, 0, stream>>>(topIdx, rowCnt, rowEnt);
    meanv_kernel<<<dim3(Bd * Hd, Ld / 64), 256, 0, stream>>>(Vb, meanV);

    attn_kernel<<<dim3(Bd * Hd, KSd), 256, 0, stream>>>(Qb, Kb, Vb, topIdx, pOb, pM, pL);
    combine_kernel<<<Bd * Hd * Ud, 64, 0, stream>>>(pOb, pM, pL, ctxTop);

    baseout_kernel<<<Bd, 512, 0, stream>>>(meanV, Woc, boc, baseOut);
    delta_kernel<<<dim3(Ud, Bd * Hd), 256, 0, stream>>>(ctxTop, meanV, Woc, deltaOut);

    ln1_kernel<<<MLd, 256, 0, stream>>>(xc, baseOut, rowCnt, rowEnt, deltaOut, g1c, b1c, x1b);

    // FFN, chunked over rows (2 chunks of 16384: h1 = 64 MiB spanning Qb+Kb)
    for (int c = 0; c < 2; ++c) {
        mfma_gemm<true ><<<dim3(16, 128), 256, 0, stream>>>(
            x1b + (size_t)c * 16384 * 512, WT1f, b1fc, h1b, 16384, DFFd, Dd);
        mfma_gemm<false><<<dim3(4, 128), 256, 0, stream>>>(
            h1b, WT2f, b2fc, ffnb + (size_t)c * 16384 * 512, 16384, Dd, DFFd);
    }

    ln2_kernel<<<MLd, 256, 0, stream>>>(x1b, ffnb, g2c, b2c, d_out, flags);
}

// Round 3
// 813.558 us; speedup vs baseline: 1.9455x; 1.1624x over previous
//
#include <hip/hip_runtime.h>
#include <hip/hip_bf16.h>

using bf16 = __hip_bfloat16;

constexpr int Bd  = 8;
constexpr int Ld  = 4096;
constexpr int Dd  = 512;
constexpr int Hd  = 8;
constexpr int DHd = 64;
constexpr int DFFd= 2048;
constexpr int Ud  = 128;           // TOP_U
constexpr int MLd = Bd * Ld;       // 32768 rows
constexpr int KSd = 16;            // attention K-split (256 keys per block)

typedef short          bf16x8 __attribute__((ext_vector_type(8)));
typedef unsigned short u16x8  __attribute__((ext_vector_type(8)));
typedef float          f32x4  __attribute__((ext_vector_type(4)));

__device__ __forceinline__ float bf2float(bf16 v) { return __bfloat162float(v); }

__device__ __forceinline__ float wred_sum(float v) {
    #pragma unroll
    for (int o = 32; o > 0; o >>= 1) v += __shfl_xor(v, o);
    return v;
}
__device__ __forceinline__ float wred_max(float v) {
    #pragma unroll
    for (int o = 32; o > 0; o >>= 1) v = fmaxf(v, __shfl_xor(v, o));
    return v;
}
__device__ __forceinline__ float scrub(float v) {       // NaN/Inf -> 0
    return (fabsf(v) < 1e20f) ? v : 0.0f;
}
__device__ __forceinline__ short f2bs(float f) {        // float -> bf16 bits
    bf16 h = __float2bfloat16(f);
    return *reinterpret_cast<short*>(&h);
}

// async global->LDS, 16B per lane; LDS dest = wave-uniform base + lane*16
__device__ __forceinline__ void gload_lds16(const bf16* g, bf16* lds_base) {
    __builtin_amdgcn_global_load_lds((const __attribute__((address_space(1))) void*)g,
                                     (__attribute__((address_space(3))) void*)lds_base,
                                     16, 0, 0);
}

// ---------------------------------------------------------------- dtype detector
__global__ void detect_kernel(const void* xraw, int* flags) {
    const unsigned short* u = (const unsigned short*)xraw;
    __shared__ int cnt;
    if (threadIdx.x == 0) cnt = 0;
    __syncthreads();
    int local = 0;
    for (int i = threadIdx.x; i < 1024; i += 256) {
        int e = (u[2 * i] >> 7) & 0xFF;
        if (e >= 96 && e <= 142) local++;
    }
    atomicAdd(&cnt, local);
    __syncthreads();
    if (threadIdx.x == 0) flags[0] = (cnt < 512) ? 1 : 0;
}

// canonicalize any float tensor to bf16
__global__ void conv_kernel(const void* raw, bf16* dst, int n, const int* flags) {
    int i = blockIdx.x * 256 + threadIdx.x;
    if (i >= n) return;
    if (flags[0]) dst[i] = __float2bfloat16(((const float*)raw)[i]);
    else          dst[i] = ((const bf16*)raw)[i];
}

// canonicalize + transpose weight: in W[K][N] -> out WT[N][K] (bf16)
__global__ void convT_kernel(const void* raw, bf16* dst, int K, int N, const int* flags) {
    __shared__ bf16 tile[32][33];
    const int k0 = blockIdx.y * 32, n0 = blockIdx.x * 32;
    const int tx = threadIdx.x & 31, ty = threadIdx.x >> 5;     // 32 x 8
    #pragma unroll
    for (int p = 0; p < 4; ++p) {
        int k = k0 + ty + p * 8, n = n0 + tx;
        float v = flags[0] ? ((const float*)raw)[(size_t)k * N + n]
                           : bf2float(((const bf16*)raw)[(size_t)k * N + n]);
        tile[ty + p * 8][tx] = __float2bfloat16(v);
    }
    __syncthreads();
    #pragma unroll
    for (int p = 0; p < 4; ++p) {
        int n = n0 + ty + p * 8, k = k0 + tx;
        dst[(size_t)n * K + k] = tile[tx][ty + p * 8];
    }
}

__global__ void zero_kernel(int* p, int n) {
    int i = blockIdx.x * 256 + threadIdx.x;
    if (i < n) p[i] = 0;
}

// sample_idx: int32 or int64 device layout; clamped to [0, Ld)
__global__ void idx_kernel(const void* raw, int* out) {
    const int* r32 = (const int*)raw;
    __shared__ int is64;
    int t = threadIdx.x;                       // 128 threads
    if (t == 0) is64 = 1;
    __syncthreads();
    if (t < 64 && r32[2 * t + 1] != 0) is64 = 0;
    __syncthreads();
    int v = is64 ? r32[2 * t] : r32[t];
    out[t] = min(max(v, 0), Ld - 1);
}

// ---------------------------------------------------------------- MFMA GEMM (m97 recipe)
// C[m,n] = sum_k X[m,k]*WT[n,k] + bias[n]; 128x128 tile, BK=32, 4 waves.
template<bool RELU>
__launch_bounds__(256)
__global__ void mfma_gemm(const bf16* __restrict__ X, const bf16* __restrict__ WT,
                          const bf16* __restrict__ bias, bf16* __restrict__ C,
                          int M, int N, int K)
{
    __shared__ bf16 As[128 * 32];
    __shared__ bf16 Bs[128 * 32];
    const int t = threadIdx.x;
    const int lane = t & 63, wave = t >> 6;
    const int wr = wave >> 1, wc = wave & 1;    // 2x2 wave grid
    const int quad = lane >> 4, l15 = lane & 15;
    const int m0 = blockIdx.y * 128, n0 = blockIdx.x * 128;
    const int lrow = lane >> 2, lcol = (lane & 3) * 8;   // 16 rows x 4x8 cols per wave-load

    f32x4 acc[4][4] = {};

    for (int k0 = 0; k0 < K; k0 += 32) {
        #pragma unroll
        for (int p = 0; p < 2; ++p) {
            int r0 = wave * 16 + p * 64;
            gload_lds16(&X [(size_t)(m0 + r0 + lrow) * K + k0 + lcol], &As[r0 * 32]);
            gload_lds16(&WT[(size_t)(n0 + r0 + lrow) * K + k0 + lcol], &Bs[r0 * 32]);
        }
        __syncthreads();
        bf16x8 a[4], b[4];
        #pragma unroll
        for (int i = 0; i < 4; ++i) {
            a[i] = *(const bf16x8*)&As[(wr * 64 + i * 16 + l15) * 32 + quad * 8];
            b[i] = *(const bf16x8*)&Bs[(wc * 64 + i * 16 + l15) * 32 + quad * 8];
        }
        #pragma unroll
        for (int i = 0; i < 4; ++i)
            #pragma unroll
            for (int j = 0; j < 4; ++j)
                acc[i][j] = __builtin_amdgcn_mfma_f32_16x16x32_bf16(a[i], b[j], acc[i][j], 0, 0, 0);
        __syncthreads();
    }
    // epilogue: D elem (m = quad*4+reg, n = lane&15) within each 16x16 tile
    #pragma unroll
    for (int j = 0; j < 4; ++j) {
        int n = n0 + wc * 64 + j * 16 + l15;
        float bi = bf2float(bias[n]);
        #pragma unroll
        for (int i = 0; i < 4; ++i) {
            #pragma unroll
            for (int r = 0; r < 4; ++r) {
                int m = m0 + wr * 64 + i * 16 + quad * 4 + r;
                float v = acc[i][j][r] + bi;
                if (RELU) v = fmaxf(v, 0.0f);
                C[(size_t)m * N + n] = __float2bfloat16(v);
            }
        }
    }
}

// ---------------------------------------------------------------- M = max-mean of sampled scores
__launch_bounds__(256)
__global__ void m_kernel(const bf16* __restrict__ Q, const bf16* __restrict__ Kg,
                         const int* __restrict__ sidx, float* __restrict__ Mv)
{
    __shared__ float Qs[64][68];
    __shared__ float Ks[64][132];
    __shared__ float redM[64][16];
    __shared__ float redS[64][16];
    const int t  = threadIdx.x;
    const int bh = blockIdx.y, b = bh >> 3, h = bh & 7;
    const int l0 = blockIdx.x * 64;

    int dl = t & 63, r4 = t >> 6;
    #pragma unroll
    for (int p = 0; p < 16; ++p) {
        int lr = r4 + p * 4;
        Qs[dl][lr] = bf2float(Q[((size_t)(b * Ld + l0 + lr)) * Dd + h * 64 + dl]);
    }
    #pragma unroll
    for (int p = 0; p < 32; ++p) {
        int j = r4 + p * 4;
        Ks[dl][j] = bf2float(Kg[((size_t)(b * Ld + sidx[j])) * Dd + h * 64 + dl]);
    }
    __syncthreads();

    const int tx = t & 15, ty = t >> 4;
    float acc[4][8] = {};
    for (int d = 0; d < 64; ++d) {
        float4 a4  = *(const float4*)&Qs[d][ty * 4];
        float4 b4a = *(const float4*)&Ks[d][tx * 8];
        float4 b4b = *(const float4*)&Ks[d][tx * 8 + 4];
        float av[4] = {a4.x, a4.y, a4.z, a4.w};
        float bv[8] = {b4a.x, b4a.y, b4a.z, b4a.w, b4b.x, b4b.y, b4b.z, b4b.w};
        #pragma unroll
        for (int i = 0; i < 4; ++i)
            #pragma unroll
            for (int j = 0; j < 8; ++j)
                acc[i][j] = fmaf(av[i], bv[j], acc[i][j]);
    }
    #pragma unroll
    for (int i = 0; i < 4; ++i) {
        float rmax = -1e30f, rsum = 0.0f;
        #pragma unroll
        for (int j = 0; j < 8; ++j) { rmax = fmaxf(rmax, acc[i][j]); rsum += acc[i][j]; }
        redM[ty * 4 + i][tx] = rmax;
        redS[ty * 4 + i][tx] = rsum;
    }
    __syncthreads();
    if (t < 64) {
        float m = -1e30f, s = 0.0f;
        #pragma unroll
        for (int q = 0; q < 16; ++q) { m = fmaxf(m, redM[t][q]); s += redS[t][q]; }
        Mv[(size_t)bh * Ld + l0 + t] = m - s * (1.0f / 128.0f);
    }
}

// ---------------------------------------------------------------- top-128 via 8-bit radix select
// One block per bh. Exact top-128 SET (order arbitrary; downstream is set/slot
// semantics). 4 byte-plane rounds: LDS histogram -> pivot bin -> emit winners,
// compact ties. ~16 barriers vs bitonic's 78 full-array phases.
__launch_bounds__(256)
__global__ void topk_kernel(const float* __restrict__ Mv, int* __restrict__ topIdx)
{
    __shared__ unsigned ukey[4096];                 // 16 KiB
    __shared__ short listA[4096], listB[4096];      // 16 KiB candidate lists
    __shared__ int hist[256];
    __shared__ int outCnt, candCnt, selB, aboveK;
    const int bh = blockIdx.x, t = threadIdx.x;

    for (int i = t; i < 4096; i += 256) {
        unsigned u = __float_as_uint(Mv[(size_t)bh * Ld + i]);
        ukey[i] = (u & 0x80000000u) ? ~u : (u | 0x80000000u);   // sort-monotonic
    }
    if (t == 0) outCnt = 0;
    __syncthreads();

    int K = Ud;                                     // remaining to select
    #pragma unroll
    for (int r = 0; r < 4; ++r) {
        const int shift = 24 - 8 * r;
        hist[t] = 0;
        __syncthreads();
        const int n = (r == 0) ? 4096 : candCnt;
        const short* cur = (r & 1) ? listB : listA;
        for (int i = t; i < n; i += 256) {
            int idx = (r == 0) ? i : cur[i];
            atomicAdd(&hist[(ukey[idx] >> shift) & 0xFF], 1);
        }
        __syncthreads();
        if (t == 0) {
            int cum = 0, b = 255;
            for (; b > 0; --b) {
                if (cum + hist[b] >= K) break;
                cum += hist[b];
            }
            selB = b; aboveK = cum; candCnt = 0;
        }
        __syncthreads();
        const int sb = selB;
        short* nxt = (r & 1) ? listA : listB;
        for (int i = t; i < n; i += 256) {
            int idx = (r == 0) ? i : cur[i];
            int by = (ukey[idx] >> shift) & 0xFF;
            if (by > sb) {
                int p = atomicAdd(&outCnt, 1);
                topIdx[bh * Ud + p] = idx;
            } else if (by == sb) {
                int p = atomicAdd(&candCnt, 1);
                nxt[p] = (short)idx;
            }
        }
        __syncthreads();
        K -= aboveK;
        if (K == 0) break;
    }
    // leftover K candidates all share an identical 32-bit key: take any K
    if (K > 0) {                                    // final list is listA (r=3 wrote it)
        for (int i = t; i < K; i += 256) {
            int p = atomicAdd(&outCnt, 1);
            topIdx[bh * Ud + p] = listA[i];
        }
    }
}

// ---------------------------------------------------------------- per-row sparse-entry list
__global__ void rows_kernel(const int* __restrict__ topIdx, int* __restrict__ rowCnt,
                            int* __restrict__ rowEnt)
{
    const int bh = blockIdx.x, u = threadIdx.x, b = bh >> 3;
    const int lq = topIdx[bh * Ud + u];
    const int row = b * Ld + lq;
    int slot = atomicAdd(&rowCnt[row], 1) & 7;
    rowEnt[row * 8 + slot] = bh * Ud + u;
}

// ---------------------------------------------------------------- meanV over L per (b,h,d)
// grid (bh=64, chunk=64): 4096 blocks; each reduces 64 rows, atomicAdd partial.
__launch_bounds__(256)
__global__ void meanv_kernel(const bf16* __restrict__ V, float* __restrict__ meanV)
{
    const int bh = blockIdx.x, b = bh >> 3, h = bh & 7;
    const int l0 = blockIdx.y * 64;
    const int t = threadIdx.x;
    const int d = t & 63, part = t >> 6;
    float s = 0.0f;
    #pragma unroll
    for (int p = 0; p < 16; ++p) {
        int l = l0 + part + p * 4;
        s += bf2float(V[((size_t)(b * Ld + l)) * Dd + h * 64 + d]);
    }
    __shared__ float red[256];
    red[t] = s;
    __syncthreads();
    if (t < 64) {
        float tot = red[t] + red[64 + t] + red[128 + t] + red[192 + t];
        atomicAdd(&meanV[bh * 64 + t], tot * (1.0f / 4096.0f));
    }
}

// ---------------------------------------------------------------- MFMA flash attention (K-split partials)
// Grid (bh, ks): each block = all 128 top-U queries x 256 keys (4 kv-tiles of 64).
// QK^T: A = Q frags (regs), B = K rows from LDS (natural [key][d] == B layout).
// K LDS is XOR-swizzled (16B-chunk ^ row&7) with pre-swizzled global_load_lds src.
// Softmax on D-layout acc (row=quad*4+r, col=l15): 4-step shfl over quad group.
// PV: P round-trips per-wave LDS [32][72] (144B rows, conflict-free b128);
// V reg-staged transposed into [d][key] stride-72 so B reads are contiguous.
__launch_bounds__(256, 3)
__global__ void attn_kernel(const bf16* __restrict__ Qg, const bf16* __restrict__ Kg,
                            const bf16* __restrict__ Vg, const int* __restrict__ topIdx,
                            bf16* __restrict__ pO, float* __restrict__ pM, float* __restrict__ pL)
{
    __shared__ __align__(16) short KsS[2][64 * 64];   // [key][d], swizzled, 16 KiB
    __shared__ __align__(16) short VsS[2][64 * 72];   // [d][key], padded, 18 KiB
    __shared__ __align__(16) short PsS[4][32 * 72];   // per-wave [q][key], 18 KiB

    const int t = threadIdx.x, lane = t & 63, w = t >> 6;
    const int l15 = lane & 15, quad = lane >> 4;
    const int bh = blockIdx.x, ks = blockIdx.y;
    const int b = bh >> 3, h = bh & 7;
    const int key0 = ks * (Ld / KSd);
    constexpr int NT = (Ld / KSd) / 64;               // 4 kv-tiles

    // Q fragments (A operand): row = l15 (+16m), k = quad*8 within 32-wide kk step
    bf16x8 qf[2][2];
    #pragma unroll
    for (int m = 0; m < 2; ++m) {
        const int u  = w * 32 + m * 16 + l15;
        const int lq = topIdx[bh * Ud + u];
        const bf16* qr = Qg + ((size_t)(b * Ld + lq)) * Dd + h * 64;
        qf[m][0] = *(const bf16x8*)(qr + quad * 8);
        qf[m][1] = *(const bf16x8*)(qr + 32 + quad * 8);
    }

    const int vkey = t >> 2, vd0 = (t & 3) * 16;
    u16x8 vr0, vr1;

    auto loadV = [&](int tt) {   // V tile -> regs (issued early, coalesced 16B)
        const bf16* vs = Vg + ((size_t)(b * Ld + key0 + tt * 64 + vkey)) * Dd + h * 64 + vd0;
        vr0 = *(const u16x8*)vs;
        vr1 = *(const u16x8*)(vs + 8);
    };
    auto stageK = [&](int buf, int tt) {  // K tile -> LDS via gload_lds, src pre-swizzled
        const int kb0 = key0 + tt * 64;
        #pragma unroll
        for (int sz = 0; sz < 2; ++sz) {
            const int sg = w * 2 + sz;                  // 8-row segment
            const int r  = sg * 8 + (lane >> 3);
            const int cs = (lane & 7) ^ (lane >> 3);    // inverse swizzle on source
            gload_lds16(Kg + ((size_t)(b * Ld + kb0 + r)) * Dd + h * 64 + cs * 8,
                        (bf16*)&KsS[buf][sg * 512]);
        }
    };
    auto writeV = [&](int buf) {  // regs -> transposed LDS
        #pragma unroll
        for (int j = 0; j < 8; ++j) {
            VsS[buf][(vd0 + j) * 72 + vkey]     = (short)vr0[j];
            VsS[buf][(vd0 + 8 + j) * 72 + vkey] = (short)vr1[j];
        }
    };

    float mrun[2][4], lrun[2][4];
    f32x4 o[2][4] = {};
    #pragma unroll
    for (int m = 0; m < 2; ++m)
        #pragma unroll
        for (int r = 0; r < 4; ++r) { mrun[m][r] = -1e30f; lrun[m][r] = 0.0f; }

    loadV(0); stageK(0, 0); writeV(0);
    __syncthreads();

    short* PsW = &PsS[w][0];
    for (int tt = 0; tt < NT; ++tt) {
        const int cur = tt & 1;
        if (tt + 1 < NT) { loadV(tt + 1); stageK(cur ^ 1, tt + 1); }

        // ---- QK^T -> S (f32), 16 MFMA
        const short* KsB = &KsS[cur][0];
        f32x4 s[2][4] = {};
        #pragma unroll
        for (int kk = 0; kk < 2; ++kk) {
            bf16x8 kb[4];
            #pragma unroll
            for (int n = 0; n < 4; ++n)
                kb[n] = *(const bf16x8*)&KsB[(n * 16 + l15) * 64 +
                                             (((kk * 4 + quad) ^ (l15 & 7)) * 8)];
            #pragma unroll
            for (int m = 0; m < 2; ++m)
                #pragma unroll
                for (int n = 0; n < 4; ++n)
                    s[m][n] = __builtin_amdgcn_mfma_f32_16x16x32_bf16(qf[m][kk], kb[n], s[m][n], 0, 0, 0);
        }

        // ---- online softmax; rows = quad*4+r (+16m), cols = l15 (+16n)
        #pragma unroll
        for (int m = 0; m < 2; ++m) {
            #pragma unroll
            for (int r = 0; r < 4; ++r) {
                float sv[4];
                #pragma unroll
                for (int n = 0; n < 4; ++n) sv[n] = s[m][n][r] * 0.125f;
                float vm = fmaxf(fmaxf(sv[0], sv[1]), fmaxf(sv[2], sv[3]));
                #pragma unroll
                for (int off = 1; off < 16; off <<= 1) vm = fmaxf(vm, __shfl_xor(vm, off));
                const float mn = fmaxf(mrun[m][r], vm);
                const float al = __expf(mrun[m][r] - mn);
                float ps = 0.0f;
                #pragma unroll
                for (int n = 0; n < 4; ++n) { sv[n] = __expf(sv[n] - mn); ps += sv[n]; }
                #pragma unroll
                for (int off = 1; off < 16; off <<= 1) ps += __shfl_xor(ps, off);
                lrun[m][r] = lrun[m][r] * al + ps;
                mrun[m][r] = mn;
                const int qrow = m * 16 + quad * 4 + r;
                #pragma unroll
                for (int n = 0; n < 4; ++n) {
                    PsW[qrow * 72 + n * 16 + l15] = f2bs(sv[n]);
                    o[m][n][r] *= al;
                }
            }
        }

        if (tt + 1 < NT) writeV(cur ^ 1);   // into other buffer; hides under PV

        // ---- PV: O += P * V, 16 MFMA
        const short* VsB = &VsS[cur][0];
        #pragma unroll
        for (int kk = 0; kk < 2; ++kk) {
            bf16x8 pa[2], vb[4];
            #pragma unroll
            for (int m = 0; m < 2; ++m)
                pa[m] = *(const bf16x8*)&PsW[(m * 16 + l15) * 72 + kk * 32 + quad * 8];
            #pragma unroll
            for (int n = 0; n < 4; ++n)
                vb[n] = *(const bf16x8*)&VsB[(n * 16 + l15) * 72 + kk * 32 + quad * 8];
            #pragma unroll
            for (int m = 0; m < 2; ++m)
                #pragma unroll
                for (int n = 0; n < 4; ++n)
                    o[m][n] = __builtin_amdgcn_mfma_f32_16x16x32_bf16(pa[m], vb[n], o[m][n], 0, 0, 0);
        }
        __syncthreads();
    }

    const size_t pbase = ((size_t)(ks * 64 + bh)) * Ud;
    #pragma unroll
    for (int m = 0; m < 2; ++m) {
        #pragma unroll
        for (int r = 0; r < 4; ++r) {
            const int u = w * 32 + m * 16 + quad * 4 + r;
            #pragma unroll
            for (int n = 0; n < 4; ++n)
                pO[(pbase + u) * 64 + n * 16 + l15] = __float2bfloat16(o[m][n][r]);
            if (l15 == 0) { pM[pbase + u] = mrun[m][r]; pL[pbase + u] = lrun[m][r]; }
        }
    }
}

// combine K-split partials -> ctxTop
__global__ void combine_kernel(const bf16* __restrict__ pO, const float* __restrict__ pM,
                               const float* __restrict__ pL, float* __restrict__ ctxTop)
{
    const int u = blockIdx.x & 127, bh = blockIdx.x >> 7, c = threadIdx.x;
    float mstar = -1e30f;
    #pragma unroll
    for (int ks = 0; ks < KSd; ++ks)
        mstar = fmaxf(mstar, pM[(ks * 64 + bh) * Ud + u]);
    float lsum = 0.0f, osum = 0.0f;
    #pragma unroll
    for (int ks = 0; ks < KSd; ++ks) {
        float wgt = __expf(pM[(ks * 64 + bh) * Ud + u] - mstar);
        lsum += pL[(ks * 64 + bh) * Ud + u] * wgt;
        osum += bf2float(pO[(((size_t)ks * 64 + bh) * Ud + u) * 64 + c]) * wgt;
    }
    ctxTop[((size_t)bh * Ud + u) * 64 + c] = scrub(osum / lsum);
}

// ---------------------------------------------------------------- base row: concat(meanV) @ Wo + bo
__launch_bounds__(512)
__global__ void baseout_kernel(const float* __restrict__ meanV, const bf16* __restrict__ Wo,
                               const bf16* __restrict__ bo, float* __restrict__ baseOut)
{
    const int b = blockIdx.x, t = threadIdx.x;
    __shared__ float mv[512];
    mv[t] = meanV[b * 512 + t];
    __syncthreads();
    float acc = bf2float(bo[t]);
    for (int d = 0; d < 512; ++d)
        acc = fmaf(mv[d], bf2float(Wo[(size_t)d * 512 + t]), acc);
    baseOut[b * 512 + t] = acc;
}

// ---------------------------------------------------------------- per-(bh,u) delta rows (bf16 out)
__launch_bounds__(256)
__global__ void delta_kernel(const float* __restrict__ ctxTop, const float* __restrict__ meanV,
                             const bf16* __restrict__ Wo, bf16* __restrict__ deltaOut)
{
    const int u = blockIdx.x, bh = blockIdx.y, h = bh & 7, t = threadIdx.x;
    __shared__ float diff[64];
    if (t < 64) diff[t] = ctxTop[((size_t)bh * Ud + u) * 64 + t] - meanV[bh * 64 + t];
    __syncthreads();
    for (int n = t; n < 512; n += 256) {
        float acc = 0.0f;
        #pragma unroll 8
        for (int dd = 0; dd < 64; ++dd)
            acc = fmaf(diff[dd], bf2float(Wo[(size_t)(h * 64 + dd) * 512 + n]), acc);
        deltaOut[((size_t)bh * Ud + u) * 512 + n] = __float2bfloat16(acc);
    }
}

// ---------------------------------------------------------------- LayerNorms
__launch_bounds__(256)
__global__ void ln1_kernel(const bf16* __restrict__ x, const float* __restrict__ baseOut,
                           const int* __restrict__ rowCnt, const int* __restrict__ rowEnt,
                           const bf16* __restrict__ deltaOut,
                           const bf16* __restrict__ g, const bf16* __restrict__ bb,
                           bf16* __restrict__ x1)
{
    const int row = blockIdx.x, t = threadIdx.x;
    const int b = row >> 12;
    const size_t base = (size_t)row * 512;
    float v0 = bf2float(x[base + t])       + baseOut[b * 512 + t];
    float v1 = bf2float(x[base + t + 256]) + baseOut[b * 512 + t + 256];
    const int cnt = min(rowCnt[row], 8);
    for (int e = 0; e < cnt; ++e) {
        const bf16* dr = &deltaOut[(size_t)rowEnt[row * 8 + e] * 512];
        v0 += bf2float(dr[t]);
        v1 += bf2float(dr[t + 256]);
    }
    v0 = scrub(v0); v1 = scrub(v1);
    float s = v0 + v1, q = v0 * v0 + v1 * v1;
    s = wred_sum(s); q = wred_sum(q);
    __shared__ float sred[4], qred[4];
    int lane = t & 63, w = t >> 6;
    if (lane == 0) { sred[w] = s; qred[w] = q; }
    __syncthreads();
    float tot  = sred[0] + sred[1] + sred[2] + sred[3];
    float totq = qred[0] + qred[1] + qred[2] + qred[3];
    float mean = tot * (1.0f / 512.0f);
    float var  = fmaxf(totq * (1.0f / 512.0f) - mean * mean, 0.0f);
    float rstd = rsqrtf(var + 1e-6f);
    x1[base + t]       = __float2bfloat16((v0 - mean) * rstd * bf2float(g[t])       + bf2float(bb[t]));
    x1[base + t + 256] = __float2bfloat16((v1 - mean) * rstd * bf2float(g[t + 256]) + bf2float(bb[t + 256]));
}

__launch_bounds__(256)
__global__ void ln2_kernel(const bf16* __restrict__ x1, const bf16* __restrict__ ffn,
                           const bf16* __restrict__ g, const bf16* __restrict__ bb,
                           void* __restrict__ out, const int* __restrict__ flags)
{
    const int row = blockIdx.x, t = threadIdx.x;
    const size_t base = (size_t)row * 512;
    float v0 = bf2float(x1[base + t])       + bf2float(ffn[base + t]);
    float v1 = bf2float(x1[base + t + 256]) + bf2float(ffn[base + t + 256]);
    v0 = scrub(v0); v1 = scrub(v1);
    float s = v0 + v1, q = v0 * v0 + v1 * v1;
    s = wred_sum(s); q = wred_sum(q);
    __shared__ float sred[4], qred[4];
    int lane = t & 63, w = t >> 6;
    if (lane == 0) { sred[w] = s; qred[w] = q; }
    __syncthreads();
    float tot  = sred[0] + sred[1] + sred[2] + sred[3];
    float totq = qred[0] + qred[1] + qred[2] + qred[3];
    float mean = tot * (1.0f / 512.0f);
    float var  = fmaxf(totq * (1.0f / 512.0f) - mean * mean, 0.0f);
    float rstd = rsqrtf(var + 1e-6f);
    float o0 = (v0 - mean) * rstd * bf2float(g[t])       + bf2float(bb[t]);
    float o1 = (v1 - mean) * rstd * bf2float(g[t + 256]) + bf2float(bb[t + 256]);
    if (flags[0]) {
        ((float*)out)[base + t]       = o0;
        ((float*)out)[base + t + 256] = o1;
    } else {
        ((bf16*)out)[base + t]       = __float2bfloat16(o0);
        ((bf16*)out)[base + t + 256] = __float2bfloat16(o1);
    }
}

// ================================================================ launcher
extern "C" void kernel_launch(void* const* d_in, const int* in_sizes, int n_in,
                              void* d_out, int out_size, void* d_ws, size_t ws_size,
                              hipStream_t stream)
{
    const void* sraw = d_in[17];

    const size_t NQ = (size_t)MLd * Dd;          // 16,777,216 elements
    char* w = (char*)d_ws;
    size_t off = 0;
    auto alloc = [&](size_t bytes) { void* p = w + off; off += (bytes + 63) & ~size_t(63); return p; };
    bf16*  Qb   = (bf16*)alloc(NQ * 2);                       // 32 MiB
    bf16*  Kb   = (bf16*)alloc(NQ * 2);                       // 32 MiB (contiguous after Qb)
    bf16*  Vb   = (bf16*)alloc(NQ * 2);                       // 32 MiB
    bf16*  xc   = (bf16*)alloc(NQ * 2);                       // 32 MiB
    bf16*  WTq  = (bf16*)alloc(Dd * Dd * 2);
    bf16*  WTk  = (bf16*)alloc(Dd * Dd * 2);
    bf16*  WTv  = (bf16*)alloc(Dd * Dd * 2);
    bf16*  Woc  = (bf16*)alloc(Dd * Dd * 2);                  // untransposed
    bf16*  WT1f = (bf16*)alloc((size_t)Dd * DFFd * 2);        // [2048][512]
    bf16*  WT2f = (bf16*)alloc((size_t)DFFd * Dd * 2);        // [512][2048]
    bf16* bqc = (bf16*)alloc(Dd * 2);
    bf16* bkc = (bf16*)alloc(Dd * 2);
    bf16* bvc = (bf16*)alloc(Dd * 2);
    bf16* boc = (bf16*)alloc(Dd * 2);
    bf16* g1c = (bf16*)alloc(Dd * 2);
    bf16* b1c = (bf16*)alloc(Dd * 2);
    bf16* b1fc= (bf16*)alloc(DFFd * 2);
    bf16* b2fc= (bf16*)alloc(Dd * 2);
    bf16* g2c = (bf16*)alloc(Dd * 2);
    bf16* b2c = (bf16*)alloc(Dd * 2);
    bf16*  pOb     = (bf16*)alloc((size_t)KSd * 64 * Ud * 64 * 2);   // 16 MiB
    float* Mv      = (float*)alloc((size_t)Bd * Hd * Ld * 4);        // 1 MiB
    float* ctxTop  = (float*)alloc((size_t)Bd * Hd * Ud * DHd * 4);  // 2 MiB
    float* meanV   = (float*)alloc(Bd * Hd * DHd * 4);
    float* baseOut = (float*)alloc(Bd * Dd * 4);
    int*   topIdx  = (int*)alloc(Bd * Hd * Ud * 4);
    int*   sidx    = (int*)alloc(128 * 4);
    int*   rowCnt  = (int*)alloc(MLd * 4);
    int*   rowEnt  = (int*)alloc(MLd * 8 * 4);
    int*   flags   = (int*)alloc(64);
    // aliases (lifetimes disjoint, stream-serialized):
    bf16*  x1b  = Vb;                 // ln1 output (V dead)
    bf16*  h1b  = Qb;                 // FFN hidden chunk 16384x2048 spans Qb+Kb (both dead)
    bf16*  ffnb = xc;                 // FFN out (xc dead after ln1)
    bf16*  deltaOut = pOb;            // after combine_kernel, pO dead
    float* pM = Mv;                   // Mv dead after topk
    float* pL = Mv + KSd * 64 * Ud;

    if (off > ws_size) return;

    detect_kernel<<<1, 256, 0, stream>>>(d_in[0], flags);

    auto conv = [&](int i, bf16* dst, int n) {
        conv_kernel<<<(n + 255) / 256, 256, 0, stream>>>(d_in[i], dst, n, flags);
    };
    conv(0,  xc, (int)NQ);
    convT_kernel<<<dim3(Dd / 32, Dd / 32), 256, 0, stream>>>(d_in[1], WTq, Dd, Dd, flags);
    convT_kernel<<<dim3(Dd / 32, Dd / 32), 256, 0, stream>>>(d_in[3], WTk, Dd, Dd, flags);
    convT_kernel<<<dim3(Dd / 32, Dd / 32), 256, 0, stream>>>(d_in[5], WTv, Dd, Dd, flags);
    convT_kernel<<<dim3(DFFd / 32, Dd / 32), 256, 0, stream>>>(d_in[11], WT1f, Dd, DFFd, flags);
    convT_kernel<<<dim3(Dd / 32, DFFd / 32), 256, 0, stream>>>(d_in[13], WT2f, DFFd, Dd, flags);
    conv(7,  Woc, Dd * Dd);
    conv(2,  bqc, Dd);  conv(4,  bkc, Dd);  conv(6,  bvc, Dd);  conv(8,  boc, Dd);
    conv(9,  g1c, Dd);  conv(10, b1c, Dd);
    conv(12, b1fc, DFFd); conv(14, b2fc, Dd);
    conv(15, g2c, Dd);  conv(16, b2c, Dd);

    zero_kernel<<<(MLd + 255) / 256, 256, 0, stream>>>(rowCnt, MLd);
    zero_kernel<<<(Bd * Hd * DHd + 255) / 256, 256, 0, stream>>>((int*)meanV, Bd * Hd * DHd);
    idx_kernel<<<1, 128, 0, stream>>>(sraw, sidx);

    // QKV projections (MFMA, async-staged)
    mfma_gemm<false><<<dim3(4, 256), 256, 0, stream>>>(xc, WTq, bqc, Qb, MLd, Dd, Dd);
    mfma_gemm<false><<<dim3(4, 256), 256, 0, stream>>>(xc, WTk, bkc, Kb, MLd, Dd, Dd);
    mfma_gemm<false><<<dim3(4, 256), 256, 0, stream>>>(xc, WTv, bvc, Vb, MLd, Dd, Dd);

    m_kernel<<<dim3(Ld / 64, Bd * Hd), 256, 0, stream>>>(Qb, Kb, sidx, Mv);
    topk_kernel<<<Bd * Hd, 256, 0, stream>>>(Mv, topIdx);
    rows_kernel<<<Bd * Hd, 128, 0, stream>>>(topIdx, rowCnt, rowEnt);
    meanv_kernel<<<dim3(Bd * Hd, Ld / 64), 256, 0, stream>>>(Vb, meanV);

    attn_kernel<<<dim3(Bd * Hd, KSd), 256, 0, stream>>>(Qb, Kb, Vb, topIdx, pOb, pM, pL);
    combine_kernel<<<Bd * Hd * Ud, 64, 0, stream>>>(pOb, pM, pL, ctxTop);

    baseout_kernel<<<Bd, 512, 0, stream>>>(meanV, Woc, boc, baseOut);
    delta_kernel<<<dim3(Ud, Bd * Hd), 256, 0, stream>>>(ctxTop, meanV, Woc, deltaOut);

    ln1_kernel<<<MLd, 256, 0, stream>>>(xc, baseOut, rowCnt, rowEnt, deltaOut, g1c, b1c, x1b);

    // FFN, chunked over rows (2 chunks of 16384: h1 = 64 MiB spanning Qb+Kb)
    for (int c = 0; c < 2; ++c) {
        mfma_gemm<true ><<<dim3(16, 128), 256, 0, stream>>>(
            x1b + (size_t)c * 16384 * 512, WT1f, b1fc, h1b, 16384, DFFd, Dd);
        mfma_gemm<false><<<dim3(4, 128), 256, 0, stream>>>(
            h1b, WT2f, b2fc, ffnb + (size_t)c * 16384 * 512, 16384, Dd, DFFd);
    }

    ln2_kernel<<<MLd, 256, 0, stream>>>(x1b, ffnb, g2c, b2c, d_out, flags);
}

// Round 4
// 763.028 us; speedup vs baseline: 2.0744x; 1.0662x over previous
//
#include <hip/hip_runtime.h>
#include <hip/hip_bf16.h>

using bf16 = __hip_bfloat16;

constexpr int Bd  = 8;
constexpr int Ld  = 4096;
constexpr int Dd  = 512;
constexpr int Hd  = 8;
constexpr int DHd = 64;
constexpr int DFFd= 2048;
constexpr int Ud  = 128;           // TOP_U
constexpr int MLd = Bd * Ld;       // 32768 rows
constexpr int KSd = 16;            // attention K-split (256 keys per block)

typedef short          bf16x8 __attribute__((ext_vector_type(8)));
typedef unsigned short u16x8  __attribute__((ext_vector_type(8)));
typedef float          f32x4  __attribute__((ext_vector_type(4)));

__device__ __forceinline__ float bf2float(bf16 v) { return __bfloat162float(v); }

__device__ __forceinline__ float wred_sum(float v) {
    #pragma unroll
    for (int o = 32; o > 0; o >>= 1) v += __shfl_xor(v, o);
    return v;
}
__device__ __forceinline__ float wred_max(float v) {
    #pragma unroll
    for (int o = 32; o > 0; o >>= 1) v = fmaxf(v, __shfl_xor(v, o));
    return v;
}
__device__ __forceinline__ float scrub(float v) {       // NaN/Inf -> 0
    return (fabsf(v) < 1e20f) ? v : 0.0f;
}
__device__ __forceinline__ short f2bs(float f) {        // float -> bf16 bits
    bf16 h = __float2bfloat16(f);
    return *reinterpret_cast<short*>(&h);
}

// async global->LDS, 16B per lane; LDS dest = wave-uniform base + lane*16
__device__ __forceinline__ void gload_lds16(const bf16* g, bf16* lds_base) {
    __builtin_amdgcn_global_load_lds((const __attribute__((address_space(1))) void*)g,
                                     (__attribute__((address_space(3))) void*)lds_base,
                                     16, 0, 0);
}

// ---------------------------------------------------------------- dtype detector
__global__ void detect_kernel(const void* xraw, int* flags) {
    const unsigned short* u = (const unsigned short*)xraw;
    __shared__ int cnt;
    if (threadIdx.x == 0) cnt = 0;
    __syncthreads();
    int local = 0;
    for (int i = threadIdx.x; i < 1024; i += 256) {
        int e = (u[2 * i] >> 7) & 0xFF;
        if (e >= 96 && e <= 142) local++;
    }
    atomicAdd(&cnt, local);
    __syncthreads();
    if (threadIdx.x == 0) flags[0] = (cnt < 512) ? 1 : 0;
}

// canonicalize any float tensor to bf16
__global__ void conv_kernel(const void* raw, bf16* dst, int n, const int* flags) {
    int i = blockIdx.x * 256 + threadIdx.x;
    if (i >= n) return;
    if (flags[0]) dst[i] = __float2bfloat16(((const float*)raw)[i]);
    else          dst[i] = ((const bf16*)raw)[i];
}

// canonicalize + transpose weight: in W[K][N] -> out WT[N][K] (bf16)
__global__ void convT_kernel(const void* raw, bf16* dst, int K, int N, const int* flags) {
    __shared__ bf16 tile[32][33];
    const int k0 = blockIdx.y * 32, n0 = blockIdx.x * 32;
    const int tx = threadIdx.x & 31, ty = threadIdx.x >> 5;     // 32 x 8
    #pragma unroll
    for (int p = 0; p < 4; ++p) {
        int k = k0 + ty + p * 8, n = n0 + tx;
        float v = flags[0] ? ((const float*)raw)[(size_t)k * N + n]
                           : bf2float(((const bf16*)raw)[(size_t)k * N + n]);
        tile[ty + p * 8][tx] = __float2bfloat16(v);
    }
    __syncthreads();
    #pragma unroll
    for (int p = 0; p < 4; ++p) {
        int n = n0 + ty + p * 8, k = k0 + tx;
        dst[(size_t)n * K + k] = tile[tx][ty + p * 8];
    }
}

__global__ void zero_kernel(int* p, int n) {
    int i = blockIdx.x * 256 + threadIdx.x;
    if (i < n) p[i] = 0;
}

// sample_idx: int32 or int64 device layout; clamped to [0, Ld)
__global__ void idx_kernel(const void* raw, int* out) {
    const int* r32 = (const int*)raw;
    __shared__ int is64;
    int t = threadIdx.x;                       // 128 threads
    if (t == 0) is64 = 1;
    __syncthreads();
    if (t < 64 && r32[2 * t + 1] != 0) is64 = 0;
    __syncthreads();
    int v = is64 ? r32[2 * t] : r32[t];
    out[t] = min(max(v, 0), Ld - 1);
}

// ---------------------------------------------------------------- MFMA GEMM (m97 recipe)
// C[m,n] = sum_k X[m,k]*WT[n,k] + bias[n]; 128x128 tile, BK=32, 4 waves.
template<bool RELU>
__launch_bounds__(256)
__global__ void mfma_gemm(const bf16* __restrict__ X, const bf16* __restrict__ WT,
                          const bf16* __restrict__ bias, bf16* __restrict__ C,
                          int M, int N, int K)
{
    __shared__ bf16 As[128 * 32];
    __shared__ bf16 Bs[128 * 32];
    const int t = threadIdx.x;
    const int lane = t & 63, wave = t >> 6;
    const int wr = wave >> 1, wc = wave & 1;    // 2x2 wave grid
    const int quad = lane >> 4, l15 = lane & 15;
    const int m0 = blockIdx.y * 128, n0 = blockIdx.x * 128;
    const int lrow = lane >> 2, lcol = (lane & 3) * 8;   // 16 rows x 4x8 cols per wave-load

    f32x4 acc[4][4] = {};

    for (int k0 = 0; k0 < K; k0 += 32) {
        #pragma unroll
        for (int p = 0; p < 2; ++p) {
            int r0 = wave * 16 + p * 64;
            gload_lds16(&X [(size_t)(m0 + r0 + lrow) * K + k0 + lcol], &As[r0 * 32]);
            gload_lds16(&WT[(size_t)(n0 + r0 + lrow) * K + k0 + lcol], &Bs[r0 * 32]);
        }
        __syncthreads();
        bf16x8 a[4], b[4];
        #pragma unroll
        for (int i = 0; i < 4; ++i) {
            a[i] = *(const bf16x8*)&As[(wr * 64 + i * 16 + l15) * 32 + quad * 8];
            b[i] = *(const bf16x8*)&Bs[(wc * 64 + i * 16 + l15) * 32 + quad * 8];
        }
        #pragma unroll
        for (int i = 0; i < 4; ++i)
            #pragma unroll
            for (int j = 0; j < 4; ++j)
                acc[i][j] = __builtin_amdgcn_mfma_f32_16x16x32_bf16(a[i], b[j], acc[i][j], 0, 0, 0);
        __syncthreads();
    }
    // epilogue: D elem (m = quad*4+reg, n = lane&15) within each 16x16 tile
    #pragma unroll
    for (int j = 0; j < 4; ++j) {
        int n = n0 + wc * 64 + j * 16 + l15;
        float bi = bf2float(bias[n]);
        #pragma unroll
        for (int i = 0; i < 4; ++i) {
            #pragma unroll
            for (int r = 0; r < 4; ++r) {
                int m = m0 + wr * 64 + i * 16 + quad * 4 + r;
                float v = acc[i][j][r] + bi;
                if (RELU) v = fmaxf(v, 0.0f);
                C[(size_t)m * N + n] = __float2bfloat16(v);
            }
        }
    }
}

// ---------------------------------------------------------------- M = max-mean of sampled scores (MFMA)
// grid (Ld/128, bh): block = 128 Q-rows x 128 samples, K=64. 4 waves, each a
// 32x128 tile (2 m-tiles x 8 n-tiles, 2 k-steps = 32 MFMA). Q and gathered
// K_samp staged bf16 via gload_lds with the attn stageK XOR-chunk swizzle
// (gather rides the per-lane GLOBAL address; LDS dest stays linear).
// Row max/mean: 8 in-lane cols + 4-step shfl over the 16-lane row group.
__launch_bounds__(256)
__global__ void m_kernel(const bf16* __restrict__ Q, const bf16* __restrict__ Kg,
                         const int* __restrict__ sidx, float* __restrict__ Mv)
{
    __shared__ __align__(16) short Qs[128 * 64];   // [row][d], swizzled, 16 KiB
    __shared__ __align__(16) short Ks[128 * 64];   // [sample][d], swizzled, 16 KiB
    __shared__ int sidxs[128];

    const int t = threadIdx.x, lane = t & 63, w = t >> 6;
    const int l15 = lane & 15, quad = lane >> 4;
    const int l0 = blockIdx.x * 128;
    const int bh = blockIdx.y, b = bh >> 3, h = bh & 7;

    if (t < 128) sidxs[t] = sidx[t];
    __syncthreads();

    const int rseg = lane >> 3;                    // row within 8-row segment
    const int cs   = (lane & 7) ^ rseg;            // pre-swizzled source chunk
    #pragma unroll
    for (int sg4 = 0; sg4 < 4; ++sg4) {
        const int sg = w * 4 + sg4;                // segment 0..15
        const int r  = sg * 8 + rseg;              // row 0..127
        gload_lds16(Q  + ((size_t)(b * Ld + l0 + r))    * Dd + h * 64 + cs * 8,
                    (bf16*)&Qs[sg * 512]);
        gload_lds16(Kg + ((size_t)(b * Ld + sidxs[r])) * Dd + h * 64 + cs * 8,
                    (bf16*)&Ks[sg * 512]);
    }
    __syncthreads();

    f32x4 s[2][8] = {};
    #pragma unroll
    for (int kk = 0; kk < 2; ++kk) {
        const int ch = ((kk * 4 + quad) ^ (l15 & 7)) * 8;
        bf16x8 qa[2], kb[8];
        #pragma unroll
        for (int mt = 0; mt < 2; ++mt)
            qa[mt] = *(const bf16x8*)&Qs[(w * 32 + mt * 16 + l15) * 64 + ch];
        #pragma unroll
        for (int nt = 0; nt < 8; ++nt)
            kb[nt] = *(const bf16x8*)&Ks[(nt * 16 + l15) * 64 + ch];
        #pragma unroll
        for (int mt = 0; mt < 2; ++mt)
            #pragma unroll
            for (int nt = 0; nt < 8; ++nt)
                s[mt][nt] = __builtin_amdgcn_mfma_f32_16x16x32_bf16(qa[mt], kb[nt], s[mt][nt], 0, 0, 0);
    }

    // rows = w*32 + mt*16 + quad*4 + r; cols = nt*16 + l15
    #pragma unroll
    for (int mt = 0; mt < 2; ++mt) {
        #pragma unroll
        for (int r = 0; r < 4; ++r) {
            float vmax = -1e30f, vsum = 0.0f;
            #pragma unroll
            for (int nt = 0; nt < 8; ++nt) {
                float v = s[mt][nt][r];
                vmax = fmaxf(vmax, v); vsum += v;
            }
            #pragma unroll
            for (int off = 1; off < 16; off <<= 1) {
                vmax = fmaxf(vmax, __shfl_xor(vmax, off));
                vsum += __shfl_xor(vsum, off);
            }
            if (l15 == 0) {
                const int row = w * 32 + mt * 16 + quad * 4 + r;
                Mv[(size_t)bh * Ld + l0 + row] = vmax - vsum * (1.0f / 128.0f);
            }
        }
    }
}

// ---------------------------------------------------------------- top-128 via 8-bit radix select
// One block per bh. Exact top-128 SET (order arbitrary; downstream is set/slot
// semantics). 4 byte-plane rounds: LDS histogram -> pivot bin -> emit winners,
// compact ties. ~16 barriers vs bitonic's 78 full-array phases.
__launch_bounds__(256)
__global__ void topk_kernel(const float* __restrict__ Mv, int* __restrict__ topIdx)
{
    __shared__ unsigned ukey[4096];                 // 16 KiB
    __shared__ short listA[4096], listB[4096];      // 16 KiB candidate lists
    __shared__ int hist[256];
    __shared__ int outCnt, candCnt, selB, aboveK;
    const int bh = blockIdx.x, t = threadIdx.x;

    for (int i = t; i < 4096; i += 256) {
        unsigned u = __float_as_uint(Mv[(size_t)bh * Ld + i]);
        ukey[i] = (u & 0x80000000u) ? ~u : (u | 0x80000000u);   // sort-monotonic
    }
    if (t == 0) outCnt = 0;
    __syncthreads();

    int K = Ud;                                     // remaining to select
    #pragma unroll
    for (int r = 0; r < 4; ++r) {
        const int shift = 24 - 8 * r;
        hist[t] = 0;
        __syncthreads();
        const int n = (r == 0) ? 4096 : candCnt;
        const short* cur = (r & 1) ? listB : listA;
        for (int i = t; i < n; i += 256) {
            int idx = (r == 0) ? i : cur[i];
            atomicAdd(&hist[(ukey[idx] >> shift) & 0xFF], 1);
        }
        __syncthreads();
        if (t == 0) {
            int cum = 0, b = 255;
            for (; b > 0; --b) {
                if (cum + hist[b] >= K) break;
                cum += hist[b];
            }
            selB = b; aboveK = cum; candCnt = 0;
        }
        __syncthreads();
        const int sb = selB;
        short* nxt = (r & 1) ? listA : listB;
        for (int i = t; i < n; i += 256) {
            int idx = (r == 0) ? i : cur[i];
            int by = (ukey[idx] >> shift) & 0xFF;
            if (by > sb) {
                int p = atomicAdd(&outCnt, 1);
                topIdx[bh * Ud + p] = idx;
            } else if (by == sb) {
                int p = atomicAdd(&candCnt, 1);
                nxt[p] = (short)idx;
            }
        }
        __syncthreads();
        K -= aboveK;
        if (K == 0) break;
    }
    // leftover K candidates all share an identical 32-bit key: take any K
    if (K > 0) {                                    // final list is listA (r=3 wrote it)
        for (int i = t; i < K; i += 256) {
            int p = atomicAdd(&outCnt, 1);
            topIdx[bh * Ud + p] = listA[i];
        }
    }
}

// ---------------------------------------------------------------- per-row sparse-entry list
__global__ void rows_kernel(const int* __restrict__ topIdx, int* __restrict__ rowCnt,
                            int* __restrict__ rowEnt)
{
    const int bh = blockIdx.x, u = threadIdx.x, b = bh >> 3;
    const int lq = topIdx[bh * Ud + u];
    const int row = b * Ld + lq;
    int slot = atomicAdd(&rowCnt[row], 1) & 7;
    rowEnt[row * 8 + slot] = bh * Ud + u;
}

// ---------------------------------------------------------------- meanV over L per (b,h,d)
// grid (bh=64, chunk=64): 4096 blocks; each reduces 64 rows, atomicAdd partial.
__launch_bounds__(256)
__global__ void meanv_kernel(const bf16* __restrict__ V, float* __restrict__ meanV)
{
    const int bh = blockIdx.x, b = bh >> 3, h = bh & 7;
    const int l0 = blockIdx.y * 64;
    const int t = threadIdx.x;
    const int d = t & 63, part = t >> 6;
    float s = 0.0f;
    #pragma unroll
    for (int p = 0; p < 16; ++p) {
        int l = l0 + part + p * 4;
        s += bf2float(V[((size_t)(b * Ld + l)) * Dd + h * 64 + d]);
    }
    __shared__ float red[256];
    red[t] = s;
    __syncthreads();
    if (t < 64) {
        float tot = red[t] + red[64 + t] + red[128 + t] + red[192 + t];
        atomicAdd(&meanV[bh * 64 + t], tot * (1.0f / 4096.0f));
    }
}

// ---------------------------------------------------------------- MFMA flash attention (K-split partials)
// Grid (bh, ks): each block = all 128 top-U queries x 256 keys (4 kv-tiles of 64).
// QK^T: A = Q frags (regs), B = K rows from LDS (natural [key][d] == B layout).
// K LDS is XOR-swizzled (16B-chunk ^ row&7) with pre-swizzled global_load_lds src.
// Softmax on D-layout acc (row=quad*4+r, col=l15): 4-step shfl over quad group.
// PV: P round-trips per-wave LDS [32][72] (144B rows, conflict-free b128);
// V reg-staged transposed into [d][key] stride-72 so B reads are contiguous.
__launch_bounds__(256, 3)
__global__ void attn_kernel(const bf16* __restrict__ Qg, const bf16* __restrict__ Kg,
                            const bf16* __restrict__ Vg, const int* __restrict__ topIdx,
                            bf16* __restrict__ pO, float* __restrict__ pM, float* __restrict__ pL)
{
    __shared__ __align__(16) short KsS[2][64 * 64];   // [key][d], swizzled, 16 KiB
    __shared__ __align__(16) short VsS[2][64 * 72];   // [d][key], padded, 18 KiB
    __shared__ __align__(16) short PsS[4][32 * 72];   // per-wave [q][key], 18 KiB

    const int t = threadIdx.x, lane = t & 63, w = t >> 6;
    const int l15 = lane & 15, quad = lane >> 4;
    const int bh = blockIdx.x, ks = blockIdx.y;
    const int b = bh >> 3, h = bh & 7;
    const int key0 = ks * (Ld / KSd);
    constexpr int NT = (Ld / KSd) / 64;               // 4 kv-tiles

    // Q fragments (A operand): row = l15 (+16m), k = quad*8 within 32-wide kk step
    bf16x8 qf[2][2];
    #pragma unroll
    for (int m = 0; m < 2; ++m) {
        const int u  = w * 32 + m * 16 + l15;
        const int lq = topIdx[bh * Ud + u];
        const bf16* qr = Qg + ((size_t)(b * Ld + lq)) * Dd + h * 64;
        qf[m][0] = *(const bf16x8*)(qr + quad * 8);
        qf[m][1] = *(const bf16x8*)(qr + 32 + quad * 8);
    }

    const int vkey = t >> 2, vd0 = (t & 3) * 16;
    u16x8 vr0, vr1;

    auto loadV = [&](int tt) {   // V tile -> regs (issued early, coalesced 16B)
        const bf16* vs = Vg + ((size_t)(b * Ld + key0 + tt * 64 + vkey)) * Dd + h * 64 + vd0;
        vr0 = *(const u16x8*)vs;
        vr1 = *(const u16x8*)(vs + 8);
    };
    auto stageK = [&](int buf, int tt) {  // K tile -> LDS via gload_lds, src pre-swizzled
        const int kb0 = key0 + tt * 64;
        #pragma unroll
        for (int sz = 0; sz < 2; ++sz) {
            const int sg = w * 2 + sz;                  // 8-row segment
            const int r  = sg * 8 + (lane >> 3);
            const int cs = (lane & 7) ^ (lane >> 3);    // inverse swizzle on source
            gload_lds16(Kg + ((size_t)(b * Ld + kb0 + r)) * Dd + h * 64 + cs * 8,
                        (bf16*)&KsS[buf][sg * 512]);
        }
    };
    auto writeV = [&](int buf) {  // regs -> transposed LDS
        #pragma unroll
        for (int j = 0; j < 8; ++j) {
            VsS[buf][(vd0 + j) * 72 + vkey]     = (short)vr0[j];
            VsS[buf][(vd0 + 8 + j) * 72 + vkey] = (short)vr1[j];
        }
    };

    float mrun[2][4], lrun[2][4];
    f32x4 o[2][4] = {};
    #pragma unroll
    for (int m = 0; m < 2; ++m)
        #pragma unroll
        for (int r = 0; r < 4; ++r) { mrun[m][r] = -1e30f; lrun[m][r] = 0.0f; }

    loadV(0); stageK(0, 0); writeV(0);
    __syncthreads();

    short* PsW = &PsS[w][0];
    for (int tt = 0; tt < NT; ++tt) {
        const int cur = tt & 1;
        if (tt + 1 < NT) { loadV(tt + 1); stageK(cur ^ 1, tt + 1); }

        // ---- QK^T -> S (f32), 16 MFMA
        const short* KsB = &KsS[cur][0];
        f32x4 s[2][4] = {};
        #pragma unroll
        for (int kk = 0; kk < 2; ++kk) {
            bf16x8 kb[4];
            #pragma unroll
            for (int n = 0; n < 4; ++n)
                kb[n] = *(const bf16x8*)&KsB[(n * 16 + l15) * 64 +
                                             (((kk * 4 + quad) ^ (l15 & 7)) * 8)];
            #pragma unroll
            for (int m = 0; m < 2; ++m)
                #pragma unroll
                for (int n = 0; n < 4; ++n)
                    s[m][n] = __builtin_amdgcn_mfma_f32_16x16x32_bf16(qf[m][kk], kb[n], s[m][n], 0, 0, 0);
        }

        // ---- online softmax; rows = quad*4+r (+16m), cols = l15 (+16n)
        #pragma unroll
        for (int m = 0; m < 2; ++m) {
            #pragma unroll
            for (int r = 0; r < 4; ++r) {
                float sv[4];
                #pragma unroll
                for (int n = 0; n < 4; ++n) sv[n] = s[m][n][r] * 0.125f;
                float vm = fmaxf(fmaxf(sv[0], sv[1]), fmaxf(sv[2], sv[3]));
                #pragma unroll
                for (int off = 1; off < 16; off <<= 1) vm = fmaxf(vm, __shfl_xor(vm, off));
                const float mn = fmaxf(mrun[m][r], vm);
                const float al = __expf(mrun[m][r] - mn);
                float ps = 0.0f;
                #pragma unroll
                for (int n = 0; n < 4; ++n) { sv[n] = __expf(sv[n] - mn); ps += sv[n]; }
                #pragma unroll
                for (int off = 1; off < 16; off <<= 1) ps += __shfl_xor(ps, off);
                lrun[m][r] = lrun[m][r] * al + ps;
                mrun[m][r] = mn;
                const int qrow = m * 16 + quad * 4 + r;
                #pragma unroll
                for (int n = 0; n < 4; ++n) {
                    PsW[qrow * 72 + n * 16 + l15] = f2bs(sv[n]);
                    o[m][n][r] *= al;
                }
            }
        }

        if (tt + 1 < NT) writeV(cur ^ 1);   // into other buffer; hides under PV

        // ---- PV: O += P * V, 16 MFMA
        const short* VsB = &VsS[cur][0];
        #pragma unroll
        for (int kk = 0; kk < 2; ++kk) {
            bf16x8 pa[2], vb[4];
            #pragma unroll
            for (int m = 0; m < 2; ++m)
                pa[m] = *(const bf16x8*)&PsW[(m * 16 + l15) * 72 + kk * 32 + quad * 8];
            #pragma unroll
            for (int n = 0; n < 4; ++n)
                vb[n] = *(const bf16x8*)&VsB[(n * 16 + l15) * 72 + kk * 32 + quad * 8];
            #pragma unroll
            for (int m = 0; m < 2; ++m)
                #pragma unroll
                for (int n = 0; n < 4; ++n)
                    o[m][n] = __builtin_amdgcn_mfma_f32_16x16x32_bf16(pa[m], vb[n], o[m][n], 0, 0, 0);
        }
        __syncthreads();
    }

    const size_t pbase = ((size_t)(ks * 64 + bh)) * Ud;
    #pragma unroll
    for (int m = 0; m < 2; ++m) {
        #pragma unroll
        for (int r = 0; r < 4; ++r) {
            const int u = w * 32 + m * 16 + quad * 4 + r;
            #pragma unroll
            for (int n = 0; n < 4; ++n)
                pO[(pbase + u) * 64 + n * 16 + l15] = __float2bfloat16(o[m][n][r]);
            if (l15 == 0) { pM[pbase + u] = mrun[m][r]; pL[pbase + u] = lrun[m][r]; }
        }
    }
}

// combine K-split partials -> ctxTop
__global__ void combine_kernel(const bf16* __restrict__ pO, const float* __restrict__ pM,
                               const float* __restrict__ pL, float* __restrict__ ctxTop)
{
    const int u = blockIdx.x & 127, bh = blockIdx.x >> 7, c = threadIdx.x;
    float mstar = -1e30f;
    #pragma unroll
    for (int ks = 0; ks < KSd; ++ks)
        mstar = fmaxf(mstar, pM[(ks * 64 + bh) * Ud + u]);
    float lsum = 0.0f, osum = 0.0f;
    #pragma unroll
    for (int ks = 0; ks < KSd; ++ks) {
        float wgt = __expf(pM[(ks * 64 + bh) * Ud + u] - mstar);
        lsum += pL[(ks * 64 + bh) * Ud + u] * wgt;
        osum += bf2float(pO[(((size_t)ks * 64 + bh) * Ud + u) * 64 + c]) * wgt;
    }
    ctxTop[((size_t)bh * Ud + u) * 64 + c] = scrub(osum / lsum);
}

// ---------------------------------------------------------------- base row: concat(meanV) @ Wo + bo
__launch_bounds__(512)
__global__ void baseout_kernel(const float* __restrict__ meanV, const bf16* __restrict__ Wo,
                               const bf16* __restrict__ bo, float* __restrict__ baseOut)
{
    const int b = blockIdx.x, t = threadIdx.x;
    __shared__ float mv[512];
    mv[t] = meanV[b * 512 + t];
    __syncthreads();
    float acc = bf2float(bo[t]);
    for (int d = 0; d < 512; ++d)
        acc = fmaf(mv[d], bf2float(Wo[(size_t)d * 512 + t]), acc);
    baseOut[b * 512 + t] = acc;
}

// ---------------------------------------------------------------- per-(bh,u) delta rows (bf16 out)
__launch_bounds__(256)
__global__ void delta_kernel(const float* __restrict__ ctxTop, const float* __restrict__ meanV,
                             const bf16* __restrict__ Wo, bf16* __restrict__ deltaOut)
{
    const int u = blockIdx.x, bh = blockIdx.y, h = bh & 7, t = threadIdx.x;
    __shared__ float diff[64];
    if (t < 64) diff[t] = ctxTop[((size_t)bh * Ud + u) * 64 + t] - meanV[bh * 64 + t];
    __syncthreads();
    for (int n = t; n < 512; n += 256) {
        float acc = 0.0f;
        #pragma unroll 8
        for (int dd = 0; dd < 64; ++dd)
            acc = fmaf(diff[dd], bf2float(Wo[(size_t)(h * 64 + dd) * 512 + n]), acc);
        deltaOut[((size_t)bh * Ud + u) * 512 + n] = __float2bfloat16(acc);
    }
}

// ---------------------------------------------------------------- LayerNorms
__launch_bounds__(256)
__global__ void ln1_kernel(const bf16* __restrict__ x, const float* __restrict__ baseOut,
                           const int* __restrict__ rowCnt, const int* __restrict__ rowEnt,
                           const bf16* __restrict__ deltaOut,
                           const bf16* __restrict__ g, const bf16* __restrict__ bb,
                           bf16* __restrict__ x1)
{
    const int row = blockIdx.x, t = threadIdx.x;
    const int b = row >> 12;
    const size_t base = (size_t)row * 512;
    float v0 = bf2float(x[base + t])       + baseOut[b * 512 + t];
    float v1 = bf2float(x[base + t + 256]) + baseOut[b * 512 + t + 256];
    const int cnt = min(rowCnt[row], 8);
    for (int e = 0; e < cnt; ++e) {
        const bf16* dr = &deltaOut[(size_t)rowEnt[row * 8 + e] * 512];
        v0 += bf2float(dr[t]);
        v1 += bf2float(dr[t + 256]);
    }
    v0 = scrub(v0); v1 = scrub(v1);
    float s = v0 + v1, q = v0 * v0 + v1 * v1;
    s = wred_sum(s); q = wred_sum(q);
    __shared__ float sred[4], qred[4];
    int lane = t & 63, w = t >> 6;
    if (lane == 0) { sred[w] = s; qred[w] = q; }
    __syncthreads();
    float tot  = sred[0] + sred[1] + sred[2] + sred[3];
    float totq = qred[0] + qred[1] + qred[2] + qred[3];
    float mean = tot * (1.0f / 512.0f);
    float var  = fmaxf(totq * (1.0f / 512.0f) - mean * mean, 0.0f);
    float rstd = rsqrtf(var + 1e-6f);
    x1[base + t]       = __float2bfloat16((v0 - mean) * rstd * bf2float(g[t])       + bf2float(bb[t]));
    x1[base + t + 256] = __float2bfloat16((v1 - mean) * rstd * bf2float(g[t + 256]) + bf2float(bb[t + 256]));
}

__launch_bounds__(256)
__global__ void ln2_kernel(const bf16* __restrict__ x1, const bf16* __restrict__ ffn,
                           const bf16* __restrict__ g, const bf16* __restrict__ bb,
                           void* __restrict__ out, const int* __restrict__ flags)
{
    const int row = blockIdx.x, t = threadIdx.x;
    const size_t base = (size_t)row * 512;
    float v0 = bf2float(x1[base + t])       + bf2float(ffn[base + t]);
    float v1 = bf2float(x1[base + t + 256]) + bf2float(ffn[base + t + 256]);
    v0 = scrub(v0); v1 = scrub(v1);
    float s = v0 + v1, q = v0 * v0 + v1 * v1;
    s = wred_sum(s); q = wred_sum(q);
    __shared__ float sred[4], qred[4];
    int lane = t & 63, w = t >> 6;
    if (lane == 0) { sred[w] = s; qred[w] = q; }
    __syncthreads();
    float tot  = sred[0] + sred[1] + sred[2] + sred[3];
    float totq = qred[0] + qred[1] + qred[2] + qred[3];
    float mean = tot * (1.0f / 512.0f);
    float var  = fmaxf(totq * (1.0f / 512.0f) - mean * mean, 0.0f);
    float rstd = rsqrtf(var + 1e-6f);
    float o0 = (v0 - mean) * rstd * bf2float(g[t])       + bf2float(bb[t]);
    float o1 = (v1 - mean) * rstd * bf2float(g[t + 256]) + bf2float(bb[t + 256]);
    if (flags[0]) {
        ((float*)out)[base + t]       = o0;
        ((float*)out)[base + t + 256] = o1;
    } else {
        ((bf16*)out)[base + t]       = __float2bfloat16(o0);
        ((bf16*)out)[base + t + 256] = __float2bfloat16(o1);
    }
}

// ================================================================ launcher
extern "C" void kernel_launch(void* const* d_in, const int* in_sizes, int n_in,
                              void* d_out, int out_size, void* d_ws, size_t ws_size,
                              hipStream_t stream)
{
    const void* sraw = d_in[17];

    const size_t NQ = (size_t)MLd * Dd;          // 16,777,216 elements
    char* w = (char*)d_ws;
    size_t off = 0;
    auto alloc = [&](size_t bytes) { void* p = w + off; off += (bytes + 63) & ~size_t(63); return p; };
    bf16*  Qb   = (bf16*)alloc(NQ * 2);                       // 32 MiB
    bf16*  Kb   = (bf16*)alloc(NQ * 2);                       // 32 MiB (contiguous after Qb)
    bf16*  Vb   = (bf16*)alloc(NQ * 2);                       // 32 MiB
    bf16*  xc   = (bf16*)alloc(NQ * 2);                       // 32 MiB
    bf16*  WTq  = (bf16*)alloc(Dd * Dd * 2);
    bf16*  WTk  = (bf16*)alloc(Dd * Dd * 2);
    bf16*  WTv  = (bf16*)alloc(Dd * Dd * 2);
    bf16*  Woc  = (bf16*)alloc(Dd * Dd * 2);                  // untransposed
    bf16*  WT1f = (bf16*)alloc((size_t)Dd * DFFd * 2);        // [2048][512]
    bf16*  WT2f = (bf16*)alloc((size_t)DFFd * Dd * 2);        // [512][2048]
    bf16* bqc = (bf16*)alloc(Dd * 2);
    bf16* bkc = (bf16*)alloc(Dd * 2);
    bf16* bvc = (bf16*)alloc(Dd * 2);
    bf16* boc = (bf16*)alloc(Dd * 2);
    bf16* g1c = (bf16*)alloc(Dd * 2);
    bf16* b1c = (bf16*)alloc(Dd * 2);
    bf16* b1fc= (bf16*)alloc(DFFd * 2);
    bf16* b2fc= (bf16*)alloc(Dd * 2);
    bf16* g2c = (bf16*)alloc(Dd * 2);
    bf16* b2c = (bf16*)alloc(Dd * 2);
    bf16*  pOb     = (bf16*)alloc((size_t)KSd * 64 * Ud * 64 * 2);   // 16 MiB
    float* Mv      = (float*)alloc((size_t)Bd * Hd * Ld * 4);        // 1 MiB
    float* ctxTop  = (float*)alloc((size_t)Bd * Hd * Ud * DHd * 4);  // 2 MiB
    float* meanV   = (float*)alloc(Bd * Hd * DHd * 4);
    float* baseOut = (float*)alloc(Bd * Dd * 4);
    int*   topIdx  = (int*)alloc(Bd * Hd * Ud * 4);
    int*   sidx    = (int*)alloc(128 * 4);
    int*   rowCnt  = (int*)alloc(MLd * 4);
    int*   rowEnt  = (int*)alloc(MLd * 8 * 4);
    int*   flags   = (int*)alloc(64);
    // aliases (lifetimes disjoint, stream-serialized):
    bf16*  x1b  = Vb;                 // ln1 output (V dead)
    bf16*  h1b  = Qb;                 // FFN hidden chunk 16384x2048 spans Qb+Kb (both dead)
    bf16*  ffnb = xc;                 // FFN out (xc dead after ln1)
    bf16*  deltaOut = pOb;            // after combine_kernel, pO dead
    float* pM = Mv;                   // Mv dead after topk
    float* pL = Mv + KSd * 64 * Ud;

    if (off > ws_size) return;

    detect_kernel<<<1, 256, 0, stream>>>(d_in[0], flags);

    auto conv = [&](int i, bf16* dst, int n) {
        conv_kernel<<<(n + 255) / 256, 256, 0, stream>>>(d_in[i], dst, n, flags);
    };
    conv(0,  xc, (int)NQ);
    convT_kernel<<<dim3(Dd / 32, Dd / 32), 256, 0, stream>>>(d_in[1], WTq, Dd, Dd, flags);
    convT_kernel<<<dim3(Dd / 32, Dd / 32), 256, 0, stream>>>(d_in[3], WTk, Dd, Dd, flags);
    convT_kernel<<<dim3(Dd / 32, Dd / 32), 256, 0, stream>>>(d_in[5], WTv, Dd, Dd, flags);
    convT_kernel<<<dim3(DFFd / 32, Dd / 32), 256, 0, stream>>>(d_in[11], WT1f, Dd, DFFd, flags);
    convT_kernel<<<dim3(Dd / 32, DFFd / 32), 256, 0, stream>>>(d_in[13], WT2f, DFFd, Dd, flags);
    conv(7,  Woc, Dd * Dd);
    conv(2,  bqc, Dd);  conv(4,  bkc, Dd);  conv(6,  bvc, Dd);  conv(8,  boc, Dd);
    conv(9,  g1c, Dd);  conv(10, b1c, Dd);
    conv(12, b1fc, DFFd); conv(14, b2fc, Dd);
    conv(15, g2c, Dd);  conv(16, b2c, Dd);

    zero_kernel<<<(MLd + 255) / 256, 256, 0, stream>>>(rowCnt, MLd);
    zero_kernel<<<(Bd * Hd * DHd + 255) / 256, 256, 0, stream>>>((int*)meanV, Bd * Hd * DHd);
    idx_kernel<<<1, 128, 0, stream>>>(sraw, sidx);

    // QKV projections (MFMA, async-staged)
    mfma_gemm<false><<<dim3(4, 256), 256, 0, stream>>>(xc, WTq, bqc, Qb, MLd, Dd, Dd);
    mfma_gemm<false><<<dim3(4, 256), 256, 0, stream>>>(xc, WTk, bkc, Kb, MLd, Dd, Dd);
    mfma_gemm<false><<<dim3(4, 256), 256, 0, stream>>>(xc, WTv, bvc, Vb, MLd, Dd, Dd);

    m_kernel<<<dim3(Ld / 128, Bd * Hd), 256, 0, stream>>>(Qb, Kb, sidx, Mv);
    topk_kernel<<<Bd * Hd, 256, 0, stream>>>(Mv, topIdx);
    rows_kernel<<<Bd * Hd, 128, 0, stream>>>(topIdx, rowCnt, rowEnt);
    meanv_kernel<<<dim3(Bd * Hd, Ld / 64), 256, 0, stream>>>(Vb, meanV);

    attn_kernel<<<dim3(Bd * Hd, KSd), 256, 0, stream>>>(Qb, Kb, Vb, topIdx, pOb, pM, pL);
    combine_kernel<<<Bd * Hd * Ud, 64, 0, stream>>>(pOb, pM, pL, ctxTop);

    baseout_kernel<<<Bd, 512, 0, stream>>>(meanV, Woc, boc, baseOut);
    delta_kernel<<<dim3(Ud, Bd * Hd), 256, 0, stream>>>(ctxTop, meanV, Woc, deltaOut);

    ln1_kernel<<<MLd, 256, 0, stream>>>(xc, baseOut, rowCnt, rowEnt, deltaOut, g1c, b1c, x1b);

    // FFN, chunked over rows (2 chunks of 16384: h1 = 64 MiB spanning Qb+Kb)
    for (int c = 0; c < 2; ++c) {
        mfma_gemm<true ><<<dim3(16, 128), 256, 0, stream>>>(
            x1b + (size_t)c * 16384 * 512, WT1f, b1fc, h1b, 16384, DFFd, Dd);
        mfma_gemm<false><<<dim3(4, 128), 256, 0, stream>>>(
            h1b, WT2f, b2fc, ffnb + (size_t)c * 16384 * 512, 16384, Dd, DFFd);
    }

    ln2_kernel<<<MLd, 256, 0, stream>>>(x1b, ffnb, g2c, b2c, d_out, flags);
}

// Round 5
// 736.474 us; speedup vs baseline: 2.1492x; 1.0361x over previous
//
#include <hip/hip_runtime.h>
#include <hip/hip_bf16.h>

using bf16 = __hip_bfloat16;

constexpr int Bd  = 8;
constexpr int Ld  = 4096;
constexpr int Dd  = 512;
constexpr int Hd  = 8;
constexpr int DHd = 64;
constexpr int DFFd= 2048;
constexpr int Ud  = 128;           // TOP_U
constexpr int MLd = Bd * Ld;       // 32768 rows
constexpr int KSd = 16;            // attention K-split (256 keys per block)

typedef short          bf16x8 __attribute__((ext_vector_type(8)));
typedef unsigned short u16x8  __attribute__((ext_vector_type(8)));
typedef float          f32x4  __attribute__((ext_vector_type(4)));

__device__ __forceinline__ float bf2float(bf16 v) { return __bfloat162float(v); }

__device__ __forceinline__ float wred_sum(float v) {
    #pragma unroll
    for (int o = 32; o > 0; o >>= 1) v += __shfl_xor(v, o);
    return v;
}
__device__ __forceinline__ float wred_max(float v) {
    #pragma unroll
    for (int o = 32; o > 0; o >>= 1) v = fmaxf(v, __shfl_xor(v, o));
    return v;
}
__device__ __forceinline__ float scrub(float v) {       // NaN/Inf -> 0
    return (fabsf(v) < 1e20f) ? v : 0.0f;
}
__device__ __forceinline__ short f2bs(float f) {        // float -> bf16 bits
    bf16 h = __float2bfloat16(f);
    return *reinterpret_cast<short*>(&h);
}

// async global->LDS, 16B per lane; LDS dest = wave-uniform base + lane*16
__device__ __forceinline__ void gload_lds16(const bf16* g, bf16* lds_base) {
    __builtin_amdgcn_global_load_lds((const __attribute__((address_space(1))) void*)g,
                                     (__attribute__((address_space(3))) void*)lds_base,
                                     16, 0, 0);
}

// ---------------------------------------------------------------- dtype detector
__global__ void detect_kernel(const void* xraw, int* flags) {
    const unsigned short* u = (const unsigned short*)xraw;
    __shared__ int cnt;
    if (threadIdx.x == 0) cnt = 0;
    __syncthreads();
    int local = 0;
    for (int i = threadIdx.x; i < 1024; i += 256) {
        int e = (u[2 * i] >> 7) & 0xFF;
        if (e >= 96 && e <= 142) local++;
    }
    atomicAdd(&cnt, local);
    __syncthreads();
    if (threadIdx.x == 0) flags[0] = (cnt < 512) ? 1 : 0;
}

// canonicalize any float tensor to bf16
__global__ void conv_kernel(const void* raw, bf16* dst, int n, const int* flags) {
    int i = blockIdx.x * 256 + threadIdx.x;
    if (i >= n) return;
    if (flags[0]) dst[i] = __float2bfloat16(((const float*)raw)[i]);
    else          dst[i] = ((const bf16*)raw)[i];
}

// canonicalize + transpose weight: in W[K][N] -> out WT[N][K] (bf16)
__global__ void convT_kernel(const void* raw, bf16* dst, int K, int N, const int* flags) {
    __shared__ bf16 tile[32][33];
    const int k0 = blockIdx.y * 32, n0 = blockIdx.x * 32;
    const int tx = threadIdx.x & 31, ty = threadIdx.x >> 5;     // 32 x 8
    #pragma unroll
    for (int p = 0; p < 4; ++p) {
        int k = k0 + ty + p * 8, n = n0 + tx;
        float v = flags[0] ? ((const float*)raw)[(size_t)k * N + n]
                           : bf2float(((const bf16*)raw)[(size_t)k * N + n]);
        tile[ty + p * 8][tx] = __float2bfloat16(v);
    }
    __syncthreads();
    #pragma unroll
    for (int p = 0; p < 4; ++p) {
        int n = n0 + ty + p * 8, k = k0 + tx;
        dst[(size_t)n * K + k] = tile[tx][ty + p * 8];
    }
}

__global__ void zero_kernel(int* p, int n) {
    int i = blockIdx.x * 256 + threadIdx.x;
    if (i < n) p[i] = 0;
}

// sample_idx: int32 or int64 device layout; clamped to [0, Ld)
__global__ void idx_kernel(const void* raw, int* out) {
    const int* r32 = (const int*)raw;
    __shared__ int is64;
    int t = threadIdx.x;                       // 128 threads
    if (t == 0) is64 = 1;
    __syncthreads();
    if (t < 64 && r32[2 * t + 1] != 0) is64 = 0;
    __syncthreads();
    int v = is64 ? r32[2 * t] : r32[t];
    out[t] = min(max(v, 0), Ld - 1);
}

// ---------------------------------------------------------------- MFMA GEMM (m97 recipe)
// C[m,n] = sum_k X[m,k]*WT[n,k] + bias[n]; 128x128 tile, BK=32, 4 waves.
// XCD-aware bijective block swizzle (T1): each XCD gets a contiguous logical
// tile range so n-blocks sharing an X row-panel hit the same L2.
template<bool RELU>
__launch_bounds__(256)
__global__ void mfma_gemm(const bf16* __restrict__ X, const bf16* __restrict__ WT,
                          const bf16* __restrict__ bias, bf16* __restrict__ C,
                          int M, int N, int K)
{
    __shared__ bf16 As[128 * 32];
    __shared__ bf16 Bs[128 * 32];
    const int t = threadIdx.x;
    const int lane = t & 63, wave = t >> 6;
    const int wr = wave >> 1, wc = wave & 1;    // 2x2 wave grid
    const int quad = lane >> 4, l15 = lane & 15;

    const int nwg = gridDim.x * gridDim.y;
    int wg = blockIdx.y * gridDim.x + blockIdx.x;
    if ((nwg & 7) == 0)                          // bijective chunked XCD swizzle
        wg = (wg & 7) * (nwg >> 3) + (wg >> 3);
    const int m0 = (wg / gridDim.x) * 128, n0 = (wg % gridDim.x) * 128;

    const int lrow = lane >> 2, lcol = (lane & 3) * 8;   // 16 rows x 4x8 cols per wave-load

    f32x4 acc[4][4] = {};

    for (int k0 = 0; k0 < K; k0 += 32) {
        #pragma unroll
        for (int p = 0; p < 2; ++p) {
            int r0 = wave * 16 + p * 64;
            gload_lds16(&X [(size_t)(m0 + r0 + lrow) * K + k0 + lcol], &As[r0 * 32]);
            gload_lds16(&WT[(size_t)(n0 + r0 + lrow) * K + k0 + lcol], &Bs[r0 * 32]);
        }
        __syncthreads();
        bf16x8 a[4], b[4];
        #pragma unroll
        for (int i = 0; i < 4; ++i) {
            a[i] = *(const bf16x8*)&As[(wr * 64 + i * 16 + l15) * 32 + quad * 8];
            b[i] = *(const bf16x8*)&Bs[(wc * 64 + i * 16 + l15) * 32 + quad * 8];
        }
        #pragma unroll
        for (int i = 0; i < 4; ++i)
            #pragma unroll
            for (int j = 0; j < 4; ++j)
                acc[i][j] = __builtin_amdgcn_mfma_f32_16x16x32_bf16(a[i], b[j], acc[i][j], 0, 0, 0);
        __syncthreads();
    }
    // epilogue: D elem (m = quad*4+reg, n = lane&15) within each 16x16 tile
    #pragma unroll
    for (int j = 0; j < 4; ++j) {
        int n = n0 + wc * 64 + j * 16 + l15;
        float bi = bf2float(bias[n]);
        #pragma unroll
        for (int i = 0; i < 4; ++i) {
            #pragma unroll
            for (int r = 0; r < 4; ++r) {
                int m = m0 + wr * 64 + i * 16 + quad * 4 + r;
                float v = acc[i][j][r] + bi;
                if (RELU) v = fmaxf(v, 0.0f);
                C[(size_t)m * N + n] = __float2bfloat16(v);
            }
        }
    }
}

// ---------------------------------------------------------------- M = max-mean of sampled scores (MFMA)
// grid (Ld/128, bh): block = 128 Q-rows x 128 samples, K=64. 4 waves, each a
// 32x128 tile (2 m-tiles x 8 n-tiles, 2 k-steps = 32 MFMA).
__launch_bounds__(256)
__global__ void m_kernel(const bf16* __restrict__ Q, const bf16* __restrict__ Kg,
                         const int* __restrict__ sidx, float* __restrict__ Mv)
{
    __shared__ __align__(16) short Qs[128 * 64];   // [row][d], swizzled, 16 KiB
    __shared__ __align__(16) short Ks[128 * 64];   // [sample][d], swizzled, 16 KiB
    __shared__ int sidxs[128];

    const int t = threadIdx.x, lane = t & 63, w = t >> 6;
    const int l15 = lane & 15, quad = lane >> 4;
    const int l0 = blockIdx.x * 128;
    const int bh = blockIdx.y, b = bh >> 3, h = bh & 7;

    if (t < 128) sidxs[t] = sidx[t];
    __syncthreads();

    const int rseg = lane >> 3;                    // row within 8-row segment
    const int cs   = (lane & 7) ^ rseg;            // pre-swizzled source chunk
    #pragma unroll
    for (int sg4 = 0; sg4 < 4; ++sg4) {
        const int sg = w * 4 + sg4;                // segment 0..15
        const int r  = sg * 8 + rseg;              // row 0..127
        gload_lds16(Q  + ((size_t)(b * Ld + l0 + r))    * Dd + h * 64 + cs * 8,
                    (bf16*)&Qs[sg * 512]);
        gload_lds16(Kg + ((size_t)(b * Ld + sidxs[r])) * Dd + h * 64 + cs * 8,
                    (bf16*)&Ks[sg * 512]);
    }
    __syncthreads();

    f32x4 s[2][8] = {};
    #pragma unroll
    for (int kk = 0; kk < 2; ++kk) {
        const int ch = ((kk * 4 + quad) ^ (l15 & 7)) * 8;
        bf16x8 qa[2], kb[8];
        #pragma unroll
        for (int mt = 0; mt < 2; ++mt)
            qa[mt] = *(const bf16x8*)&Qs[(w * 32 + mt * 16 + l15) * 64 + ch];
        #pragma unroll
        for (int nt = 0; nt < 8; ++nt)
            kb[nt] = *(const bf16x8*)&Ks[(nt * 16 + l15) * 64 + ch];
        #pragma unroll
        for (int mt = 0; mt < 2; ++mt)
            #pragma unroll
            for (int nt = 0; nt < 8; ++nt)
                s[mt][nt] = __builtin_amdgcn_mfma_f32_16x16x32_bf16(qa[mt], kb[nt], s[mt][nt], 0, 0, 0);
    }

    // rows = w*32 + mt*16 + quad*4 + r; cols = nt*16 + l15
    #pragma unroll
    for (int mt = 0; mt < 2; ++mt) {
        #pragma unroll
        for (int r = 0; r < 4; ++r) {
            float vmax = -1e30f, vsum = 0.0f;
            #pragma unroll
            for (int nt = 0; nt < 8; ++nt) {
                float v = s[mt][nt][r];
                vmax = fmaxf(vmax, v); vsum += v;
            }
            #pragma unroll
            for (int off = 1; off < 16; off <<= 1) {
                vmax = fmaxf(vmax, __shfl_xor(vmax, off));
                vsum += __shfl_xor(vsum, off);
            }
            if (l15 == 0) {
                const int row = w * 32 + mt * 16 + quad * 4 + r;
                Mv[(size_t)bh * Ld + l0 + row] = vmax - vsum * (1.0f / 128.0f);
            }
        }
    }
}

// ---------------------------------------------------------------- top-128 via 8-bit radix select
__launch_bounds__(256)
__global__ void topk_kernel(const float* __restrict__ Mv, int* __restrict__ topIdx)
{
    __shared__ unsigned ukey[4096];                 // 16 KiB
    __shared__ short listA[4096], listB[4096];      // 16 KiB candidate lists
    __shared__ int hist[256];
    __shared__ int outCnt, candCnt, selB, aboveK;
    const int bh = blockIdx.x, t = threadIdx.x;

    for (int i = t; i < 4096; i += 256) {
        unsigned u = __float_as_uint(Mv[(size_t)bh * Ld + i]);
        ukey[i] = (u & 0x80000000u) ? ~u : (u | 0x80000000u);   // sort-monotonic
    }
    if (t == 0) outCnt = 0;
    __syncthreads();

    int K = Ud;                                     // remaining to select
    #pragma unroll
    for (int r = 0; r < 4; ++r) {
        const int shift = 24 - 8 * r;
        hist[t] = 0;
        __syncthreads();
        const int n = (r == 0) ? 4096 : candCnt;
        const short* cur = (r & 1) ? listB : listA;
        for (int i = t; i < n; i += 256) {
            int idx = (r == 0) ? i : cur[i];
            atomicAdd(&hist[(ukey[idx] >> shift) & 0xFF], 1);
        }
        __syncthreads();
        if (t == 0) {
            int cum = 0, b = 255;
            for (; b > 0; --b) {
                if (cum + hist[b] >= K) break;
                cum += hist[b];
            }
            selB = b; aboveK = cum; candCnt = 0;
        }
        __syncthreads();
        const int sb = selB;
        short* nxt = (r & 1) ? listA : listB;
        for (int i = t; i < n; i += 256) {
            int idx = (r == 0) ? i : cur[i];
            int by = (ukey[idx] >> shift) & 0xFF;
            if (by > sb) {
                int p = atomicAdd(&outCnt, 1);
                topIdx[bh * Ud + p] = idx;
            } else if (by == sb) {
                int p = atomicAdd(&candCnt, 1);
                nxt[p] = (short)idx;
            }
        }
        __syncthreads();
        K -= aboveK;
        if (K == 0) break;
    }
    // leftover K candidates all share an identical 32-bit key: take any K
    if (K > 0) {                                    // final list is listA (r=3 wrote it)
        for (int i = t; i < K; i += 256) {
            int p = atomicAdd(&outCnt, 1);
            topIdx[bh * Ud + p] = listA[i];
        }
    }
}

// ---------------------------------------------------------------- per-row sparse-entry list
__global__ void rows_kernel(const int* __restrict__ topIdx, int* __restrict__ rowCnt,
                            int* __restrict__ rowEnt)
{
    const int bh = blockIdx.x, u = threadIdx.x, b = bh >> 3;
    const int lq = topIdx[bh * Ud + u];
    const int row = b * Ld + lq;
    int slot = atomicAdd(&rowCnt[row], 1) & 7;
    rowEnt[row * 8 + slot] = bh * Ud + u;
}

// ---------------------------------------------------------------- meanV over L per (b,h,d)
// grid (bh=64, chunk=64): 4096 blocks; each reduces 64 rows, atomicAdd partial.
__launch_bounds__(256)
__global__ void meanv_kernel(const bf16* __restrict__ V, float* __restrict__ meanV)
{
    const int bh = blockIdx.x, b = bh >> 3, h = bh & 7;
    const int l0 = blockIdx.y * 64;
    const int t = threadIdx.x;
    const int d = t & 63, part = t >> 6;
    float s = 0.0f;
    #pragma unroll
    for (int p = 0; p < 16; ++p) {
        int l = l0 + part + p * 4;
        s += bf2float(V[((size_t)(b * Ld + l)) * Dd + h * 64 + d]);
    }
    __shared__ float red[256];
    red[t] = s;
    __syncthreads();
    if (t < 64) {
        float tot = red[t] + red[64 + t] + red[128 + t] + red[192 + t];
        atomicAdd(&meanV[bh * 64 + t], tot * (1.0f / 4096.0f));
    }
}

// ---------------------------------------------------------------- MFMA flash attention (K-split partials)
__launch_bounds__(256, 3)
__global__ void attn_kernel(const bf16* __restrict__ Qg, const bf16* __restrict__ Kg,
                            const bf16* __restrict__ Vg, const int* __restrict__ topIdx,
                            bf16* __restrict__ pO, float* __restrict__ pM, float* __restrict__ pL)
{
    __shared__ __align__(16) short KsS[2][64 * 64];   // [key][d], swizzled, 16 KiB
    __shared__ __align__(16) short VsS[2][64 * 72];   // [d][key], padded, 18 KiB
    __shared__ __align__(16) short PsS[4][32 * 72];   // per-wave [q][key], 18 KiB

    const int t = threadIdx.x, lane = t & 63, w = t >> 6;
    const int l15 = lane & 15, quad = lane >> 4;
    const int bh = blockIdx.x, ks = blockIdx.y;
    const int b = bh >> 3, h = bh & 7;
    const int key0 = ks * (Ld / KSd);
    constexpr int NT = (Ld / KSd) / 64;               // 4 kv-tiles

    // Q fragments (A operand): row = l15 (+16m), k = quad*8 within 32-wide kk step
    bf16x8 qf[2][2];
    #pragma unroll
    for (int m = 0; m < 2; ++m) {
        const int u  = w * 32 + m * 16 + l15;
        const int lq = topIdx[bh * Ud + u];
        const bf16* qr = Qg + ((size_t)(b * Ld + lq)) * Dd + h * 64;
        qf[m][0] = *(const bf16x8*)(qr + quad * 8);
        qf[m][1] = *(const bf16x8*)(qr + 32 + quad * 8);
    }

    const int vkey = t >> 2, vd0 = (t & 3) * 16;
    u16x8 vr0, vr1;

    auto loadV = [&](int tt) {   // V tile -> regs (issued early, coalesced 16B)
        const bf16* vs = Vg + ((size_t)(b * Ld + key0 + tt * 64 + vkey)) * Dd + h * 64 + vd0;
        vr0 = *(const u16x8*)vs;
        vr1 = *(const u16x8*)(vs + 8);
    };
    auto stageK = [&](int buf, int tt) {  // K tile -> LDS via gload_lds, src pre-swizzled
        const int kb0 = key0 + tt * 64;
        #pragma unroll
        for (int sz = 0; sz < 2; ++sz) {
            const int sg = w * 2 + sz;                  // 8-row segment
            const int r  = sg * 8 + (lane >> 3);
            const int cs = (lane & 7) ^ (lane >> 3);    // inverse swizzle on source
            gload_lds16(Kg + ((size_t)(b * Ld + kb0 + r)) * Dd + h * 64 + cs * 8,
                        (bf16*)&KsS[buf][sg * 512]);
        }
    };
    auto writeV = [&](int buf) {  // regs -> transposed LDS
        #pragma unroll
        for (int j = 0; j < 8; ++j) {
            VsS[buf][(vd0 + j) * 72 + vkey]     = (short)vr0[j];
            VsS[buf][(vd0 + 8 + j) * 72 + vkey] = (short)vr1[j];
        }
    };

    float mrun[2][4], lrun[2][4];
    f32x4 o[2][4] = {};
    #pragma unroll
    for (int m = 0; m < 2; ++m)
        #pragma unroll
        for (int r = 0; r < 4; ++r) { mrun[m][r] = -1e30f; lrun[m][r] = 0.0f; }

    loadV(0); stageK(0, 0); writeV(0);
    __syncthreads();

    short* PsW = &PsS[w][0];
    for (int tt = 0; tt < NT; ++tt) {
        const int cur = tt & 1;
        if (tt + 1 < NT) { loadV(tt + 1); stageK(cur ^ 1, tt + 1); }

        // ---- QK^T -> S (f32), 16 MFMA
        const short* KsB = &KsS[cur][0];
        f32x4 s[2][4] = {};
        #pragma unroll
        for (int kk = 0; kk < 2; ++kk) {
            bf16x8 kb[4];
            #pragma unroll
            for (int n = 0; n < 4; ++n)
                kb[n] = *(const bf16x8*)&KsB[(n * 16 + l15) * 64 +
                                             (((kk * 4 + quad) ^ (l15 & 7)) * 8)];
            #pragma unroll
            for (int m = 0; m < 2; ++m)
                #pragma unroll
                for (int n = 0; n < 4; ++n)
                    s[m][n] = __builtin_amdgcn_mfma_f32_16x16x32_bf16(qf[m][kk], kb[n], s[m][n], 0, 0, 0);
        }

        // ---- online softmax; rows = quad*4+r (+16m), cols = l15 (+16n)
        #pragma unroll
        for (int m = 0; m < 2; ++m) {
            #pragma unroll
            for (int r = 0; r < 4; ++r) {
                float sv[4];
                #pragma unroll
                for (int n = 0; n < 4; ++n) sv[n] = s[m][n][r] * 0.125f;
                float vm = fmaxf(fmaxf(sv[0], sv[1]), fmaxf(sv[2], sv[3]));
                #pragma unroll
                for (int off = 1; off < 16; off <<= 1) vm = fmaxf(vm, __shfl_xor(vm, off));
                const float mn = fmaxf(mrun[m][r], vm);
                const float al = __expf(mrun[m][r] - mn);
                float ps = 0.0f;
                #pragma unroll
                for (int n = 0; n < 4; ++n) { sv[n] = __expf(sv[n] - mn); ps += sv[n]; }
                #pragma unroll
                for (int off = 1; off < 16; off <<= 1) ps += __shfl_xor(ps, off);
                lrun[m][r] = lrun[m][r] * al + ps;
                mrun[m][r] = mn;
                const int qrow = m * 16 + quad * 4 + r;
                #pragma unroll
                for (int n = 0; n < 4; ++n) {
                    PsW[qrow * 72 + n * 16 + l15] = f2bs(sv[n]);
                    o[m][n][r] *= al;
                }
            }
        }

        if (tt + 1 < NT) writeV(cur ^ 1);   // into other buffer; hides under PV

        // ---- PV: O += P * V, 16 MFMA
        const short* VsB = &VsS[cur][0];
        #pragma unroll
        for (int kk = 0; kk < 2; ++kk) {
            bf16x8 pa[2], vb[4];
            #pragma unroll
            for (int m = 0; m < 2; ++m)
                pa[m] = *(const bf16x8*)&PsW[(m * 16 + l15) * 72 + kk * 32 + quad * 8];
            #pragma unroll
            for (int n = 0; n < 4; ++n)
                vb[n] = *(const bf16x8*)&VsB[(n * 16 + l15) * 72 + kk * 32 + quad * 8];
            #pragma unroll
            for (int m = 0; m < 2; ++m)
                #pragma unroll
                for (int n = 0; n < 4; ++n)
                    o[m][n] = __builtin_amdgcn_mfma_f32_16x16x32_bf16(pa[m], vb[n], o[m][n], 0, 0, 0);
        }
        __syncthreads();
    }

    const size_t pbase = ((size_t)(ks * 64 + bh)) * Ud;
    #pragma unroll
    for (int m = 0; m < 2; ++m) {
        #pragma unroll
        for (int r = 0; r < 4; ++r) {
            const int u = w * 32 + m * 16 + quad * 4 + r;
            #pragma unroll
            for (int n = 0; n < 4; ++n)
                pO[(pbase + u) * 64 + n * 16 + l15] = __float2bfloat16(o[m][n][r]);
            if (l15 == 0) { pM[pbase + u] = mrun[m][r]; pL[pbase + u] = lrun[m][r]; }
        }
    }
}

// combine K-split partials -> ctxTop
__global__ void combine_kernel(const bf16* __restrict__ pO, const float* __restrict__ pM,
                               const float* __restrict__ pL, float* __restrict__ ctxTop)
{
    const int u = blockIdx.x & 127, bh = blockIdx.x >> 7, c = threadIdx.x;
    float mstar = -1e30f;
    #pragma unroll
    for (int ks = 0; ks < KSd; ++ks)
        mstar = fmaxf(mstar, pM[(ks * 64 + bh) * Ud + u]);
    float lsum = 0.0f, osum = 0.0f;
    #pragma unroll
    for (int ks = 0; ks < KSd; ++ks) {
        float wgt = __expf(pM[(ks * 64 + bh) * Ud + u] - mstar);
        lsum += pL[(ks * 64 + bh) * Ud + u] * wgt;
        osum += bf2float(pO[(((size_t)ks * 64 + bh) * Ud + u) * 64 + c]) * wgt;
    }
    ctxTop[((size_t)bh * Ud + u) * 64 + c] = scrub(osum / lsum);
}

// ---------------------------------------------------------------- base row: concat(meanV) @ Wo + bo
__launch_bounds__(512)
__global__ void baseout_kernel(const float* __restrict__ meanV, const bf16* __restrict__ Wo,
                               const bf16* __restrict__ bo, float* __restrict__ baseOut)
{
    const int b = blockIdx.x, t = threadIdx.x;
    __shared__ float mv[512];
    mv[t] = meanV[b * 512 + t];
    __syncthreads();
    float acc = bf2float(bo[t]);
    for (int d = 0; d < 512; ++d)
        acc = fmaf(mv[d], bf2float(Wo[(size_t)d * 512 + t]), acc);
    baseOut[b * 512 + t] = acc;
}

// ---------------------------------------------------------------- per-(bh,u) delta rows (bf16 out)
__launch_bounds__(256)
__global__ void delta_kernel(const float* __restrict__ ctxTop, const float* __restrict__ meanV,
                             const bf16* __restrict__ Wo, bf16* __restrict__ deltaOut)
{
    const int u = blockIdx.x, bh = blockIdx.y, h = bh & 7, t = threadIdx.x;
    __shared__ float diff[64];
    if (t < 64) diff[t] = ctxTop[((size_t)bh * Ud + u) * 64 + t] - meanV[bh * 64 + t];
    __syncthreads();
    for (int n = t; n < 512; n += 256) {
        float acc = 0.0f;
        #pragma unroll 8
        for (int dd = 0; dd < 64; ++dd)
            acc = fmaf(diff[dd], bf2float(Wo[(size_t)(h * 64 + dd) * 512 + n]), acc);
        deltaOut[((size_t)bh * Ud + u) * 512 + n] = __float2bfloat16(acc);
    }
}

// ---------------------------------------------------------------- LayerNorms
__launch_bounds__(256)
__global__ void ln1_kernel(const bf16* __restrict__ x, const float* __restrict__ baseOut,
                           const int* __restrict__ rowCnt, const int* __restrict__ rowEnt,
                           const bf16* __restrict__ deltaOut,
                           const bf16* __restrict__ g, const bf16* __restrict__ bb,
                           bf16* __restrict__ x1)
{
    const int row = blockIdx.x, t = threadIdx.x;
    const int b = row >> 12;
    const size_t base = (size_t)row * 512;
    float v0 = bf2float(x[base + t])       + baseOut[b * 512 + t];
    float v1 = bf2float(x[base + t + 256]) + baseOut[b * 512 + t + 256];
    const int cnt = min(rowCnt[row], 8);
    for (int e = 0; e < cnt; ++e) {
        const bf16* dr = &deltaOut[(size_t)rowEnt[row * 8 + e] * 512];
        v0 += bf2float(dr[t]);
        v1 += bf2float(dr[t + 256]);
    }
    v0 = scrub(v0); v1 = scrub(v1);
    float s = v0 + v1, q = v0 * v0 + v1 * v1;
    s = wred_sum(s); q = wred_sum(q);
    __shared__ float sred[4], qred[4];
    int lane = t & 63, w = t >> 6;
    if (lane == 0) { sred[w] = s; qred[w] = q; }
    __syncthreads();
    float tot  = sred[0] + sred[1] + sred[2] + sred[3];
    float totq = qred[0] + qred[1] + qred[2] + qred[3];
    float mean = tot * (1.0f / 512.0f);
    float var  = fmaxf(totq * (1.0f / 512.0f) - mean * mean, 0.0f);
    float rstd = rsqrtf(var + 1e-6f);
    x1[base + t]       = __float2bfloat16((v0 - mean) * rstd * bf2float(g[t])       + bf2float(bb[t]));
    x1[base + t + 256] = __float2bfloat16((v1 - mean) * rstd * bf2float(g[t + 256]) + bf2float(bb[t + 256]));
}

__launch_bounds__(256)
__global__ void ln2_kernel(const bf16* __restrict__ x1, const bf16* __restrict__ ffn,
                           const bf16* __restrict__ g, const bf16* __restrict__ bb,
                           void* __restrict__ out, const int* __restrict__ flags)
{
    const int row = blockIdx.x, t = threadIdx.x;
    const size_t base = (size_t)row * 512;
    float v0 = bf2float(x1[base + t])       + bf2float(ffn[base + t]);
    float v1 = bf2float(x1[base + t + 256]) + bf2float(ffn[base + t + 256]);
    v0 = scrub(v0); v1 = scrub(v1);
    float s = v0 + v1, q = v0 * v0 + v1 * v1;
    s = wred_sum(s); q = wred_sum(q);
    __shared__ float sred[4], qred[4];
    int lane = t & 63, w = t >> 6;
    if (lane == 0) { sred[w] = s; qred[w] = q; }
    __syncthreads();
    float tot  = sred[0] + sred[1] + sred[2] + sred[3];
    float totq = qred[0] + qred[1] + qred[2] + qred[3];
    float mean = tot * (1.0f / 512.0f);
    float var  = fmaxf(totq * (1.0f / 512.0f) - mean * mean, 0.0f);
    float rstd = rsqrtf(var + 1e-6f);
    float o0 = (v0 - mean) * rstd * bf2float(g[t])       + bf2float(bb[t]);
    float o1 = (v1 - mean) * rstd * bf2float(g[t + 256]) + bf2float(bb[t + 256]);
    if (flags[0]) {
        ((float*)out)[base + t]       = o0;
        ((float*)out)[base + t + 256] = o1;
    } else {
        ((bf16*)out)[base + t]       = __float2bfloat16(o0);
        ((bf16*)out)[base + t + 256] = __float2bfloat16(o1);
    }
}

// ================================================================ launcher
extern "C" void kernel_launch(void* const* d_in, const int* in_sizes, int n_in,
                              void* d_out, int out_size, void* d_ws, size_t ws_size,
                              hipStream_t stream)
{
    const void* sraw = d_in[17];

    const size_t NQ = (size_t)MLd * Dd;          // 16,777,216 elements
    char* w = (char*)d_ws;
    size_t off = 0;
    auto alloc = [&](size_t bytes) { void* p = w + off; off += (bytes + 63) & ~size_t(63); return p; };
    bf16*  Qb   = (bf16*)alloc(NQ * 2);                       // 32 MiB
    bf16*  Kb   = (bf16*)alloc(NQ * 2);                       // 32 MiB (contiguous after Qb)
    bf16*  Vb   = (bf16*)alloc(NQ * 2);                       // 32 MiB
    bf16*  xc   = (bf16*)alloc(NQ * 2);                       // 32 MiB
    bf16*  WTq  = (bf16*)alloc(Dd * Dd * 2);
    bf16*  WTk  = (bf16*)alloc(Dd * Dd * 2);
    bf16*  WTv  = (bf16*)alloc(Dd * Dd * 2);
    bf16*  Woc  = (bf16*)alloc(Dd * Dd * 2);                  // untransposed
    bf16*  WT1f = (bf16*)alloc((size_t)Dd * DFFd * 2);        // [2048][512]
    bf16*  WT2f = (bf16*)alloc((size_t)DFFd * Dd * 2);        // [512][2048]
    bf16* bqc = (bf16*)alloc(Dd * 2);
    bf16* bkc = (bf16*)alloc(Dd * 2);
    bf16* bvc = (bf16*)alloc(Dd * 2);
    bf16* boc = (bf16*)alloc(Dd * 2);
    bf16* g1c = (bf16*)alloc(Dd * 2);
    bf16* b1c = (bf16*)alloc(Dd * 2);
    bf16* b1fc= (bf16*)alloc(DFFd * 2);
    bf16* b2fc= (bf16*)alloc(Dd * 2);
    bf16* g2c = (bf16*)alloc(Dd * 2);
    bf16* b2c = (bf16*)alloc(Dd * 2);
    bf16*  pOb     = (bf16*)alloc((size_t)KSd * 64 * Ud * 64 * 2);   // 16 MiB
    float* Mv      = (float*)alloc((size_t)Bd * Hd * Ld * 4);        // 1 MiB
    float* ctxTop  = (float*)alloc((size_t)Bd * Hd * Ud * DHd * 4);  // 2 MiB
    float* meanV   = (float*)alloc(Bd * Hd * DHd * 4);
    float* baseOut = (float*)alloc(Bd * Dd * 4);
    int*   topIdx  = (int*)alloc(Bd * Hd * Ud * 4);
    int*   sidx    = (int*)alloc(128 * 4);
    int*   rowCnt  = (int*)alloc(MLd * 4);
    int*   rowEnt  = (int*)alloc(MLd * 8 * 4);
    int*   flags   = (int*)alloc(64);
    if (off > ws_size) return;

    // optional full-size FFN hidden buffer (128 MiB) if workspace allows
    bf16* h1full = nullptr;
    if (ws_size - off >= (size_t)MLd * DFFd * 2 + 64)
        h1full = (bf16*)alloc((size_t)MLd * DFFd * 2);

    // aliases (lifetimes disjoint, stream-serialized):
    bf16*  x1b  = Vb;                 // ln1 output (V dead)
    bf16*  h1b  = Qb;                 // FFN hidden chunk 16384x2048 spans Qb+Kb (both dead)
    bf16*  ffnb = xc;                 // FFN out (xc dead after ln1)
    bf16*  deltaOut = pOb;            // after combine_kernel, pO dead
    float* pM = Mv;                   // Mv dead after topk
    float* pL = Mv + KSd * 64 * Ud;

    detect_kernel<<<1, 256, 0, stream>>>(d_in[0], flags);

    auto conv = [&](int i, bf16* dst, int n) {
        conv_kernel<<<(n + 255) / 256, 256, 0, stream>>>(d_in[i], dst, n, flags);
    };
    conv(0,  xc, (int)NQ);
    convT_kernel<<<dim3(Dd / 32, Dd / 32), 256, 0, stream>>>(d_in[1], WTq, Dd, Dd, flags);
    convT_kernel<<<dim3(Dd / 32, Dd / 32), 256, 0, stream>>>(d_in[3], WTk, Dd, Dd, flags);
    convT_kernel<<<dim3(Dd / 32, Dd / 32), 256, 0, stream>>>(d_in[5], WTv, Dd, Dd, flags);
    convT_kernel<<<dim3(DFFd / 32, Dd / 32), 256, 0, stream>>>(d_in[11], WT1f, Dd, DFFd, flags);
    convT_kernel<<<dim3(Dd / 32, DFFd / 32), 256, 0, stream>>>(d_in[13], WT2f, DFFd, Dd, flags);
    conv(7,  Woc, Dd * Dd);
    conv(2,  bqc, Dd);  conv(4,  bkc, Dd);  conv(6,  bvc, Dd);  conv(8,  boc, Dd);
    conv(9,  g1c, Dd);  conv(10, b1c, Dd);
    conv(12, b1fc, DFFd); conv(14, b2fc, Dd);
    conv(15, g2c, Dd);  conv(16, b2c, Dd);

    zero_kernel<<<(MLd + 255) / 256, 256, 0, stream>>>(rowCnt, MLd);
    zero_kernel<<<(Bd * Hd * DHd + 255) / 256, 256, 0, stream>>>((int*)meanV, Bd * Hd * DHd);
    idx_kernel<<<1, 128, 0, stream>>>(sraw, sidx);

    // QKV projections (MFMA, async-staged, XCD-swizzled)
    mfma_gemm<false><<<dim3(4, 256), 256, 0, stream>>>(xc, WTq, bqc, Qb, MLd, Dd, Dd);
    mfma_gemm<false><<<dim3(4, 256), 256, 0, stream>>>(xc, WTk, bkc, Kb, MLd, Dd, Dd);
    mfma_gemm<false><<<dim3(4, 256), 256, 0, stream>>>(xc, WTv, bvc, Vb, MLd, Dd, Dd);

    m_kernel<<<dim3(Ld / 128, Bd * Hd), 256, 0, stream>>>(Qb, Kb, sidx, Mv);
    topk_kernel<<<Bd * Hd, 256, 0, stream>>>(Mv, topIdx);
    rows_kernel<<<Bd * Hd, 128, 0, stream>>>(topIdx, rowCnt, rowEnt);
    meanv_kernel<<<dim3(Bd * Hd, Ld / 64), 256, 0, stream>>>(Vb, meanV);

    attn_kernel<<<dim3(Bd * Hd, KSd), 256, 0, stream>>>(Qb, Kb, Vb, topIdx, pOb, pM, pL);
    combine_kernel<<<Bd * Hd * Ud, 64, 0, stream>>>(pOb, pM, pL, ctxTop);

    baseout_kernel<<<Bd, 512, 0, stream>>>(meanV, Woc, boc, baseOut);
    delta_kernel<<<dim3(Ud, Bd * Hd), 256, 0, stream>>>(ctxTop, meanV, Woc, deltaOut);

    ln1_kernel<<<MLd, 256, 0, stream>>>(xc, baseOut, rowCnt, rowEnt, deltaOut, g1c, b1c, x1b);

    // FFN: single full-width dispatches when workspace allows (4 blocks/CU on
    // FFN2 vs 2), else the proven 2-chunk path (h1 = 64 MiB spanning Qb+Kb).
    if (h1full) {
        mfma_gemm<true ><<<dim3(16, 256), 256, 0, stream>>>(x1b, WT1f, b1fc, h1full, MLd, DFFd, Dd);
        mfma_gemm<false><<<dim3(4, 256), 256, 0, stream>>>(h1full, WT2f, b2fc, ffnb, MLd, Dd, DFFd);
    } else {
        for (int c = 0; c < 2; ++c) {
            mfma_gemm<true ><<<dim3(16, 128), 256, 0, stream>>>(
                x1b + (size_t)c * 16384 * 512, WT1f, b1fc, h1b, 16384, DFFd, Dd);
            mfma_gemm<false><<<dim3(4, 128), 256, 0, stream>>>(
                h1b, WT2f, b2fc, ffnb + (size_t)c * 16384 * 512, 16384, Dd, DFFd);
        }
    }

    ln2_kernel<<<MLd, 256, 0, stream>>>(x1b, ffnb, g2c, b2c, d_out, flags);
}

// Round 6
// 695.351 us; speedup vs baseline: 2.2763x; 1.0591x over previous
//
#include <hip/hip_runtime.h>
#include <hip/hip_bf16.h>

using bf16 = __hip_bfloat16;

constexpr int Bd  = 8;
constexpr int Ld  = 4096;
constexpr int Dd  = 512;
constexpr int Hd  = 8;
constexpr int DHd = 64;
constexpr int DFFd= 2048;
constexpr int Ud  = 128;           // TOP_U
constexpr int MLd = Bd * Ld;       // 32768 rows
constexpr int KSd = 16;            // attention K-split (256 keys per block)

typedef short          bf16x8 __attribute__((ext_vector_type(8)));
typedef unsigned short u16x8  __attribute__((ext_vector_type(8)));
typedef float          f32x4  __attribute__((ext_vector_type(4)));

__device__ __forceinline__ float bf2float(bf16 v) { return __bfloat162float(v); }

__device__ __forceinline__ float wred_sum(float v) {
    #pragma unroll
    for (int o = 32; o > 0; o >>= 1) v += __shfl_xor(v, o);
    return v;
}
__device__ __forceinline__ float wred_max(float v) {
    #pragma unroll
    for (int o = 32; o > 0; o >>= 1) v = fmaxf(v, __shfl_xor(v, o));
    return v;
}
__device__ __forceinline__ float scrub(float v) {       // NaN/Inf -> 0
    return (fabsf(v) < 1e20f) ? v : 0.0f;
}
__device__ __forceinline__ short f2bs(float f) {        // float -> bf16 bits
    bf16 h = __float2bfloat16(f);
    return *reinterpret_cast<short*>(&h);
}

// async global->LDS, 16B per lane; LDS dest = wave-uniform base + lane*16
__device__ __forceinline__ void gload_lds16(const bf16* g, bf16* lds_base) {
    __builtin_amdgcn_global_load_lds((const __attribute__((address_space(1))) void*)g,
                                     (__attribute__((address_space(3))) void*)lds_base,
                                     16, 0, 0);
}

// ---------------------------------------------------------------- dtype detector
__global__ void detect_kernel(const void* xraw, int* flags) {
    const unsigned short* u = (const unsigned short*)xraw;
    __shared__ int cnt;
    if (threadIdx.x == 0) cnt = 0;
    __syncthreads();
    int local = 0;
    for (int i = threadIdx.x; i < 1024; i += 256) {
        int e = (u[2 * i] >> 7) & 0xFF;
        if (e >= 96 && e <= 142) local++;
    }
    atomicAdd(&cnt, local);
    __syncthreads();
    if (threadIdx.x == 0) flags[0] = (cnt < 512) ? 1 : 0;
}

// canonicalize any float tensor to bf16
__global__ void conv_kernel(const void* raw, bf16* dst, int n, const int* flags) {
    int i = blockIdx.x * 256 + threadIdx.x;
    if (i >= n) return;
    if (flags[0]) dst[i] = __float2bfloat16(((const float*)raw)[i]);
    else          dst[i] = ((const bf16*)raw)[i];
}

// canonicalize + transpose weight: in W[K][N] -> out WT[N][K] (bf16)
__global__ void convT_kernel(const void* raw, bf16* dst, int K, int N, const int* flags) {
    __shared__ bf16 tile[32][33];
    const int k0 = blockIdx.y * 32, n0 = blockIdx.x * 32;
    const int tx = threadIdx.x & 31, ty = threadIdx.x >> 5;     // 32 x 8
    #pragma unroll
    for (int p = 0; p < 4; ++p) {
        int k = k0 + ty + p * 8, n = n0 + tx;
        float v = flags[0] ? ((const float*)raw)[(size_t)k * N + n]
                           : bf2float(((const bf16*)raw)[(size_t)k * N + n]);
        tile[ty + p * 8][tx] = __float2bfloat16(v);
    }
    __syncthreads();
    #pragma unroll
    for (int p = 0; p < 4; ++p) {
        int n = n0 + ty + p * 8, k = k0 + tx;
        dst[(size_t)n * K + k] = tile[tx][ty + p * 8];
    }
}

__global__ void zero_kernel(int* p, int n) {
    int i = blockIdx.x * 256 + threadIdx.x;
    if (i < n) p[i] = 0;
}

// sample_idx: int32 or int64 device layout; clamped to [0, Ld)
__global__ void idx_kernel(const void* raw, int* out) {
    const int* r32 = (const int*)raw;
    __shared__ int is64;
    int t = threadIdx.x;                       // 128 threads
    if (t == 0) is64 = 1;
    __syncthreads();
    if (t < 64 && r32[2 * t + 1] != 0) is64 = 0;
    __syncthreads();
    int v = is64 ? r32[2 * t] : r32[t];
    out[t] = min(max(v, 0), Ld - 1);
}

// ---------------------------------------------------------------- MFMA GEMM
// C[m,n] = sum_k X[m,k]*WT[n,k] + bias[n]; 128x128 tile, BK=64, 4 waves.
// BK=64 halves the barrier-pair count vs BK=32 (the dominant per-iteration
// fixed cost at 2 blocks/CU); LDS uses the m_kernel-proven XOR-chunk swizzle
// (pre-swizzled gload_lds source + swizzled ds_read) -> conflict-free b128.
// XCD-aware bijective block swizzle (T1) for L2 panel reuse.
template<bool RELU>
__launch_bounds__(256)
__global__ void mfma_gemm(const bf16* __restrict__ X, const bf16* __restrict__ WT,
                          const bf16* __restrict__ bias, bf16* __restrict__ C,
                          int M, int N, int K)
{
    __shared__ bf16 As[128 * 64];   // 16 KiB, swizzled
    __shared__ bf16 Bs[128 * 64];   // 16 KiB, swizzled
    const int t = threadIdx.x;
    const int lane = t & 63, wave = t >> 6;
    const int wr = wave >> 1, wc = wave & 1;    // 2x2 wave grid
    const int quad = lane >> 4, l15 = lane & 15;

    const int nwg = gridDim.x * gridDim.y;
    int wg = blockIdx.y * gridDim.x + blockIdx.x;
    if ((nwg & 7) == 0)                          // bijective chunked XCD swizzle
        wg = (wg & 7) * (nwg >> 3) + (wg >> 3);
    const int m0 = (wg / gridDim.x) * 128, n0 = (wg % gridDim.x) * 128;

    const int rseg = lane >> 3;                  // row within 8-row segment
    const int cs   = (lane & 7) ^ rseg;          // pre-swizzled source chunk

    f32x4 acc[4][4] = {};

    for (int k0 = 0; k0 < K; k0 += 64) {
        #pragma unroll
        for (int p = 0; p < 4; ++p) {
            const int sg = wave * 4 + p;         // 16 segments of 8 rows
            const int r  = sg * 8 + rseg;
            gload_lds16(&X [(size_t)(m0 + r) * K + k0 + cs * 8], &As[sg * 512]);
            gload_lds16(&WT[(size_t)(n0 + r) * K + k0 + cs * 8], &Bs[sg * 512]);
        }
        __syncthreads();
        #pragma unroll
        for (int kk = 0; kk < 2; ++kk) {
            const int ch = ((kk * 4 + quad) ^ (l15 & 7)) * 8;
            bf16x8 a[4], b[4];
            #pragma unroll
            for (int i = 0; i < 4; ++i) {
                a[i] = *(const bf16x8*)&As[(wr * 64 + i * 16 + l15) * 64 + ch];
                b[i] = *(const bf16x8*)&Bs[(wc * 64 + i * 16 + l15) * 64 + ch];
            }
            #pragma unroll
            for (int i = 0; i < 4; ++i)
                #pragma unroll
                for (int j = 0; j < 4; ++j)
                    acc[i][j] = __builtin_amdgcn_mfma_f32_16x16x32_bf16(a[i], b[j], acc[i][j], 0, 0, 0);
        }
        __syncthreads();
    }
    // epilogue: D elem (m = quad*4+reg, n = lane&15) within each 16x16 tile
    #pragma unroll
    for (int j = 0; j < 4; ++j) {
        int n = n0 + wc * 64 + j * 16 + l15;
        float bi = bf2float(bias[n]);
        #pragma unroll
        for (int i = 0; i < 4; ++i) {
            #pragma unroll
            for (int r = 0; r < 4; ++r) {
                int m = m0 + wr * 64 + i * 16 + quad * 4 + r;
                float v = acc[i][j][r] + bi;
                if (RELU) v = fmaxf(v, 0.0f);
                C[(size_t)m * N + n] = __float2bfloat16(v);
            }
        }
    }
}

// ---------------------------------------------------------------- M = max-mean of sampled scores (MFMA)
// grid (Ld/128, bh): block = 128 Q-rows x 128 samples, K=64. 4 waves, each a
// 32x128 tile (2 m-tiles x 8 n-tiles, 2 k-steps = 32 MFMA).
__launch_bounds__(256)
__global__ void m_kernel(const bf16* __restrict__ Q, const bf16* __restrict__ Kg,
                         const int* __restrict__ sidx, float* __restrict__ Mv)
{
    __shared__ __align__(16) short Qs[128 * 64];   // [row][d], swizzled, 16 KiB
    __shared__ __align__(16) short Ks[128 * 64];   // [sample][d], swizzled, 16 KiB
    __shared__ int sidxs[128];

    const int t = threadIdx.x, lane = t & 63, w = t >> 6;
    const int l15 = lane & 15, quad = lane >> 4;
    const int l0 = blockIdx.x * 128;
    const int bh = blockIdx.y, b = bh >> 3, h = bh & 7;

    if (t < 128) sidxs[t] = sidx[t];
    __syncthreads();

    const int rseg = lane >> 3;                    // row within 8-row segment
    const int cs   = (lane & 7) ^ rseg;            // pre-swizzled source chunk
    #pragma unroll
    for (int sg4 = 0; sg4 < 4; ++sg4) {
        const int sg = w * 4 + sg4;                // segment 0..15
        const int r  = sg * 8 + rseg;              // row 0..127
        gload_lds16(Q  + ((size_t)(b * Ld + l0 + r))    * Dd + h * 64 + cs * 8,
                    (bf16*)&Qs[sg * 512]);
        gload_lds16(Kg + ((size_t)(b * Ld + sidxs[r])) * Dd + h * 64 + cs * 8,
                    (bf16*)&Ks[sg * 512]);
    }
    __syncthreads();

    f32x4 s[2][8] = {};
    #pragma unroll
    for (int kk = 0; kk < 2; ++kk) {
        const int ch = ((kk * 4 + quad) ^ (l15 & 7)) * 8;
        bf16x8 qa[2], kb[8];
        #pragma unroll
        for (int mt = 0; mt < 2; ++mt)
            qa[mt] = *(const bf16x8*)&Qs[(w * 32 + mt * 16 + l15) * 64 + ch];
        #pragma unroll
        for (int nt = 0; nt < 8; ++nt)
            kb[nt] = *(const bf16x8*)&Ks[(nt * 16 + l15) * 64 + ch];
        #pragma unroll
        for (int mt = 0; mt < 2; ++mt)
            #pragma unroll
            for (int nt = 0; nt < 8; ++nt)
                s[mt][nt] = __builtin_amdgcn_mfma_f32_16x16x32_bf16(qa[mt], kb[nt], s[mt][nt], 0, 0, 0);
    }

    // rows = w*32 + mt*16 + quad*4 + r; cols = nt*16 + l15
    #pragma unroll
    for (int mt = 0; mt < 2; ++mt) {
        #pragma unroll
        for (int r = 0; r < 4; ++r) {
            float vmax = -1e30f, vsum = 0.0f;
            #pragma unroll
            for (int nt = 0; nt < 8; ++nt) {
                float v = s[mt][nt][r];
                vmax = fmaxf(vmax, v); vsum += v;
            }
            #pragma unroll
            for (int off = 1; off < 16; off <<= 1) {
                vmax = fmaxf(vmax, __shfl_xor(vmax, off));
                vsum += __shfl_xor(vsum, off);
            }
            if (l15 == 0) {
                const int row = w * 32 + mt * 16 + quad * 4 + r;
                Mv[(size_t)bh * Ld + l0 + row] = vmax - vsum * (1.0f / 128.0f);
            }
        }
    }
}

// ---------------------------------------------------------------- top-128 via 8-bit radix select
__launch_bounds__(256)
__global__ void topk_kernel(const float* __restrict__ Mv, int* __restrict__ topIdx)
{
    __shared__ unsigned ukey[4096];                 // 16 KiB
    __shared__ short listA[4096], listB[4096];      // 16 KiB candidate lists
    __shared__ int hist[256];
    __shared__ int outCnt, candCnt, selB, aboveK;
    const int bh = blockIdx.x, t = threadIdx.x;

    for (int i = t; i < 4096; i += 256) {
        unsigned u = __float_as_uint(Mv[(size_t)bh * Ld + i]);
        ukey[i] = (u & 0x80000000u) ? ~u : (u | 0x80000000u);   // sort-monotonic
    }
    if (t == 0) outCnt = 0;
    __syncthreads();

    int K = Ud;                                     // remaining to select
    #pragma unroll
    for (int r = 0; r < 4; ++r) {
        const int shift = 24 - 8 * r;
        hist[t] = 0;
        __syncthreads();
        const int n = (r == 0) ? 4096 : candCnt;
        const short* cur = (r & 1) ? listB : listA;
        for (int i = t; i < n; i += 256) {
            int idx = (r == 0) ? i : cur[i];
            atomicAdd(&hist[(ukey[idx] >> shift) & 0xFF], 1);
        }
        __syncthreads();
        if (t == 0) {
            int cum = 0, b = 255;
            for (; b > 0; --b) {
                if (cum + hist[b] >= K) break;
                cum += hist[b];
            }
            selB = b; aboveK = cum; candCnt = 0;
        }
        __syncthreads();
        const int sb = selB;
        short* nxt = (r & 1) ? listA : listB;
        for (int i = t; i < n; i += 256) {
            int idx = (r == 0) ? i : cur[i];
            int by = (ukey[idx] >> shift) & 0xFF;
            if (by > sb) {
                int p = atomicAdd(&outCnt, 1);
                topIdx[bh * Ud + p] = idx;
            } else if (by == sb) {
                int p = atomicAdd(&candCnt, 1);
                nxt[p] = (short)idx;
            }
        }
        __syncthreads();
        K -= aboveK;
        if (K == 0) break;
    }
    // leftover K candidates all share an identical 32-bit key: take any K
    if (K > 0) {                                    // final list is listA (r=3 wrote it)
        for (int i = t; i < K; i += 256) {
            int p = atomicAdd(&outCnt, 1);
            topIdx[bh * Ud + p] = listA[i];
        }
    }
}

// ---------------------------------------------------------------- per-row sparse-entry list
__global__ void rows_kernel(const int* __restrict__ topIdx, int* __restrict__ rowCnt,
                            int* __restrict__ rowEnt)
{
    const int bh = blockIdx.x, u = threadIdx.x, b = bh >> 3;
    const int lq = topIdx[bh * Ud + u];
    const int row = b * Ld + lq;
    int slot = atomicAdd(&rowCnt[row], 1) & 7;
    rowEnt[row * 8 + slot] = bh * Ud + u;
}

// ---------------------------------------------------------------- meanV over L per (b,h,d)
// grid (bh=64, chunk=64): 4096 blocks; each reduces 64 rows, atomicAdd partial.
__launch_bounds__(256)
__global__ void meanv_kernel(const bf16* __restrict__ V, float* __restrict__ meanV)
{
    const int bh = blockIdx.x, b = bh >> 3, h = bh & 7;
    const int l0 = blockIdx.y * 64;
    const int t = threadIdx.x;
    const int d = t & 63, part = t >> 6;
    float s = 0.0f;
    #pragma unroll
    for (int p = 0; p < 16; ++p) {
        int l = l0 + part + p * 4;
        s += bf2float(V[((size_t)(b * Ld + l)) * Dd + h * 64 + d]);
    }
    __shared__ float red[256];
    red[t] = s;
    __syncthreads();
    if (t < 64) {
        float tot = red[t] + red[64 + t] + red[128 + t] + red[192 + t];
        atomicAdd(&meanV[bh * 64 + t], tot * (1.0f / 4096.0f));
    }
}

// ---------------------------------------------------------------- MFMA flash attention (K-split partials)
__launch_bounds__(256, 3)
__global__ void attn_kernel(const bf16* __restrict__ Qg, const bf16* __restrict__ Kg,
                            const bf16* __restrict__ Vg, const int* __restrict__ topIdx,
                            bf16* __restrict__ pO, float* __restrict__ pM, float* __restrict__ pL)
{
    __shared__ __align__(16) short KsS[2][64 * 64];   // [key][d], swizzled, 16 KiB
    __shared__ __align__(16) short VsS[2][64 * 72];   // [d][key], padded, 18 KiB
    __shared__ __align__(16) short PsS[4][32 * 72];   // per-wave [q][key], 18 KiB

    const int t = threadIdx.x, lane = t & 63, w = t >> 6;
    const int l15 = lane & 15, quad = lane >> 4;
    const int bh = blockIdx.x, ks = blockIdx.y;
    const int b = bh >> 3, h = bh & 7;
    const int key0 = ks * (Ld / KSd);
    constexpr int NT = (Ld / KSd) / 64;               // 4 kv-tiles

    // Q fragments (A operand): row = l15 (+16m), k = quad*8 within 32-wide kk step
    bf16x8 qf[2][2];
    #pragma unroll
    for (int m = 0; m < 2; ++m) {
        const int u  = w * 32 + m * 16 + l15;
        const int lq = topIdx[bh * Ud + u];
        const bf16* qr = Qg + ((size_t)(b * Ld + lq)) * Dd + h * 64;
        qf[m][0] = *(const bf16x8*)(qr + quad * 8);
        qf[m][1] = *(const bf16x8*)(qr + 32 + quad * 8);
    }

    const int vkey = t >> 2, vd0 = (t & 3) * 16;
    u16x8 vr0, vr1;

    auto loadV = [&](int tt) {   // V tile -> regs (issued early, coalesced 16B)
        const bf16* vs = Vg + ((size_t)(b * Ld + key0 + tt * 64 + vkey)) * Dd + h * 64 + vd0;
        vr0 = *(const u16x8*)vs;
        vr1 = *(const u16x8*)(vs + 8);
    };
    auto stageK = [&](int buf, int tt) {  // K tile -> LDS via gload_lds, src pre-swizzled
        const int kb0 = key0 + tt * 64;
        #pragma unroll
        for (int sz = 0; sz < 2; ++sz) {
            const int sg = w * 2 + sz;                  // 8-row segment
            const int r  = sg * 8 + (lane >> 3);
            const int cs = (lane & 7) ^ (lane >> 3);    // inverse swizzle on source
            gload_lds16(Kg + ((size_t)(b * Ld + kb0 + r)) * Dd + h * 64 + cs * 8,
                        (bf16*)&KsS[buf][sg * 512]);
        }
    };
    auto writeV = [&](int buf) {  // regs -> transposed LDS
        #pragma unroll
        for (int j = 0; j < 8; ++j) {
            VsS[buf][(vd0 + j) * 72 + vkey]     = (short)vr0[j];
            VsS[buf][(vd0 + 8 + j) * 72 + vkey] = (short)vr1[j];
        }
    };

    float mrun[2][4], lrun[2][4];
    f32x4 o[2][4] = {};
    #pragma unroll
    for (int m = 0; m < 2; ++m)
        #pragma unroll
        for (int r = 0; r < 4; ++r) { mrun[m][r] = -1e30f; lrun[m][r] = 0.0f; }

    loadV(0); stageK(0, 0); writeV(0);
    __syncthreads();

    short* PsW = &PsS[w][0];
    for (int tt = 0; tt < NT; ++tt) {
        const int cur = tt & 1;
        if (tt + 1 < NT) { loadV(tt + 1); stageK(cur ^ 1, tt + 1); }

        // ---- QK^T -> S (f32), 16 MFMA
        const short* KsB = &KsS[cur][0];
        f32x4 s[2][4] = {};
        #pragma unroll
        for (int kk = 0; kk < 2; ++kk) {
            bf16x8 kb[4];
            #pragma unroll
            for (int n = 0; n < 4; ++n)
                kb[n] = *(const bf16x8*)&KsB[(n * 16 + l15) * 64 +
                                             (((kk * 4 + quad) ^ (l15 & 7)) * 8)];
            #pragma unroll
            for (int m = 0; m < 2; ++m)
                #pragma unroll
                for (int n = 0; n < 4; ++n)
                    s[m][n] = __builtin_amdgcn_mfma_f32_16x16x32_bf16(qf[m][kk], kb[n], s[m][n], 0, 0, 0);
        }

        // ---- online softmax; rows = quad*4+r (+16m), cols = l15 (+16n)
        #pragma unroll
        for (int m = 0; m < 2; ++m) {
            #pragma unroll
            for (int r = 0; r < 4; ++r) {
                float sv[4];
                #pragma unroll
                for (int n = 0; n < 4; ++n) sv[n] = s[m][n][r] * 0.125f;
                float vm = fmaxf(fmaxf(sv[0], sv[1]), fmaxf(sv[2], sv[3]));
                #pragma unroll
                for (int off = 1; off < 16; off <<= 1) vm = fmaxf(vm, __shfl_xor(vm, off));
                const float mn = fmaxf(mrun[m][r], vm);
                const float al = __expf(mrun[m][r] - mn);
                float ps = 0.0f;
                #pragma unroll
                for (int n = 0; n < 4; ++n) { sv[n] = __expf(sv[n] - mn); ps += sv[n]; }
                #pragma unroll
                for (int off = 1; off < 16; off <<= 1) ps += __shfl_xor(ps, off);
                lrun[m][r] = lrun[m][r] * al + ps;
                mrun[m][r] = mn;
                const int qrow = m * 16 + quad * 4 + r;
                #pragma unroll
                for (int n = 0; n < 4; ++n) {
                    PsW[qrow * 72 + n * 16 + l15] = f2bs(sv[n]);
                    o[m][n][r] *= al;
                }
            }
        }

        if (tt + 1 < NT) writeV(cur ^ 1);   // into other buffer; hides under PV

        // ---- PV: O += P * V, 16 MFMA
        const short* VsB = &VsS[cur][0];
        #pragma unroll
        for (int kk = 0; kk < 2; ++kk) {
            bf16x8 pa[2], vb[4];
            #pragma unroll
            for (int m = 0; m < 2; ++m)
                pa[m] = *(const bf16x8*)&PsW[(m * 16 + l15) * 72 + kk * 32 + quad * 8];
            #pragma unroll
            for (int n = 0; n < 4; ++n)
                vb[n] = *(const bf16x8*)&VsB[(n * 16 + l15) * 72 + kk * 32 + quad * 8];
            #pragma unroll
            for (int m = 0; m < 2; ++m)
                #pragma unroll
                for (int n = 0; n < 4; ++n)
                    o[m][n] = __builtin_amdgcn_mfma_f32_16x16x32_bf16(pa[m], vb[n], o[m][n], 0, 0, 0);
        }
        __syncthreads();
    }

    const size_t pbase = ((size_t)(ks * 64 + bh)) * Ud;
    #pragma unroll
    for (int m = 0; m < 2; ++m) {
        #pragma unroll
        for (int r = 0; r < 4; ++r) {
            const int u = w * 32 + m * 16 + quad * 4 + r;
            #pragma unroll
            for (int n = 0; n < 4; ++n)
                pO[(pbase + u) * 64 + n * 16 + l15] = __float2bfloat16(o[m][n][r]);
            if (l15 == 0) { pM[pbase + u] = mrun[m][r]; pL[pbase + u] = lrun[m][r]; }
        }
    }
}

// combine K-split partials -> ctxTop
__global__ void combine_kernel(const bf16* __restrict__ pO, const float* __restrict__ pM,
                               const float* __restrict__ pL, float* __restrict__ ctxTop)
{
    const int u = blockIdx.x & 127, bh = blockIdx.x >> 7, c = threadIdx.x;
    float mstar = -1e30f;
    #pragma unroll
    for (int ks = 0; ks < KSd; ++ks)
        mstar = fmaxf(mstar, pM[(ks * 64 + bh) * Ud + u]);
    float lsum = 0.0f, osum = 0.0f;
    #pragma unroll
    for (int ks = 0; ks < KSd; ++ks) {
        float wgt = __expf(pM[(ks * 64 + bh) * Ud + u] - mstar);
        lsum += pL[(ks * 64 + bh) * Ud + u] * wgt;
        osum += bf2float(pO[(((size_t)ks * 64 + bh) * Ud + u) * 64 + c]) * wgt;
    }
    ctxTop[((size_t)bh * Ud + u) * 64 + c] = scrub(osum / lsum);
}

// ---------------------------------------------------------------- base row: concat(meanV) @ Wo + bo
__launch_bounds__(512)
__global__ void baseout_kernel(const float* __restrict__ meanV, const bf16* __restrict__ Wo,
                               const bf16* __restrict__ bo, float* __restrict__ baseOut)
{
    const int b = blockIdx.x, t = threadIdx.x;
    __shared__ float mv[512];
    mv[t] = meanV[b * 512 + t];
    __syncthreads();
    float acc = bf2float(bo[t]);
    for (int d = 0; d < 512; ++d)
        acc = fmaf(mv[d], bf2float(Wo[(size_t)d * 512 + t]), acc);
    baseOut[b * 512 + t] = acc;
}

// ---------------------------------------------------------------- per-(bh,u) delta rows (bf16 out)
__launch_bounds__(256)
__global__ void delta_kernel(const float* __restrict__ ctxTop, const float* __restrict__ meanV,
                             const bf16* __restrict__ Wo, bf16* __restrict__ deltaOut)
{
    const int u = blockIdx.x, bh = blockIdx.y, h = bh & 7, t = threadIdx.x;
    __shared__ float diff[64];
    if (t < 64) diff[t] = ctxTop[((size_t)bh * Ud + u) * 64 + t] - meanV[bh * 64 + t];
    __syncthreads();
    for (int n = t; n < 512; n += 256) {
        float acc = 0.0f;
        #pragma unroll 8
        for (int dd = 0; dd < 64; ++dd)
            acc = fmaf(diff[dd], bf2float(Wo[(size_t)(h * 64 + dd) * 512 + n]), acc);
        deltaOut[((size_t)bh * Ud + u) * 512 + n] = __float2bfloat16(acc);
    }
}

// ---------------------------------------------------------------- LayerNorms
__launch_bounds__(256)
__global__ void ln1_kernel(const bf16* __restrict__ x, const float* __restrict__ baseOut,
                           const int* __restrict__ rowCnt, const int* __restrict__ rowEnt,
                           const bf16* __restrict__ deltaOut,
                           const bf16* __restrict__ g, const bf16* __restrict__ bb,
                           bf16* __restrict__ x1)
{
    const int row = blockIdx.x, t = threadIdx.x;
    const int b = row >> 12;
    const size_t base = (size_t)row * 512;
    float v0 = bf2float(x[base + t])       + baseOut[b * 512 + t];
    float v1 = bf2float(x[base + t + 256]) + baseOut[b * 512 + t + 256];
    const int cnt = min(rowCnt[row], 8);
    for (int e = 0; e < cnt; ++e) {
        const bf16* dr = &deltaOut[(size_t)rowEnt[row * 8 + e] * 512];
        v0 += bf2float(dr[t]);
        v1 += bf2float(dr[t + 256]);
    }
    v0 = scrub(v0); v1 = scrub(v1);
    float s = v0 + v1, q = v0 * v0 + v1 * v1;
    s = wred_sum(s); q = wred_sum(q);
    __shared__ float sred[4], qred[4];
    int lane = t & 63, w = t >> 6;
    if (lane == 0) { sred[w] = s; qred[w] = q; }
    __syncthreads();
    float tot  = sred[0] + sred[1] + sred[2] + sred[3];
    float totq = qred[0] + qred[1] + qred[2] + qred[3];
    float mean = tot * (1.0f / 512.0f);
    float var  = fmaxf(totq * (1.0f / 512.0f) - mean * mean, 0.0f);
    float rstd = rsqrtf(var + 1e-6f);
    x1[base + t]       = __float2bfloat16((v0 - mean) * rstd * bf2float(g[t])       + bf2float(bb[t]));
    x1[base + t + 256] = __float2bfloat16((v1 - mean) * rstd * bf2float(g[t + 256]) + bf2float(bb[t + 256]));
}

__launch_bounds__(256)
__global__ void ln2_kernel(const bf16* __restrict__ x1, const bf16* __restrict__ ffn,
                           const bf16* __restrict__ g, const bf16* __restrict__ bb,
                           void* __restrict__ out, const int* __restrict__ flags)
{
    const int row = blockIdx.x, t = threadIdx.x;
    const size_t base = (size_t)row * 512;
    float v0 = bf2float(x1[base + t])       + bf2float(ffn[base + t]);
    float v1 = bf2float(x1[base + t + 256]) + bf2float(ffn[base + t + 256]);
    v0 = scrub(v0); v1 = scrub(v1);
    float s = v0 + v1, q = v0 * v0 + v1 * v1;
    s = wred_sum(s); q = wred_sum(q);
    __shared__ float sred[4], qred[4];
    int lane = t & 63, w = t >> 6;
    if (lane == 0) { sred[w] = s; qred[w] = q; }
    __syncthreads();
    float tot  = sred[0] + sred[1] + sred[2] + sred[3];
    float totq = qred[0] + qred[1] + qred[2] + qred[3];
    float mean = tot * (1.0f / 512.0f);
    float var  = fmaxf(totq * (1.0f / 512.0f) - mean * mean, 0.0f);
    float rstd = rsqrtf(var + 1e-6f);
    float o0 = (v0 - mean) * rstd * bf2float(g[t])       + bf2float(bb[t]);
    float o1 = (v1 - mean) * rstd * bf2float(g[t + 256]) + bf2float(bb[t + 256]);
    if (flags[0]) {
        ((float*)out)[base + t]       = o0;
        ((float*)out)[base + t + 256] = o1;
    } else {
        ((bf16*)out)[base + t]       = __float2bfloat16(o0);
        ((bf16*)out)[base + t + 256] = __float2bfloat16(o1);
    }
}

// ================================================================ launcher
extern "C" void kernel_launch(void* const* d_in, const int* in_sizes, int n_in,
                              void* d_out, int out_size, void* d_ws, size_t ws_size,
                              hipStream_t stream)
{
    const void* sraw = d_in[17];

    const size_t NQ = (size_t)MLd * Dd;          // 16,777,216 elements
    char* w = (char*)d_ws;
    size_t off = 0;
    auto alloc = [&](size_t bytes) { void* p = w + off; off += (bytes + 63) & ~size_t(63); return p; };
    bf16*  Qb   = (bf16*)alloc(NQ * 2);                       // 32 MiB
    bf16*  Kb   = (bf16*)alloc(NQ * 2);                       // 32 MiB (contiguous after Qb)
    bf16*  Vb   = (bf16*)alloc(NQ * 2);                       // 32 MiB
    bf16*  xc   = (bf16*)alloc(NQ * 2);                       // 32 MiB
    bf16*  WTq  = (bf16*)alloc(Dd * Dd * 2);
    bf16*  WTk  = (bf16*)alloc(Dd * Dd * 2);
    bf16*  WTv  = (bf16*)alloc(Dd * Dd * 2);
    bf16*  Woc  = (bf16*)alloc(Dd * Dd * 2);                  // untransposed
    bf16*  WT1f = (bf16*)alloc((size_t)Dd * DFFd * 2);        // [2048][512]
    bf16*  WT2f = (bf16*)alloc((size_t)DFFd * Dd * 2);        // [512][2048]
    bf16* bqc = (bf16*)alloc(Dd * 2);
    bf16* bkc = (bf16*)alloc(Dd * 2);
    bf16* bvc = (bf16*)alloc(Dd * 2);
    bf16* boc = (bf16*)alloc(Dd * 2);
    bf16* g1c = (bf16*)alloc(Dd * 2);
    bf16* b1c = (bf16*)alloc(Dd * 2);
    bf16* b1fc= (bf16*)alloc(DFFd * 2);
    bf16* b2fc= (bf16*)alloc(Dd * 2);
    bf16* g2c = (bf16*)alloc(Dd * 2);
    bf16* b2c = (bf16*)alloc(Dd * 2);
    bf16*  pOb     = (bf16*)alloc((size_t)KSd * 64 * Ud * 64 * 2);   // 16 MiB
    float* Mv      = (float*)alloc((size_t)Bd * Hd * Ld * 4);        // 1 MiB
    float* ctxTop  = (float*)alloc((size_t)Bd * Hd * Ud * DHd * 4);  // 2 MiB
    float* meanV   = (float*)alloc(Bd * Hd * DHd * 4);
    float* baseOut = (float*)alloc(Bd * Dd * 4);
    int*   topIdx  = (int*)alloc(Bd * Hd * Ud * 4);
    int*   sidx    = (int*)alloc(128 * 4);
    int*   rowCnt  = (int*)alloc(MLd * 4);
    int*   rowEnt  = (int*)alloc(MLd * 8 * 4);
    int*   flags   = (int*)alloc(64);
    if (off > ws_size) return;

    // optional full-size FFN hidden buffer (128 MiB) if workspace allows
    bf16* h1full = nullptr;
    if (ws_size - off >= (size_t)MLd * DFFd * 2 + 64)
        h1full = (bf16*)alloc((size_t)MLd * DFFd * 2);

    // aliases (lifetimes disjoint, stream-serialized):
    bf16*  x1b  = Vb;                 // ln1 output (V dead)
    bf16*  h1b  = Qb;                 // FFN hidden chunk 16384x2048 spans Qb+Kb (both dead)
    bf16*  ffnb = xc;                 // FFN out (xc dead after ln1)
    bf16*  deltaOut = pOb;            // after combine_kernel, pO dead
    float* pM = Mv;                   // Mv dead after topk
    float* pL = Mv + KSd * 64 * Ud;

    detect_kernel<<<1, 256, 0, stream>>>(d_in[0], flags);

    auto conv = [&](int i, bf16* dst, int n) {
        conv_kernel<<<(n + 255) / 256, 256, 0, stream>>>(d_in[i], dst, n, flags);
    };
    conv(0,  xc, (int)NQ);
    convT_kernel<<<dim3(Dd / 32, Dd / 32), 256, 0, stream>>>(d_in[1], WTq, Dd, Dd, flags);
    convT_kernel<<<dim3(Dd / 32, Dd / 32), 256, 0, stream>>>(d_in[3], WTk, Dd, Dd, flags);
    convT_kernel<<<dim3(Dd / 32, Dd / 32), 256, 0, stream>>>(d_in[5], WTv, Dd, Dd, flags);
    convT_kernel<<<dim3(DFFd / 32, Dd / 32), 256, 0, stream>>>(d_in[11], WT1f, Dd, DFFd, flags);
    convT_kernel<<<dim3(Dd / 32, DFFd / 32), 256, 0, stream>>>(d_in[13], WT2f, DFFd, Dd, flags);
    conv(7,  Woc, Dd * Dd);
    conv(2,  bqc, Dd);  conv(4,  bkc, Dd);  conv(6,  bvc, Dd);  conv(8,  boc, Dd);
    conv(9,  g1c, Dd);  conv(10, b1c, Dd);
    conv(12, b1fc, DFFd); conv(14, b2fc, Dd);
    conv(15, g2c, Dd);  conv(16, b2c, Dd);

    zero_kernel<<<(MLd + 255) / 256, 256, 0, stream>>>(rowCnt, MLd);
    zero_kernel<<<(Bd * Hd * DHd + 255) / 256, 256, 0, stream>>>((int*)meanV, Bd * Hd * DHd);
    idx_kernel<<<1, 128, 0, stream>>>(sraw, sidx);

    // QKV projections (MFMA, async-staged, XCD-swizzled, BK=64)
    mfma_gemm<false><<<dim3(4, 256), 256, 0, stream>>>(xc, WTq, bqc, Qb, MLd, Dd, Dd);
    mfma_gemm<false><<<dim3(4, 256), 256, 0, stream>>>(xc, WTk, bkc, Kb, MLd, Dd, Dd);
    mfma_gemm<false><<<dim3(4, 256), 256, 0, stream>>>(xc, WTv, bvc, Vb, MLd, Dd, Dd);

    m_kernel<<<dim3(Ld / 128, Bd * Hd), 256, 0, stream>>>(Qb, Kb, sidx, Mv);
    topk_kernel<<<Bd * Hd, 256, 0, stream>>>(Mv, topIdx);
    rows_kernel<<<Bd * Hd, 128, 0, stream>>>(topIdx, rowCnt, rowEnt);
    meanv_kernel<<<dim3(Bd * Hd, Ld / 64), 256, 0, stream>>>(Vb, meanV);

    attn_kernel<<<dim3(Bd * Hd, KSd), 256, 0, stream>>>(Qb, Kb, Vb, topIdx, pOb, pM, pL);
    combine_kernel<<<Bd * Hd * Ud, 64, 0, stream>>>(pOb, pM, pL, ctxTop);

    baseout_kernel<<<Bd, 512, 0, stream>>>(meanV, Woc, boc, baseOut);
    delta_kernel<<<dim3(Ud, Bd * Hd), 256, 0, stream>>>(ctxTop, meanV, Woc, deltaOut);

    ln1_kernel<<<MLd, 256, 0, stream>>>(xc, baseOut, rowCnt, rowEnt, deltaOut, g1c, b1c, x1b);

    // FFN: single full-width dispatches when workspace allows (4 blocks/CU on
    // FFN2 vs 2), else the proven 2-chunk path (h1 = 64 MiB spanning Qb+Kb).
    if (h1full) {
        mfma_gemm<true ><<<dim3(16, 256), 256, 0, stream>>>(x1b, WT1f, b1fc, h1full, MLd, DFFd, Dd);
        mfma_gemm<false><<<dim3(4, 256), 256, 0, stream>>>(h1full, WT2f, b2fc, ffnb, MLd, Dd, DFFd);
    } else {
        for (int c = 0; c < 2; ++c) {
            mfma_gemm<true ><<<dim3(16, 128), 256, 0, stream>>>(
                x1b + (size_t)c * 16384 * 512, WT1f, b1fc, h1b, 16384, DFFd, Dd);
            mfma_gemm<false><<<dim3(4, 128), 256, 0, stream>>>(
                h1b, WT2f, b2fc, ffnb + (size_t)c * 16384 * 512, 16384, Dd, DFFd);
        }
    }

    ln2_kernel<<<MLd, 256, 0, stream>>>(x1b, ffnb, g2c, b2c, d_out, flags);
}

// Round 7
// 668.998 us; speedup vs baseline: 2.3659x; 1.0394x over previous
//
#include <hip/hip_runtime.h>
#include <hip/hip_bf16.h>

using bf16 = __hip_bfloat16;

constexpr int Bd  = 8;
constexpr int Ld  = 4096;
constexpr int Dd  = 512;
constexpr int Hd  = 8;
constexpr int DHd = 64;
constexpr int DFFd= 2048;
constexpr int Ud  = 128;           // TOP_U
constexpr int MLd = Bd * Ld;       // 32768 rows
constexpr int KSd = 16;            // attention K-split (256 keys per block)

typedef short          bf16x8 __attribute__((ext_vector_type(8)));
typedef unsigned short u16x8  __attribute__((ext_vector_type(8)));
typedef float          f32x4  __attribute__((ext_vector_type(4)));

__device__ __forceinline__ float bf2float(bf16 v) { return __bfloat162float(v); }

__device__ __forceinline__ float wred_sum(float v) {
    #pragma unroll
    for (int o = 32; o > 0; o >>= 1) v += __shfl_xor(v, o);
    return v;
}
__device__ __forceinline__ float wred_max(float v) {
    #pragma unroll
    for (int o = 32; o > 0; o >>= 1) v = fmaxf(v, __shfl_xor(v, o));
    return v;
}
__device__ __forceinline__ float scrub(float v) {       // NaN/Inf -> 0
    return (fabsf(v) < 1e20f) ? v : 0.0f;
}
__device__ __forceinline__ short f2bs(float f) {        // float -> bf16 bits
    bf16 h = __float2bfloat16(f);
    return *reinterpret_cast<short*>(&h);
}

// async global->LDS, 16B per lane; LDS dest = wave-uniform base + lane*16
__device__ __forceinline__ void gload_lds16(const bf16* g, bf16* lds_base) {
    __builtin_amdgcn_global_load_lds((const __attribute__((address_space(1))) void*)g,
                                     (__attribute__((address_space(3))) void*)lds_base,
                                     16, 0, 0);
}

// ---------------------------------------------------------------- dtype detector
__global__ void detect_kernel(const void* xraw, int* flags) {
    const unsigned short* u = (const unsigned short*)xraw;
    __shared__ int cnt;
    if (threadIdx.x == 0) cnt = 0;
    __syncthreads();
    int local = 0;
    for (int i = threadIdx.x; i < 1024; i += 256) {
        int e = (u[2 * i] >> 7) & 0xFF;
        if (e >= 96 && e <= 142) local++;
    }
    atomicAdd(&cnt, local);
    __syncthreads();
    if (threadIdx.x == 0) flags[0] = (cnt < 512) ? 1 : 0;
}

// canonicalize any float tensor to bf16
__global__ void conv_kernel(const void* raw, bf16* dst, int n, const int* flags) {
    int i = blockIdx.x * 256 + threadIdx.x;
    if (i >= n) return;
    if (flags[0]) dst[i] = __float2bfloat16(((const float*)raw)[i]);
    else          dst[i] = ((const bf16*)raw)[i];
}

// canonicalize + transpose weight: in W[K][N] -> out WT[N][K] (bf16)
__global__ void convT_kernel(const void* raw, bf16* dst, int K, int N, const int* flags) {
    __shared__ bf16 tile[32][33];
    const int k0 = blockIdx.y * 32, n0 = blockIdx.x * 32;
    const int tx = threadIdx.x & 31, ty = threadIdx.x >> 5;     // 32 x 8
    #pragma unroll
    for (int p = 0; p < 4; ++p) {
        int k = k0 + ty + p * 8, n = n0 + tx;
        float v = flags[0] ? ((const float*)raw)[(size_t)k * N + n]
                           : bf2float(((const bf16*)raw)[(size_t)k * N + n]);
        tile[ty + p * 8][tx] = __float2bfloat16(v);
    }
    __syncthreads();
    #pragma unroll
    for (int p = 0; p < 4; ++p) {
        int n = n0 + ty + p * 8, k = k0 + tx;
        dst[(size_t)n * K + k] = tile[tx][ty + p * 8];
    }
}

__global__ void zero_kernel(int* p, int n) {
    int i = blockIdx.x * 256 + threadIdx.x;
    if (i < n) p[i] = 0;
}

// sample_idx: int32 or int64 device layout; clamped to [0, Ld)
__global__ void idx_kernel(const void* raw, int* out) {
    const int* r32 = (const int*)raw;
    __shared__ int is64;
    int t = threadIdx.x;                       // 128 threads
    if (t == 0) is64 = 1;
    __syncthreads();
    if (t < 64 && r32[2 * t + 1] != 0) is64 = 0;
    __syncthreads();
    int v = is64 ? r32[2 * t] : r32[t];
    out[t] = min(max(v, 0), Ld - 1);
}

// ---------------------------------------------------------------- MFMA GEMM
// C[m,n] = sum_k X[m,k]*WT[n,k] + bias[n]; 128x128 tile, BK=64, 4 waves.
// T3-minimum 2-phase pipeline: double-buffered LDS; tile t+1's gload_lds
// issued BEFORE tile t's ds_read+MFMA, one barrier per iteration (its
// compiler-emitted vmcnt(0) waits on the prefetch whose latency hid under
// the current tile's compute). LDS 64 KiB -> 2 blocks/CU; ILP replaces TLP.
// XOR-chunk swizzle (conflict-free) + bijective XCD block swizzle (T1).
// QKV3: N spans 3 concatenated weight blocks; output buffer = n>>9
// (Qb/Kb/Vb are contiguous in workspace), row stride Dd.
template<bool RELU, bool QKV3>
__launch_bounds__(256)
__global__ void mfma_gemm(const bf16* __restrict__ X, const bf16* __restrict__ WT,
                          const bf16* __restrict__ bias, bf16* __restrict__ C,
                          int M, int N, int K)
{
    __shared__ bf16 As[2][128 * 64];   // 32 KiB, swizzled, double-buffered
    __shared__ bf16 Bs[2][128 * 64];   // 32 KiB
    const int t = threadIdx.x;
    const int lane = t & 63, wave = t >> 6;
    const int wr = wave >> 1, wc = wave & 1;    // 2x2 wave grid
    const int quad = lane >> 4, l15 = lane & 15;

    const int nwg = gridDim.x * gridDim.y;
    int wg = blockIdx.y * gridDim.x + blockIdx.x;
    if ((nwg & 7) == 0)                          // bijective chunked XCD swizzle
        wg = (wg & 7) * (nwg >> 3) + (wg >> 3);
    const int m0 = (wg / gridDim.x) * 128, n0 = (wg % gridDim.x) * 128;

    const int rseg = lane >> 3;                  // row within 8-row segment
    const int cs   = (lane & 7) ^ rseg;          // pre-swizzled source chunk

    auto stage = [&](int buf, int k0) {
        #pragma unroll
        for (int p = 0; p < 4; ++p) {
            const int sg = wave * 4 + p;         // 16 segments of 8 rows
            const int r  = sg * 8 + rseg;
            gload_lds16(&X [(size_t)(m0 + r) * K + k0 + cs * 8], &As[buf][sg * 512]);
            gload_lds16(&WT[(size_t)(n0 + r) * K + k0 + cs * 8], &Bs[buf][sg * 512]);
        }
    };

    f32x4 acc[4][4] = {};

    stage(0, 0);
    __syncthreads();                             // drains vmcnt -> buf0 ready
    int cur = 0;
    const int NI = K >> 6;
    for (int it = 0; it < NI; ++it) {
        if (it + 1 < NI) stage(cur ^ 1, (it + 1) << 6);   // prefetch next tile
        #pragma unroll
        for (int kk = 0; kk < 2; ++kk) {
            const int ch = ((kk * 4 + quad) ^ (l15 & 7)) * 8;
            bf16x8 a[4], b[4];
            #pragma unroll
            for (int i = 0; i < 4; ++i) {
                a[i] = *(const bf16x8*)&As[cur][(wr * 64 + i * 16 + l15) * 64 + ch];
                b[i] = *(const bf16x8*)&Bs[cur][(wc * 64 + i * 16 + l15) * 64 + ch];
            }
            #pragma unroll
            for (int i = 0; i < 4; ++i)
                #pragma unroll
                for (int j = 0; j < 4; ++j)
                    acc[i][j] = __builtin_amdgcn_mfma_f32_16x16x32_bf16(a[i], b[j], acc[i][j], 0, 0, 0);
        }
        if (it + 1 < NI) __syncthreads();        // waits prefetch (latency hidden)
        cur ^= 1;
    }
    // epilogue: D elem (m = quad*4+reg, n = lane&15) within each 16x16 tile
    #pragma unroll
    for (int j = 0; j < 4; ++j) {
        int n = n0 + wc * 64 + j * 16 + l15;
        float bi = bf2float(bias[n]);
        bf16* cb;
        size_t stride;
        if (QKV3) {
            cb = C + (size_t)(n >> 9) * ((size_t)MLd * Dd) + (n & (Dd - 1));
            stride = Dd;
        } else {
            cb = C + n;
            stride = (size_t)N;
        }
        #pragma unroll
        for (int i = 0; i < 4; ++i) {
            #pragma unroll
            for (int r = 0; r < 4; ++r) {
                int m = m0 + wr * 64 + i * 16 + quad * 4 + r;
                float v = acc[i][j][r] + bi;
                if (RELU) v = fmaxf(v, 0.0f);
                cb[(size_t)m * stride] = __float2bfloat16(v);
            }
        }
    }
}

// ---------------------------------------------------------------- M = max-mean of sampled scores (MFMA)
// grid (Ld/128, bh): block = 128 Q-rows x 128 samples, K=64. 4 waves, each a
// 32x128 tile (2 m-tiles x 8 n-tiles, 2 k-steps = 32 MFMA).
__launch_bounds__(256)
__global__ void m_kernel(const bf16* __restrict__ Q, const bf16* __restrict__ Kg,
                         const int* __restrict__ sidx, float* __restrict__ Mv)
{
    __shared__ __align__(16) short Qs[128 * 64];   // [row][d], swizzled, 16 KiB
    __shared__ __align__(16) short Ks[128 * 64];   // [sample][d], swizzled, 16 KiB
    __shared__ int sidxs[128];

    const int t = threadIdx.x, lane = t & 63, w = t >> 6;
    const int l15 = lane & 15, quad = lane >> 4;
    const int l0 = blockIdx.x * 128;
    const int bh = blockIdx.y, b = bh >> 3, h = bh & 7;

    if (t < 128) sidxs[t] = sidx[t];
    __syncthreads();

    const int rseg = lane >> 3;                    // row within 8-row segment
    const int cs   = (lane & 7) ^ rseg;            // pre-swizzled source chunk
    #pragma unroll
    for (int sg4 = 0; sg4 < 4; ++sg4) {
        const int sg = w * 4 + sg4;                // segment 0..15
        const int r  = sg * 8 + rseg;              // row 0..127
        gload_lds16(Q  + ((size_t)(b * Ld + l0 + r))    * Dd + h * 64 + cs * 8,
                    (bf16*)&Qs[sg * 512]);
        gload_lds16(Kg + ((size_t)(b * Ld + sidxs[r])) * Dd + h * 64 + cs * 8,
                    (bf16*)&Ks[sg * 512]);
    }
    __syncthreads();

    f32x4 s[2][8] = {};
    #pragma unroll
    for (int kk = 0; kk < 2; ++kk) {
        const int ch = ((kk * 4 + quad) ^ (l15 & 7)) * 8;
        bf16x8 qa[2], kb[8];
        #pragma unroll
        for (int mt = 0; mt < 2; ++mt)
            qa[mt] = *(const bf16x8*)&Qs[(w * 32 + mt * 16 + l15) * 64 + ch];
        #pragma unroll
        for (int nt = 0; nt < 8; ++nt)
            kb[nt] = *(const bf16x8*)&Ks[(nt * 16 + l15) * 64 + ch];
        #pragma unroll
        for (int mt = 0; mt < 2; ++mt)
            #pragma unroll
            for (int nt = 0; nt < 8; ++nt)
                s[mt][nt] = __builtin_amdgcn_mfma_f32_16x16x32_bf16(qa[mt], kb[nt], s[mt][nt], 0, 0, 0);
    }

    // rows = w*32 + mt*16 + quad*4 + r; cols = nt*16 + l15
    #pragma unroll
    for (int mt = 0; mt < 2; ++mt) {
        #pragma unroll
        for (int r = 0; r < 4; ++r) {
            float vmax = -1e30f, vsum = 0.0f;
            #pragma unroll
            for (int nt = 0; nt < 8; ++nt) {
                float v = s[mt][nt][r];
                vmax = fmaxf(vmax, v); vsum += v;
            }
            #pragma unroll
            for (int off = 1; off < 16; off <<= 1) {
                vmax = fmaxf(vmax, __shfl_xor(vmax, off));
                vsum += __shfl_xor(vsum, off);
            }
            if (l15 == 0) {
                const int row = w * 32 + mt * 16 + quad * 4 + r;
                Mv[(size_t)bh * Ld + l0 + row] = vmax - vsum * (1.0f / 128.0f);
            }
        }
    }
}

// ---------------------------------------------------------------- top-128 via 8-bit radix select
__launch_bounds__(256)
__global__ void topk_kernel(const float* __restrict__ Mv, int* __restrict__ topIdx)
{
    __shared__ unsigned ukey[4096];                 // 16 KiB
    __shared__ short listA[4096], listB[4096];      // 16 KiB candidate lists
    __shared__ int hist[256];
    __shared__ int outCnt, candCnt, selB, aboveK;
    const int bh = blockIdx.x, t = threadIdx.x;

    for (int i = t; i < 4096; i += 256) {
        unsigned u = __float_as_uint(Mv[(size_t)bh * Ld + i]);
        ukey[i] = (u & 0x80000000u) ? ~u : (u | 0x80000000u);   // sort-monotonic
    }
    if (t == 0) outCnt = 0;
    __syncthreads();

    int K = Ud;                                     // remaining to select
    #pragma unroll
    for (int r = 0; r < 4; ++r) {
        const int shift = 24 - 8 * r;
        hist[t] = 0;
        __syncthreads();
        const int n = (r == 0) ? 4096 : candCnt;
        const short* cur = (r & 1) ? listB : listA;
        for (int i = t; i < n; i += 256) {
            int idx = (r == 0) ? i : cur[i];
            atomicAdd(&hist[(ukey[idx] >> shift) & 0xFF], 1);
        }
        __syncthreads();
        if (t == 0) {
            int cum = 0, b = 255;
            for (; b > 0; --b) {
                if (cum + hist[b] >= K) break;
                cum += hist[b];
            }
            selB = b; aboveK = cum; candCnt = 0;
        }
        __syncthreads();
        const int sb = selB;
        short* nxt = (r & 1) ? listA : listB;
        for (int i = t; i < n; i += 256) {
            int idx = (r == 0) ? i : cur[i];
            int by = (ukey[idx] >> shift) & 0xFF;
            if (by > sb) {
                int p = atomicAdd(&outCnt, 1);
                topIdx[bh * Ud + p] = idx;
            } else if (by == sb) {
                int p = atomicAdd(&candCnt, 1);
                nxt[p] = (short)idx;
            }
        }
        __syncthreads();
        K -= aboveK;
        if (K == 0) break;
    }
    // leftover K candidates all share an identical 32-bit key: take any K
    if (K > 0) {                                    // final list is listA (r=3 wrote it)
        for (int i = t; i < K; i += 256) {
            int p = atomicAdd(&outCnt, 1);
            topIdx[bh * Ud + p] = listA[i];
        }
    }
}

// ---------------------------------------------------------------- per-row sparse-entry list
__global__ void rows_kernel(const int* __restrict__ topIdx, int* __restrict__ rowCnt,
                            int* __restrict__ rowEnt)
{
    const int bh = blockIdx.x, u = threadIdx.x, b = bh >> 3;
    const int lq = topIdx[bh * Ud + u];
    const int row = b * Ld + lq;
    int slot = atomicAdd(&rowCnt[row], 1) & 7;
    rowEnt[row * 8 + slot] = bh * Ud + u;
}

// ---------------------------------------------------------------- meanV over L per (b,h,d)
// grid (bh=64, chunk=64): 4096 blocks; each reduces 64 rows, atomicAdd partial.
__launch_bounds__(256)
__global__ void meanv_kernel(const bf16* __restrict__ V, float* __restrict__ meanV)
{
    const int bh = blockIdx.x, b = bh >> 3, h = bh & 7;
    const int l0 = blockIdx.y * 64;
    const int t = threadIdx.x;
    const int d = t & 63, part = t >> 6;
    float s = 0.0f;
    #pragma unroll
    for (int p = 0; p < 16; ++p) {
        int l = l0 + part + p * 4;
        s += bf2float(V[((size_t)(b * Ld + l)) * Dd + h * 64 + d]);
    }
    __shared__ float red[256];
    red[t] = s;
    __syncthreads();
    if (t < 64) {
        float tot = red[t] + red[64 + t] + red[128 + t] + red[192 + t];
        atomicAdd(&meanV[bh * 64 + t], tot * (1.0f / 4096.0f));
    }
}

// ---------------------------------------------------------------- MFMA flash attention (K-split partials)
__launch_bounds__(256, 3)
__global__ void attn_kernel(const bf16* __restrict__ Qg, const bf16* __restrict__ Kg,
                            const bf16* __restrict__ Vg, const int* __restrict__ topIdx,
                            bf16* __restrict__ pO, float* __restrict__ pM, float* __restrict__ pL)
{
    __shared__ __align__(16) short KsS[2][64 * 64];   // [key][d], swizzled, 16 KiB
    __shared__ __align__(16) short VsS[2][64 * 72];   // [d][key], padded, 18 KiB
    __shared__ __align__(16) short PsS[4][32 * 72];   // per-wave [q][key], 18 KiB

    const int t = threadIdx.x, lane = t & 63, w = t >> 6;
    const int l15 = lane & 15, quad = lane >> 4;
    const int bh = blockIdx.x, ks = blockIdx.y;
    const int b = bh >> 3, h = bh & 7;
    const int key0 = ks * (Ld / KSd);
    constexpr int NT = (Ld / KSd) / 64;               // 4 kv-tiles

    // Q fragments (A operand): row = l15 (+16m), k = quad*8 within 32-wide kk step
    bf16x8 qf[2][2];
    #pragma unroll
    for (int m = 0; m < 2; ++m) {
        const int u  = w * 32 + m * 16 + l15;
        const int lq = topIdx[bh * Ud + u];
        const bf16* qr = Qg + ((size_t)(b * Ld + lq)) * Dd + h * 64;
        qf[m][0] = *(const bf16x8*)(qr + quad * 8);
        qf[m][1] = *(const bf16x8*)(qr + 32 + quad * 8);
    }

    const int vkey = t >> 2, vd0 = (t & 3) * 16;
    u16x8 vr0, vr1;

    auto loadV = [&](int tt) {   // V tile -> regs (issued early, coalesced 16B)
        const bf16* vs = Vg + ((size_t)(b * Ld + key0 + tt * 64 + vkey)) * Dd + h * 64 + vd0;
        vr0 = *(const u16x8*)vs;
        vr1 = *(const u16x8*)(vs + 8);
    };
    auto stageK = [&](int buf, int tt) {  // K tile -> LDS via gload_lds, src pre-swizzled
        const int kb0 = key0 + tt * 64;
        #pragma unroll
        for (int sz = 0; sz < 2; ++sz) {
            const int sg = w * 2 + sz;                  // 8-row segment
            const int r  = sg * 8 + (lane >> 3);
            const int cs = (lane & 7) ^ (lane >> 3);    // inverse swizzle on source
            gload_lds16(Kg + ((size_t)(b * Ld + kb0 + r)) * Dd + h * 64 + cs * 8,
                        (bf16*)&KsS[buf][sg * 512]);
        }
    };
    auto writeV = [&](int buf) {  // regs -> transposed LDS
        #pragma unroll
        for (int j = 0; j < 8; ++j) {
            VsS[buf][(vd0 + j) * 72 + vkey]     = (short)vr0[j];
            VsS[buf][(vd0 + 8 + j) * 72 + vkey] = (short)vr1[j];
        }
    };

    float mrun[2][4], lrun[2][4];
    f32x4 o[2][4] = {};
    #pragma unroll
    for (int m = 0; m < 2; ++m)
        #pragma unroll
        for (int r = 0; r < 4; ++r) { mrun[m][r] = -1e30f; lrun[m][r] = 0.0f; }

    loadV(0); stageK(0, 0); writeV(0);
    __syncthreads();

    short* PsW = &PsS[w][0];
    for (int tt = 0; tt < NT; ++tt) {
        const int cur = tt & 1;
        if (tt + 1 < NT) { loadV(tt + 1); stageK(cur ^ 1, tt + 1); }

        // ---- QK^T -> S (f32), 16 MFMA
        const short* KsB = &KsS[cur][0];
        f32x4 s[2][4] = {};
        #pragma unroll
        for (int kk = 0; kk < 2; ++kk) {
            bf16x8 kb[4];
            #pragma unroll
            for (int n = 0; n < 4; ++n)
                kb[n] = *(const bf16x8*)&KsB[(n * 16 + l15) * 64 +
                                             (((kk * 4 + quad) ^ (l15 & 7)) * 8)];
            #pragma unroll
            for (int m = 0; m < 2; ++m)
                #pragma unroll
                for (int n = 0; n < 4; ++n)
                    s[m][n] = __builtin_amdgcn_mfma_f32_16x16x32_bf16(qf[m][kk], kb[n], s[m][n], 0, 0, 0);
        }

        // ---- online softmax; rows = quad*4+r (+16m), cols = l15 (+16n)
        #pragma unroll
        for (int m = 0; m < 2; ++m) {
            #pragma unroll
            for (int r = 0; r < 4; ++r) {
                float sv[4];
                #pragma unroll
                for (int n = 0; n < 4; ++n) sv[n] = s[m][n][r] * 0.125f;
                float vm = fmaxf(fmaxf(sv[0], sv[1]), fmaxf(sv[2], sv[3]));
                #pragma unroll
                for (int off = 1; off < 16; off <<= 1) vm = fmaxf(vm, __shfl_xor(vm, off));
                const float mn = fmaxf(mrun[m][r], vm);
                const float al = __expf(mrun[m][r] - mn);
                float ps = 0.0f;
                #pragma unroll
                for (int n = 0; n < 4; ++n) { sv[n] = __expf(sv[n] - mn); ps += sv[n]; }
                #pragma unroll
                for (int off = 1; off < 16; off <<= 1) ps += __shfl_xor(ps, off);
                lrun[m][r] = lrun[m][r] * al + ps;
                mrun[m][r] = mn;
                const int qrow = m * 16 + quad * 4 + r;
                #pragma unroll
                for (int n = 0; n < 4; ++n) {
                    PsW[qrow * 72 + n * 16 + l15] = f2bs(sv[n]);
                    o[m][n][r] *= al;
                }
            }
        }

        if (tt + 1 < NT) writeV(cur ^ 1);   // into other buffer; hides under PV

        // ---- PV: O += P * V, 16 MFMA
        const short* VsB = &VsS[cur][0];
        #pragma unroll
        for (int kk = 0; kk < 2; ++kk) {
            bf16x8 pa[2], vb[4];
            #pragma unroll
            for (int m = 0; m < 2; ++m)
                pa[m] = *(const bf16x8*)&PsW[(m * 16 + l15) * 72 + kk * 32 + quad * 8];
            #pragma unroll
            for (int n = 0; n < 4; ++n)
                vb[n] = *(const bf16x8*)&VsB[(n * 16 + l15) * 72 + kk * 32 + quad * 8];
            #pragma unroll
            for (int m = 0; m < 2; ++m)
                #pragma unroll
                for (int n = 0; n < 4; ++n)
                    o[m][n] = __builtin_amdgcn_mfma_f32_16x16x32_bf16(pa[m], vb[n], o[m][n], 0, 0, 0);
        }
        __syncthreads();
    }

    const size_t pbase = ((size_t)(ks * 64 + bh)) * Ud;
    #pragma unroll
    for (int m = 0; m < 2; ++m) {
        #pragma unroll
        for (int r = 0; r < 4; ++r) {
            const int u = w * 32 + m * 16 + quad * 4 + r;
            #pragma unroll
            for (int n = 0; n < 4; ++n)
                pO[(pbase + u) * 64 + n * 16 + l15] = __float2bfloat16(o[m][n][r]);
            if (l15 == 0) { pM[pbase + u] = mrun[m][r]; pL[pbase + u] = lrun[m][r]; }
        }
    }
}

// combine K-split partials -> ctxTop (256 threads, 4 u's per block)
__launch_bounds__(256)
__global__ void combine_kernel(const bf16* __restrict__ pO, const float* __restrict__ pM,
                               const float* __restrict__ pL, float* __restrict__ ctxTop)
{
    const int t = threadIdx.x, c = t & 63, ui = t >> 6;
    const int u = (blockIdx.x & 31) * 4 + ui, bh = blockIdx.x >> 5;
    float mstar = -1e30f;
    #pragma unroll
    for (int ks = 0; ks < KSd; ++ks)
        mstar = fmaxf(mstar, pM[(ks * 64 + bh) * Ud + u]);
    float lsum = 0.0f, osum = 0.0f;
    #pragma unroll
    for (int ks = 0; ks < KSd; ++ks) {
        float wgt = __expf(pM[(ks * 64 + bh) * Ud + u] - mstar);
        lsum += pL[(ks * 64 + bh) * Ud + u] * wgt;
        osum += bf2float(pO[(((size_t)ks * 64 + bh) * Ud + u) * 64 + c]) * wgt;
    }
    ctxTop[((size_t)bh * Ud + u) * 64 + c] = scrub(osum / lsum);
}

// ---------------------------------------------------------------- base row: concat(meanV) @ Wo + bo
__launch_bounds__(512)
__global__ void baseout_kernel(const float* __restrict__ meanV, const bf16* __restrict__ Wo,
                               const bf16* __restrict__ bo, float* __restrict__ baseOut)
{
    const int b = blockIdx.x, t = threadIdx.x;
    __shared__ float mv[512];
    mv[t] = meanV[b * 512 + t];
    __syncthreads();
    float acc = bf2float(bo[t]);
    for (int d = 0; d < 512; ++d)
        acc = fmaf(mv[d], bf2float(Wo[(size_t)d * 512 + t]), acc);
    baseOut[b * 512 + t] = acc;
}

// ---------------------------------------------------------------- per-(bh,u) delta rows (bf16 out)
__launch_bounds__(256)
__global__ void delta_kernel(const float* __restrict__ ctxTop, const float* __restrict__ meanV,
                             const bf16* __restrict__ Wo, bf16* __restrict__ deltaOut)
{
    const int u = blockIdx.x, bh = blockIdx.y, h = bh & 7, t = threadIdx.x;
    __shared__ float diff[64];
    if (t < 64) diff[t] = ctxTop[((size_t)bh * Ud + u) * 64 + t] - meanV[bh * 64 + t];
    __syncthreads();
    for (int n = t; n < 512; n += 256) {
        float acc = 0.0f;
        #pragma unroll 8
        for (int dd = 0; dd < 64; ++dd)
            acc = fmaf(diff[dd], bf2float(Wo[(size_t)(h * 64 + dd) * 512 + n]), acc);
        deltaOut[((size_t)bh * Ud + u) * 512 + n] = __float2bfloat16(acc);
    }
}

// ---------------------------------------------------------------- LayerNorms
__launch_bounds__(256)
__global__ void ln1_kernel(const bf16* __restrict__ x, const float* __restrict__ baseOut,
                           const int* __restrict__ rowCnt, const int* __restrict__ rowEnt,
                           const bf16* __restrict__ deltaOut,
                           const bf16* __restrict__ g, const bf16* __restrict__ bb,
                           bf16* __restrict__ x1)
{
    const int row = blockIdx.x, t = threadIdx.x;
    const int b = row >> 12;
    const size_t base = (size_t)row * 512;
    float v0 = bf2float(x[base + t])       + baseOut[b * 512 + t];
    float v1 = bf2float(x[base + t + 256]) + baseOut[b * 512 + t + 256];
    const int cnt = min(rowCnt[row], 8);
    for (int e = 0; e < cnt; ++e) {
        const bf16* dr = &deltaOut[(size_t)rowEnt[row * 8 + e] * 512];
        v0 += bf2float(dr[t]);
        v1 += bf2float(dr[t + 256]);
    }
    v0 = scrub(v0); v1 = scrub(v1);
    float s = v0 + v1, q = v0 * v0 + v1 * v1;
    s = wred_sum(s); q = wred_sum(q);
    __shared__ float sred[4], qred[4];
    int lane = t & 63, w = t >> 6;
    if (lane == 0) { sred[w] = s; qred[w] = q; }
    __syncthreads();
    float tot  = sred[0] + sred[1] + sred[2] + sred[3];
    float totq = qred[0] + qred[1] + qred[2] + qred[3];
    float mean = tot * (1.0f / 512.0f);
    float var  = fmaxf(totq * (1.0f / 512.0f) - mean * mean, 0.0f);
    float rstd = rsqrtf(var + 1e-6f);
    x1[base + t]       = __float2bfloat16((v0 - mean) * rstd * bf2float(g[t])       + bf2float(bb[t]));
    x1[base + t + 256] = __float2bfloat16((v1 - mean) * rstd * bf2float(g[t + 256]) + bf2float(bb[t + 256]));
}

__launch_bounds__(256)
__global__ void ln2_kernel(const bf16* __restrict__ x1, const bf16* __restrict__ ffn,
                           const bf16* __restrict__ g, const bf16* __restrict__ bb,
                           void* __restrict__ out, const int* __restrict__ flags)
{
    const int row = blockIdx.x, t = threadIdx.x;
    const size_t base = (size_t)row * 512;
    float v0 = bf2float(x1[base + t])       + bf2float(ffn[base + t]);
    float v1 = bf2float(x1[base + t + 256]) + bf2float(ffn[base + t + 256]);
    v0 = scrub(v0); v1 = scrub(v1);
    float s = v0 + v1, q = v0 * v0 + v1 * v1;
    s = wred_sum(s); q = wred_sum(q);
    __shared__ float sred[4], qred[4];
    int lane = t & 63, w = t >> 6;
    if (lane == 0) { sred[w] = s; qred[w] = q; }
    __syncthreads();
    float tot  = sred[0] + sred[1] + sred[2] + sred[3];
    float totq = qred[0] + qred[1] + qred[2] + qred[3];
    float mean = tot * (1.0f / 512.0f);
    float var  = fmaxf(totq * (1.0f / 512.0f) - mean * mean, 0.0f);
    float rstd = rsqrtf(var + 1e-6f);
    float o0 = (v0 - mean) * rstd * bf2float(g[t])       + bf2float(bb[t]);
    float o1 = (v1 - mean) * rstd * bf2float(g[t + 256]) + bf2float(bb[t + 256]);
    if (flags[0]) {
        ((float*)out)[base + t]       = o0;
        ((float*)out)[base + t + 256] = o1;
    } else {
        ((bf16*)out)[base + t]       = __float2bfloat16(o0);
        ((bf16*)out)[base + t + 256] = __float2bfloat16(o1);
    }
}

// ================================================================ launcher
extern "C" void kernel_launch(void* const* d_in, const int* in_sizes, int n_in,
                              void* d_out, int out_size, void* d_ws, size_t ws_size,
                              hipStream_t stream)
{
    const void* sraw = d_in[17];

    const size_t NQ = (size_t)MLd * Dd;          // 16,777,216 elements
    char* w = (char*)d_ws;
    size_t off = 0;
    auto alloc = [&](size_t bytes) { void* p = w + off; off += (bytes + 63) & ~size_t(63); return p; };
    bf16*  Qb   = (bf16*)alloc(NQ * 2);                       // 32 MiB
    bf16*  Kb   = (bf16*)alloc(NQ * 2);                       // 32 MiB (contiguous after Qb)
    bf16*  Vb   = (bf16*)alloc(NQ * 2);                       // 32 MiB (contiguous after Kb)
    bf16*  xc   = (bf16*)alloc(NQ * 2);                       // 32 MiB
    bf16*  WTq  = (bf16*)alloc(Dd * Dd * 2);                  // WTq/WTk/WTv contiguous
    bf16*  WTk  = (bf16*)alloc(Dd * Dd * 2);
    bf16*  WTv  = (bf16*)alloc(Dd * Dd * 2);
    bf16*  Woc  = (bf16*)alloc(Dd * Dd * 2);                  // untransposed
    bf16*  WT1f = (bf16*)alloc((size_t)Dd * DFFd * 2);        // [2048][512]
    bf16*  WT2f = (bf16*)alloc((size_t)DFFd * Dd * 2);        // [512][2048]
    bf16* bqc = (bf16*)alloc(Dd * 2);                         // bq/bk/bv contiguous
    bf16* bkc = (bf16*)alloc(Dd * 2);
    bf16* bvc = (bf16*)alloc(Dd * 2);
    bf16* boc = (bf16*)alloc(Dd * 2);
    bf16* g1c = (bf16*)alloc(Dd * 2);
    bf16* b1c = (bf16*)alloc(Dd * 2);
    bf16* b1fc= (bf16*)alloc(DFFd * 2);
    bf16* b2fc= (bf16*)alloc(Dd * 2);
    bf16* g2c = (bf16*)alloc(Dd * 2);
    bf16* b2c = (bf16*)alloc(Dd * 2);
    bf16*  pOb     = (bf16*)alloc((size_t)KSd * 64 * Ud * 64 * 2);   // 16 MiB
    float* Mv      = (float*)alloc((size_t)Bd * Hd * Ld * 4);        // 1 MiB
    float* ctxTop  = (float*)alloc((size_t)Bd * Hd * Ud * DHd * 4);  // 2 MiB
    float* meanV   = (float*)alloc(Bd * Hd * DHd * 4);
    float* baseOut = (float*)alloc(Bd * Dd * 4);
    int*   topIdx  = (int*)alloc(Bd * Hd * Ud * 4);
    int*   sidx    = (int*)alloc(128 * 4);
    int*   rowCnt  = (int*)alloc(MLd * 4);
    int*   rowEnt  = (int*)alloc(MLd * 8 * 4);
    int*   flags   = (int*)alloc(64);
    if (off > ws_size) return;

    // optional full-size FFN hidden buffer (128 MiB) if workspace allows
    bf16* h1full = nullptr;
    if (ws_size - off >= (size_t)MLd * DFFd * 2 + 64)
        h1full = (bf16*)alloc((size_t)MLd * DFFd * 2);

    // aliases (lifetimes disjoint, stream-serialized):
    bf16*  x1b  = Vb;                 // ln1 output (V dead)
    bf16*  h1b  = Qb;                 // FFN hidden chunk 16384x2048 spans Qb+Kb (both dead)
    bf16*  ffnb = xc;                 // FFN out (xc dead after ln1)
    bf16*  deltaOut = pOb;            // after combine_kernel, pO dead
    float* pM = Mv;                   // Mv dead after topk
    float* pL = Mv + KSd * 64 * Ud;

    detect_kernel<<<1, 256, 0, stream>>>(d_in[0], flags);

    auto conv = [&](int i, bf16* dst, int n) {
        conv_kernel<<<(n + 255) / 256, 256, 0, stream>>>(d_in[i], dst, n, flags);
    };
    conv(0,  xc, (int)NQ);
    convT_kernel<<<dim3(Dd / 32, Dd / 32), 256, 0, stream>>>(d_in[1], WTq, Dd, Dd, flags);
    convT_kernel<<<dim3(Dd / 32, Dd / 32), 256, 0, stream>>>(d_in[3], WTk, Dd, Dd, flags);
    convT_kernel<<<dim3(Dd / 32, Dd / 32), 256, 0, stream>>>(d_in[5], WTv, Dd, Dd, flags);
    convT_kernel<<<dim3(DFFd / 32, Dd / 32), 256, 0, stream>>>(d_in[11], WT1f, Dd, DFFd, flags);
    convT_kernel<<<dim3(Dd / 32, DFFd / 32), 256, 0, stream>>>(d_in[13], WT2f, DFFd, Dd, flags);
    conv(7,  Woc, Dd * Dd);
    conv(2,  bqc, Dd);  conv(4,  bkc, Dd);  conv(6,  bvc, Dd);  conv(8,  boc, Dd);
    conv(9,  g1c, Dd);  conv(10, b1c, Dd);
    conv(12, b1fc, DFFd); conv(14, b2fc, Dd);
    conv(15, g2c, Dd);  conv(16, b2c, Dd);

    zero_kernel<<<(MLd + 255) / 256, 256, 0, stream>>>(rowCnt, MLd);
    zero_kernel<<<(Bd * Hd * DHd + 255) / 256, 256, 0, stream>>>((int*)meanV, Bd * Hd * DHd);
    idx_kernel<<<1, 128, 0, stream>>>(sraw, sidx);

    // merged QKV projection: WTq/WTk/WTv and bq/bk/bv are contiguous; output
    // buffer selected by n>>9 inside the epilogue (Qb/Kb/Vb contiguous).
    mfma_gemm<false, true><<<dim3(12, 256), 256, 0, stream>>>(xc, WTq, bqc, Qb, MLd, 3 * Dd, Dd);

    m_kernel<<<dim3(Ld / 128, Bd * Hd), 256, 0, stream>>>(Qb, Kb, sidx, Mv);
    topk_kernel<<<Bd * Hd, 256, 0, stream>>>(Mv, topIdx);
    rows_kernel<<<Bd * Hd, 128, 0, stream>>>(topIdx, rowCnt, rowEnt);
    meanv_kernel<<<dim3(Bd * Hd, Ld / 64), 256, 0, stream>>>(Vb, meanV);

    attn_kernel<<<dim3(Bd * Hd, KSd), 256, 0, stream>>>(Qb, Kb, Vb, topIdx, pOb, pM, pL);
    combine_kernel<<<Bd * Hd * 32, 256, 0, stream>>>(pOb, pM, pL, ctxTop);

    baseout_kernel<<<Bd, 512, 0, stream>>>(meanV, Woc, boc, baseOut);
    delta_kernel<<<dim3(Ud, Bd * Hd), 256, 0, stream>>>(ctxTop, meanV, Woc, deltaOut);

    ln1_kernel<<<MLd, 256, 0, stream>>>(xc, baseOut, rowCnt, rowEnt, deltaOut, g1c, b1c, x1b);

    // FFN: single full-width dispatches when workspace allows, else 2-chunk.
    if (h1full) {
        mfma_gemm<true , false><<<dim3(16, 256), 256, 0, stream>>>(x1b, WT1f, b1fc, h1full, MLd, DFFd, Dd);
        mfma_gemm<false, false><<<dim3(4, 256), 256, 0, stream>>>(h1full, WT2f, b2fc, ffnb, MLd, Dd, DFFd);
    } else {
        for (int c = 0; c < 2; ++c) {
            mfma_gemm<true , false><<<dim3(16, 128), 256, 0, stream>>>(
                x1b + (size_t)c * 16384 * 512, WT1f, b1fc, h1b, 16384, DFFd, Dd);
            mfma_gemm<false, false><<<dim3(4, 128), 256, 0, stream>>>(
                h1b, WT2f, b2fc, ffnb + (size_t)c * 16384 * 512, 16384, Dd, DFFd);
        }
    }

    ln2_kernel<<<MLd, 256, 0, stream>>>(x1b, ffnb, g2c, b2c, d_out, flags);
}

// Round 8
// 658.545 us; speedup vs baseline: 2.4035x; 1.0159x over previous
//
#include <hip/hip_runtime.h>
#include <hip/hip_bf16.h>

using bf16 = __hip_bfloat16;

constexpr int Bd  = 8;
constexpr int Ld  = 4096;
constexpr int Dd  = 512;
constexpr int Hd  = 8;
constexpr int DHd = 64;
constexpr int DFFd= 2048;
constexpr int Ud  = 128;           // TOP_U
constexpr int MLd = Bd * Ld;       // 32768 rows
constexpr int KSd = 16;            // attention K-split (256 keys per block)

typedef short          bf16x8 __attribute__((ext_vector_type(8)));
typedef unsigned short u16x8  __attribute__((ext_vector_type(8)));
typedef float          f32x4  __attribute__((ext_vector_type(4)));

__device__ __forceinline__ float bf2float(bf16 v) { return __bfloat162float(v); }

__device__ __forceinline__ float wred_sum(float v) {
    #pragma unroll
    for (int o = 32; o > 0; o >>= 1) v += __shfl_xor(v, o);
    return v;
}
__device__ __forceinline__ float scrub(float v) {       // NaN/Inf -> 0
    return (fabsf(v) < 1e20f) ? v : 0.0f;
}
__device__ __forceinline__ short f2bs(float f) {        // float -> bf16 bits
    bf16 h = __float2bfloat16(f);
    return *reinterpret_cast<short*>(&h);
}

// async global->LDS, 16B per lane; LDS dest = wave-uniform base + lane*16
__device__ __forceinline__ void gload_lds16(const bf16* g, bf16* lds_base) {
    __builtin_amdgcn_global_load_lds((const __attribute__((address_space(1))) void*)g,
                                     (__attribute__((address_space(3))) void*)lds_base,
                                     16, 0, 0);
}

// ---------------------------------------------------------------- dtype detector
__global__ void detect_kernel(const void* xraw, int* flags) {
    const unsigned short* u = (const unsigned short*)xraw;
    __shared__ int cnt;
    if (threadIdx.x == 0) cnt = 0;
    __syncthreads();
    int local = 0;
    for (int i = threadIdx.x; i < 1024; i += 256) {
        int e = (u[2 * i] >> 7) & 0xFF;
        if (e >= 96 && e <= 142) local++;
    }
    atomicAdd(&cnt, local);
    __syncthreads();
    if (threadIdx.x == 0) flags[0] = (cnt < 512) ? 1 : 0;
}

// canonicalize any float tensor to bf16
__global__ void conv_kernel(const void* raw, bf16* dst, int n, const int* flags) {
    int i = blockIdx.x * 256 + threadIdx.x;
    if (i >= n) return;
    if (flags[0]) dst[i] = __float2bfloat16(((const float*)raw)[i]);
    else          dst[i] = ((const bf16*)raw)[i];
}

// batched small-tensor canonicalize + zero-fill: one block per descriptor
struct ConvBatch {
    const void* src[12];
    void*       dst[12];
    int         n[12];
    int         mode[12];     // 0 = conv->bf16, 1 = zero int32
};
__global__ void conv_batch_kernel(ConvBatch cb, const int* __restrict__ flags) {
    const int d = blockIdx.x, n = cb.n[d];
    if (cb.mode[d] == 1) {
        int* p = (int*)cb.dst[d];
        for (int i = threadIdx.x; i < n; i += 256) p[i] = 0;
    } else {
        bf16* p = (bf16*)cb.dst[d];
        for (int i = threadIdx.x; i < n; i += 256) {
            if (flags[0]) p[i] = __float2bfloat16(((const float*)cb.src[d])[i]);
            else          p[i] = ((const bf16*)cb.src[d])[i];
        }
    }
}

// canonicalize + transpose weight: in W[K][N] -> out WT[N][K] (bf16)
__global__ void convT_kernel(const void* raw, bf16* dst, int K, int N, const int* flags) {
    __shared__ bf16 tile[32][33];
    const int k0 = blockIdx.y * 32, n0 = blockIdx.x * 32;
    const int tx = threadIdx.x & 31, ty = threadIdx.x >> 5;     // 32 x 8
    #pragma unroll
    for (int p = 0; p < 4; ++p) {
        int k = k0 + ty + p * 8, n = n0 + tx;
        float v = flags[0] ? ((const float*)raw)[(size_t)k * N + n]
                           : bf2float(((const bf16*)raw)[(size_t)k * N + n]);
        tile[ty + p * 8][tx] = __float2bfloat16(v);
    }
    __syncthreads();
    #pragma unroll
    for (int p = 0; p < 4; ++p) {
        int n = n0 + ty + p * 8, k = k0 + tx;
        dst[(size_t)n * K + k] = tile[tx][ty + p * 8];
    }
}

__global__ void zero_kernel(int* p, int n) {
    int i = blockIdx.x * 256 + threadIdx.x;
    if (i < n) p[i] = 0;
}

// sample_idx: int32 or int64 device layout; clamped to [0, Ld)
__global__ void idx_kernel(const void* raw, int* out) {
    const int* r32 = (const int*)raw;
    __shared__ int is64;
    int t = threadIdx.x;                       // 128 threads
    if (t == 0) is64 = 1;
    __syncthreads();
    if (t < 64 && r32[2 * t + 1] != 0) is64 = 0;
    __syncthreads();
    int v = is64 ? r32[2 * t] : r32[t];
    out[t] = min(max(v, 0), Ld - 1);
}

// ---------------------------------------------------------------- MFMA GEMM
// C[m,n] = sum_k X[m,k]*WT[n,k] + bias[n]; 128x128 tile, BK=64, 4 waves.
// T3-minimum 2-phase pipeline: double-buffered LDS; tile t+1's gload_lds
// issued BEFORE tile t's ds_read+MFMA, one barrier per iteration. LDS 64 KiB.
// XOR-chunk swizzle (conflict-free) + bijective XCD block swizzle (T1).
// QKV3: N spans 3 concatenated weight blocks; output buffer = n>>9.
template<bool RELU, bool QKV3>
__launch_bounds__(256)
__global__ void mfma_gemm(const bf16* __restrict__ X, const bf16* __restrict__ WT,
                          const bf16* __restrict__ bias, bf16* __restrict__ C,
                          int M, int N, int K)
{
    __shared__ bf16 As[2][128 * 64];   // 32 KiB, swizzled, double-buffered
    __shared__ bf16 Bs[2][128 * 64];   // 32 KiB
    const int t = threadIdx.x;
    const int lane = t & 63, wave = t >> 6;
    const int wr = wave >> 1, wc = wave & 1;    // 2x2 wave grid
    const int quad = lane >> 4, l15 = lane & 15;

    const int nwg = gridDim.x * gridDim.y;
    int wg = blockIdx.y * gridDim.x + blockIdx.x;
    if ((nwg & 7) == 0)                          // bijective chunked XCD swizzle
        wg = (wg & 7) * (nwg >> 3) + (wg >> 3);
    const int m0 = (wg / gridDim.x) * 128, n0 = (wg % gridDim.x) * 128;

    const int rseg = lane >> 3;                  // row within 8-row segment
    const int cs   = (lane & 7) ^ rseg;          // pre-swizzled source chunk

    auto stage = [&](int buf, int k0) {
        #pragma unroll
        for (int p = 0; p < 4; ++p) {
            const int sg = wave * 4 + p;         // 16 segments of 8 rows
            const int r  = sg * 8 + rseg;
            gload_lds16(&X [(size_t)(m0 + r) * K + k0 + cs * 8], &As[buf][sg * 512]);
            gload_lds16(&WT[(size_t)(n0 + r) * K + k0 + cs * 8], &Bs[buf][sg * 512]);
        }
    };

    f32x4 acc[4][4] = {};

    stage(0, 0);
    __syncthreads();                             // drains vmcnt -> buf0 ready
    int cur = 0;
    const int NI = K >> 6;
    for (int it = 0; it < NI; ++it) {
        if (it + 1 < NI) stage(cur ^ 1, (it + 1) << 6);   // prefetch next tile
        #pragma unroll
        for (int kk = 0; kk < 2; ++kk) {
            const int ch = ((kk * 4 + quad) ^ (l15 & 7)) * 8;
            bf16x8 a[4], b[4];
            #pragma unroll
            for (int i = 0; i < 4; ++i) {
                a[i] = *(const bf16x8*)&As[cur][(wr * 64 + i * 16 + l15) * 64 + ch];
                b[i] = *(const bf16x8*)&Bs[cur][(wc * 64 + i * 16 + l15) * 64 + ch];
            }
            #pragma unroll
            for (int i = 0; i < 4; ++i)
                #pragma unroll
                for (int j = 0; j < 4; ++j)
                    acc[i][j] = __builtin_amdgcn_mfma_f32_16x16x32_bf16(a[i], b[j], acc[i][j], 0, 0, 0);
        }
        if (it + 1 < NI) __syncthreads();        // waits prefetch (latency hidden)
        cur ^= 1;
    }
    // epilogue: D elem (m = quad*4+reg, n = lane&15) within each 16x16 tile
    #pragma unroll
    for (int j = 0; j < 4; ++j) {
        int n = n0 + wc * 64 + j * 16 + l15;
        float bi = bf2float(bias[n]);
        bf16* cb;
        size_t stride;
        if (QKV3) {
            cb = C + (size_t)(n >> 9) * ((size_t)MLd * Dd) + (n & (Dd - 1));
            stride = Dd;
        } else {
            cb = C + n;
            stride = (size_t)N;
        }
        #pragma unroll
        for (int i = 0; i < 4; ++i) {
            #pragma unroll
            for (int r = 0; r < 4; ++r) {
                int m = m0 + wr * 64 + i * 16 + quad * 4 + r;
                float v = acc[i][j][r] + bi;
                if (RELU) v = fmaxf(v, 0.0f);
                cb[(size_t)m * stride] = __float2bfloat16(v);
            }
        }
    }
}

// ---------------------------------------------------------------- M = max-mean of sampled scores (MFMA)
__launch_bounds__(256)
__global__ void m_kernel(const bf16* __restrict__ Q, const bf16* __restrict__ Kg,
                         const int* __restrict__ sidx, float* __restrict__ Mv)
{
    __shared__ __align__(16) short Qs[128 * 64];   // [row][d], swizzled, 16 KiB
    __shared__ __align__(16) short Ks[128 * 64];   // [sample][d], swizzled, 16 KiB
    __shared__ int sidxs[128];

    const int t = threadIdx.x, lane = t & 63, w = t >> 6;
    const int l15 = lane & 15, quad = lane >> 4;
    const int l0 = blockIdx.x * 128;
    const int bh = blockIdx.y, b = bh >> 3, h = bh & 7;

    if (t < 128) sidxs[t] = sidx[t];
    __syncthreads();

    const int rseg = lane >> 3;                    // row within 8-row segment
    const int cs   = (lane & 7) ^ rseg;            // pre-swizzled source chunk
    #pragma unroll
    for (int sg4 = 0; sg4 < 4; ++sg4) {
        const int sg = w * 4 + sg4;                // segment 0..15
        const int r  = sg * 8 + rseg;              // row 0..127
        gload_lds16(Q  + ((size_t)(b * Ld + l0 + r))    * Dd + h * 64 + cs * 8,
                    (bf16*)&Qs[sg * 512]);
        gload_lds16(Kg + ((size_t)(b * Ld + sidxs[r])) * Dd + h * 64 + cs * 8,
                    (bf16*)&Ks[sg * 512]);
    }
    __syncthreads();

    f32x4 s[2][8] = {};
    #pragma unroll
    for (int kk = 0; kk < 2; ++kk) {
        const int ch = ((kk * 4 + quad) ^ (l15 & 7)) * 8;
        bf16x8 qa[2], kb[8];
        #pragma unroll
        for (int mt = 0; mt < 2; ++mt)
            qa[mt] = *(const bf16x8*)&Qs[(w * 32 + mt * 16 + l15) * 64 + ch];
        #pragma unroll
        for (int nt = 0; nt < 8; ++nt)
            kb[nt] = *(const bf16x8*)&Ks[(nt * 16 + l15) * 64 + ch];
        #pragma unroll
        for (int mt = 0; mt < 2; ++mt)
            #pragma unroll
            for (int nt = 0; nt < 8; ++nt)
                s[mt][nt] = __builtin_amdgcn_mfma_f32_16x16x32_bf16(qa[mt], kb[nt], s[mt][nt], 0, 0, 0);
    }

    // rows = w*32 + mt*16 + quad*4 + r; cols = nt*16 + l15
    #pragma unroll
    for (int mt = 0; mt < 2; ++mt) {
        #pragma unroll
        for (int r = 0; r < 4; ++r) {
            float vmax = -1e30f, vsum = 0.0f;
            #pragma unroll
            for (int nt = 0; nt < 8; ++nt) {
                float v = s[mt][nt][r];
                vmax = fmaxf(vmax, v); vsum += v;
            }
            #pragma unroll
            for (int off = 1; off < 16; off <<= 1) {
                vmax = fmaxf(vmax, __shfl_xor(vmax, off));
                vsum += __shfl_xor(vsum, off);
            }
            if (l15 == 0) {
                const int row = w * 32 + mt * 16 + quad * 4 + r;
                Mv[(size_t)bh * Ld + l0 + row] = vmax - vsum * (1.0f / 128.0f);
            }
        }
    }
}

// ---------------------------------------------------------------- top-128 via 8-bit radix select
__launch_bounds__(256)
__global__ void topk_kernel(const float* __restrict__ Mv, int* __restrict__ topIdx)
{
    __shared__ unsigned ukey[4096];                 // 16 KiB
    __shared__ short listA[4096], listB[4096];      // 16 KiB candidate lists
    __shared__ int hist[256];
    __shared__ int outCnt, candCnt, selB, aboveK;
    const int bh = blockIdx.x, t = threadIdx.x;

    for (int i = t; i < 4096; i += 256) {
        unsigned u = __float_as_uint(Mv[(size_t)bh * Ld + i]);
        ukey[i] = (u & 0x80000000u) ? ~u : (u | 0x80000000u);   // sort-monotonic
    }
    if (t == 0) outCnt = 0;
    __syncthreads();

    int K = Ud;                                     // remaining to select
    #pragma unroll
    for (int r = 0; r < 4; ++r) {
        const int shift = 24 - 8 * r;
        hist[t] = 0;
        __syncthreads();
        const int n = (r == 0) ? 4096 : candCnt;
        const short* cur = (r & 1) ? listB : listA;
        for (int i = t; i < n; i += 256) {
            int idx = (r == 0) ? i : cur[i];
            atomicAdd(&hist[(ukey[idx] >> shift) & 0xFF], 1);
        }
        __syncthreads();
        if (t == 0) {
            int cum = 0, b = 255;
            for (; b > 0; --b) {
                if (cum + hist[b] >= K) break;
                cum += hist[b];
            }
            selB = b; aboveK = cum; candCnt = 0;
        }
        __syncthreads();
        const int sb = selB;
        short* nxt = (r & 1) ? listA : listB;
        for (int i = t; i < n; i += 256) {
            int idx = (r == 0) ? i : cur[i];
            int by = (ukey[idx] >> shift) & 0xFF;
            if (by > sb) {
                int p = atomicAdd(&outCnt, 1);
                topIdx[bh * Ud + p] = idx;
            } else if (by == sb) {
                int p = atomicAdd(&candCnt, 1);
                nxt[p] = (short)idx;
            }
        }
        __syncthreads();
        K -= aboveK;
        if (K == 0) break;
    }
    // leftover K candidates all share an identical 32-bit key: take any K
    if (K > 0) {                                    // final list is listA (r=3 wrote it)
        for (int i = t; i < K; i += 256) {
            int p = atomicAdd(&outCnt, 1);
            topIdx[bh * Ud + p] = listA[i];
        }
    }
}

// ---------------------------------------------------------------- per-row sparse-entry list
__global__ void rows_kernel(const int* __restrict__ topIdx, int* __restrict__ rowCnt,
                            int* __restrict__ rowEnt)
{
    const int bh = blockIdx.x, u = threadIdx.x, b = bh >> 3;
    const int lq = topIdx[bh * Ud + u];
    const int row = b * Ld + lq;
    int slot = atomicAdd(&rowCnt[row], 1) & 7;
    rowEnt[row * 8 + slot] = bh * Ud + u;
}

// ---------------------------------------------------------------- meanV over L per (b,h,d)
__launch_bounds__(256)
__global__ void meanv_kernel(const bf16* __restrict__ V, float* __restrict__ meanV)
{
    const int bh = blockIdx.x, b = bh >> 3, h = bh & 7;
    const int l0 = blockIdx.y * 64;
    const int t = threadIdx.x;
    const int d = t & 63, part = t >> 6;
    float s = 0.0f;
    #pragma unroll
    for (int p = 0; p < 16; ++p) {
        int l = l0 + part + p * 4;
        s += bf2float(V[((size_t)(b * Ld + l)) * Dd + h * 64 + d]);
    }
    __shared__ float red[256];
    red[t] = s;
    __syncthreads();
    if (t < 64) {
        float tot = red[t] + red[64 + t] + red[128 + t] + red[192 + t];
        atomicAdd(&meanV[bh * 64 + t], tot * (1.0f / 4096.0f));
    }
}

// ---------------------------------------------------------------- MFMA flash attention (K-split partials)
__launch_bounds__(256, 3)
__global__ void attn_kernel(const bf16* __restrict__ Qg, const bf16* __restrict__ Kg,
                            const bf16* __restrict__ Vg, const int* __restrict__ topIdx,
                            bf16* __restrict__ pO, float* __restrict__ pM, float* __restrict__ pL)
{
    __shared__ __align__(16) short KsS[2][64 * 64];   // [key][d], swizzled, 16 KiB
    __shared__ __align__(16) short VsS[2][64 * 72];   // [d][key], padded, 18 KiB
    __shared__ __align__(16) short PsS[4][32 * 72];   // per-wave [q][key], 18 KiB

    const int t = threadIdx.x, lane = t & 63, w = t >> 6;
    const int l15 = lane & 15, quad = lane >> 4;
    const int bh = blockIdx.x, ks = blockIdx.y;
    const int b = bh >> 3, h = bh & 7;
    const int key0 = ks * (Ld / KSd);
    constexpr int NT = (Ld / KSd) / 64;               // 4 kv-tiles

    // Q fragments (A operand): row = l15 (+16m), k = quad*8 within 32-wide kk step
    bf16x8 qf[2][2];
    #pragma unroll
    for (int m = 0; m < 2; ++m) {
        const int u  = w * 32 + m * 16 + l15;
        const int lq = topIdx[bh * Ud + u];
        const bf16* qr = Qg + ((size_t)(b * Ld + lq)) * Dd + h * 64;
        qf[m][0] = *(const bf16x8*)(qr + quad * 8);
        qf[m][1] = *(const bf16x8*)(qr + 32 + quad * 8);
    }

    const int vkey = t >> 2, vd0 = (t & 3) * 16;
    u16x8 vr0, vr1;

    auto loadV = [&](int tt) {   // V tile -> regs (issued early, coalesced 16B)
        const bf16* vs = Vg + ((size_t)(b * Ld + key0 + tt * 64 + vkey)) * Dd + h * 64 + vd0;
        vr0 = *(const u16x8*)vs;
        vr1 = *(const u16x8*)(vs + 8);
    };
    auto stageK = [&](int buf, int tt) {  // K tile -> LDS via gload_lds, src pre-swizzled
        const int kb0 = key0 + tt * 64;
        #pragma unroll
        for (int sz = 0; sz < 2; ++sz) {
            const int sg = w * 2 + sz;                  // 8-row segment
            const int r  = sg * 8 + (lane >> 3);
            const int cs = (lane & 7) ^ (lane >> 3);    // inverse swizzle on source
            gload_lds16(Kg + ((size_t)(b * Ld + kb0 + r)) * Dd + h * 64 + cs * 8,
                        (bf16*)&KsS[buf][sg * 512]);
        }
    };
    auto writeV = [&](int buf) {  // regs -> transposed LDS
        #pragma unroll
        for (int j = 0; j < 8; ++j) {
            VsS[buf][(vd0 + j) * 72 + vkey]     = (short)vr0[j];
            VsS[buf][(vd0 + 8 + j) * 72 + vkey] = (short)vr1[j];
        }
    };

    float mrun[2][4], lrun[2][4];
    f32x4 o[2][4] = {};
    #pragma unroll
    for (int m = 0; m < 2; ++m)
        #pragma unroll
        for (int r = 0; r < 4; ++r) { mrun[m][r] = -1e30f; lrun[m][r] = 0.0f; }

    loadV(0); stageK(0, 0); writeV(0);
    __syncthreads();

    short* PsW = &PsS[w][0];
    for (int tt = 0; tt < NT; ++tt) {
        const int cur = tt & 1;
        if (tt + 1 < NT) { loadV(tt + 1); stageK(cur ^ 1, tt + 1); }

        // ---- QK^T -> S (f32), 16 MFMA
        const short* KsB = &KsS[cur][0];
        f32x4 s[2][4] = {};
        #pragma unroll
        for (int kk = 0; kk < 2; ++kk) {
            bf16x8 kb[4];
            #pragma unroll
            for (int n = 0; n < 4; ++n)
                kb[n] = *(const bf16x8*)&KsB[(n * 16 + l15) * 64 +
                                             (((kk * 4 + quad) ^ (l15 & 7)) * 8)];
            #pragma unroll
            for (int m = 0; m < 2; ++m)
                #pragma unroll
                for (int n = 0; n < 4; ++n)
                    s[m][n] = __builtin_amdgcn_mfma_f32_16x16x32_bf16(qf[m][kk], kb[n], s[m][n], 0, 0, 0);
        }

        // ---- online softmax; rows = quad*4+r (+16m), cols = l15 (+16n)
        #pragma unroll
        for (int m = 0; m < 2; ++m) {
            #pragma unroll
            for (int r = 0; r < 4; ++r) {
                float sv[4];
                #pragma unroll
                for (int n = 0; n < 4; ++n) sv[n] = s[m][n][r] * 0.125f;
                float vm = fmaxf(fmaxf(sv[0], sv[1]), fmaxf(sv[2], sv[3]));
                #pragma unroll
                for (int off = 1; off < 16; off <<= 1) vm = fmaxf(vm, __shfl_xor(vm, off));
                const float mn = fmaxf(mrun[m][r], vm);
                const float al = __expf(mrun[m][r] - mn);
                float ps = 0.0f;
                #pragma unroll
                for (int n = 0; n < 4; ++n) { sv[n] = __expf(sv[n] - mn); ps += sv[n]; }
                #pragma unroll
                for (int off = 1; off < 16; off <<= 1) ps += __shfl_xor(ps, off);
                lrun[m][r] = lrun[m][r] * al + ps;
                mrun[m][r] = mn;
                const int qrow = m * 16 + quad * 4 + r;
                #pragma unroll
                for (int n = 0; n < 4; ++n) {
                    PsW[qrow * 72 + n * 16 + l15] = f2bs(sv[n]);
                    o[m][n][r] *= al;
                }
            }
        }

        if (tt + 1 < NT) writeV(cur ^ 1);   // into other buffer; hides under PV

        // ---- PV: O += P * V, 16 MFMA
        const short* VsB = &VsS[cur][0];
        #pragma unroll
        for (int kk = 0; kk < 2; ++kk) {
            bf16x8 pa[2], vb[4];
            #pragma unroll
            for (int m = 0; m < 2; ++m)
                pa[m] = *(const bf16x8*)&PsW[(m * 16 + l15) * 72 + kk * 32 + quad * 8];
            #pragma unroll
            for (int n = 0; n < 4; ++n)
                vb[n] = *(const bf16x8*)&VsB[(n * 16 + l15) * 72 + kk * 32 + quad * 8];
            #pragma unroll
            for (int m = 0; m < 2; ++m)
                #pragma unroll
                for (int n = 0; n < 4; ++n)
                    o[m][n] = __builtin_amdgcn_mfma_f32_16x16x32_bf16(pa[m], vb[n], o[m][n], 0, 0, 0);
        }
        __syncthreads();
    }

    const size_t pbase = ((size_t)(ks * 64 + bh)) * Ud;
    #pragma unroll
    for (int m = 0; m < 2; ++m) {
        #pragma unroll
        for (int r = 0; r < 4; ++r) {
            const int u = w * 32 + m * 16 + quad * 4 + r;
            #pragma unroll
            for (int n = 0; n < 4; ++n)
                pO[(pbase + u) * 64 + n * 16 + l15] = __float2bfloat16(o[m][n][r]);
            if (l15 == 0) { pM[pbase + u] = mrun[m][r]; pL[pbase + u] = lrun[m][r]; }
        }
    }
}

// combine K-split partials -> ctxTop (256 threads, 4 u's per block)
__launch_bounds__(256)
__global__ void combine_kernel(const bf16* __restrict__ pO, const float* __restrict__ pM,
                               const float* __restrict__ pL, float* __restrict__ ctxTop)
{
    const int t = threadIdx.x, c = t & 63, ui = t >> 6;
    const int u = (blockIdx.x & 31) * 4 + ui, bh = blockIdx.x >> 5;
    float mstar = -1e30f;
    #pragma unroll
    for (int ks = 0; ks < KSd; ++ks)
        mstar = fmaxf(mstar, pM[(ks * 64 + bh) * Ud + u]);
    float lsum = 0.0f, osum = 0.0f;
    #pragma unroll
    for (int ks = 0; ks < KSd; ++ks) {
        float wgt = __expf(pM[(ks * 64 + bh) * Ud + u] - mstar);
        lsum += pL[(ks * 64 + bh) * Ud + u] * wgt;
        osum += bf2float(pO[(((size_t)ks * 64 + bh) * Ud + u) * 64 + c]) * wgt;
    }
    ctxTop[((size_t)bh * Ud + u) * 64 + c] = scrub(osum / lsum);
}

// ---------------------------------------------------------------- base row: concat(meanV) @ Wo + bo
// grid (Bd, 4): 32 blocks; 2 threads per output column, 256 d's each.
__launch_bounds__(256)
__global__ void baseout_kernel(const float* __restrict__ meanV, const bf16* __restrict__ Wo,
                               const bf16* __restrict__ bo, float* __restrict__ baseOut)
{
    const int b = blockIdx.x, t = threadIdx.x;
    const int n = blockIdx.y * 128 + (t >> 1), half = t & 1;
    __shared__ float mv[512];
    mv[t] = meanV[b * 512 + t];
    mv[t + 256] = meanV[b * 512 + t + 256];
    __syncthreads();
    float acc = 0.0f;
    const int d0 = half * 256;
    #pragma unroll 8
    for (int d = 0; d < 256; ++d)
        acc = fmaf(mv[d0 + d], bf2float(Wo[(size_t)(d0 + d) * 512 + n]), acc);
    acc += __shfl_xor(acc, 1);
    if (half == 0) baseOut[b * 512 + n] = acc + bf2float(bo[n]);
}

// ---------------------------------------------------------------- LayerNorms
// ln1 with fused delta: each sparse entry's (ctxTop-meanV)@Wo row computed
// inline (f32, no bf16 round-trip through deltaOut; removes a dispatch +
// 32 MiB write/read). cnt is block-uniform -> barriers are safe.
__launch_bounds__(256)
__global__ void ln1_kernel(const bf16* __restrict__ x, const float* __restrict__ baseOut,
                           const int* __restrict__ rowCnt, const int* __restrict__ rowEnt,
                           const float* __restrict__ ctxTop, const float* __restrict__ meanV,
                           const bf16* __restrict__ Wo,
                           const bf16* __restrict__ g, const bf16* __restrict__ bb,
                           bf16* __restrict__ x1)
{
    const int row = blockIdx.x, t = threadIdx.x;
    const int b = row >> 12;
    const size_t base = (size_t)row * 512;
    float v0 = bf2float(x[base + t])       + baseOut[b * 512 + t];
    float v1 = bf2float(x[base + t + 256]) + baseOut[b * 512 + t + 256];
    const int cnt = min(rowCnt[row], 8);
    __shared__ float diff[64];
    for (int e = 0; e < cnt; ++e) {
        const int bhu = rowEnt[row * 8 + e];
        const int bh = bhu >> 7, u = bhu & 127, h = bh & 7;
        if (t < 64) diff[t] = ctxTop[((size_t)bh * Ud + u) * 64 + t] - meanV[bh * 64 + t];
        __syncthreads();
        float a0 = 0.0f, a1 = 0.0f;
        #pragma unroll 8
        for (int dd = 0; dd < 64; ++dd) {
            const float df = diff[dd];
            const bf16* wr = Wo + (size_t)(h * 64 + dd) * 512;
            a0 = fmaf(df, bf2float(wr[t]), a0);
            a1 = fmaf(df, bf2float(wr[t + 256]), a1);
        }
        v0 += a0; v1 += a1;
        __syncthreads();
    }
    v0 = scrub(v0); v1 = scrub(v1);
    float s = v0 + v1, q = v0 * v0 + v1 * v1;
    s = wred_sum(s); q = wred_sum(q);
    __shared__ float sred[4], qred[4];
    int lane = t & 63, w = t >> 6;
    if (lane == 0) { sred[w] = s; qred[w] = q; }
    __syncthreads();
    float tot  = sred[0] + sred[1] + sred[2] + sred[3];
    float totq = qred[0] + qred[1] + qred[2] + qred[3];
    float mean = tot * (1.0f / 512.0f);
    float var  = fmaxf(totq * (1.0f / 512.0f) - mean * mean, 0.0f);
    float rstd = rsqrtf(var + 1e-6f);
    x1[base + t]       = __float2bfloat16((v0 - mean) * rstd * bf2float(g[t])       + bf2float(bb[t]));
    x1[base + t + 256] = __float2bfloat16((v1 - mean) * rstd * bf2float(g[t + 256]) + bf2float(bb[t + 256]));
}

__launch_bounds__(256)
__global__ void ln2_kernel(const bf16* __restrict__ x1, const bf16* __restrict__ ffn,
                           const bf16* __restrict__ g, const bf16* __restrict__ bb,
                           void* __restrict__ out, const int* __restrict__ flags)
{
    const int row = blockIdx.x, t = threadIdx.x;
    const size_t base = (size_t)row * 512;
    float v0 = bf2float(x1[base + t])       + bf2float(ffn[base + t]);
    float v1 = bf2float(x1[base + t + 256]) + bf2float(ffn[base + t + 256]);
    v0 = scrub(v0); v1 = scrub(v1);
    float s = v0 + v1, q = v0 * v0 + v1 * v1;
    s = wred_sum(s); q = wred_sum(q);
    __shared__ float sred[4], qred[4];
    int lane = t & 63, w = t >> 6;
    if (lane == 0) { sred[w] = s; qred[w] = q; }
    __syncthreads();
    float tot  = sred[0] + sred[1] + sred[2] + sred[3];
    float totq = qred[0] + qred[1] + qred[2] + qred[3];
    float mean = tot * (1.0f / 512.0f);
    float var  = fmaxf(totq * (1.0f / 512.0f) - mean * mean, 0.0f);
    float rstd = rsqrtf(var + 1e-6f);
    float o0 = (v0 - mean) * rstd * bf2float(g[t])       + bf2float(bb[t]);
    float o1 = (v1 - mean) * rstd * bf2float(g[t + 256]) + bf2float(bb[t + 256]);
    if (flags[0]) {
        ((float*)out)[base + t]       = o0;
        ((float*)out)[base + t + 256] = o1;
    } else {
        ((bf16*)out)[base + t]       = __float2bfloat16(o0);
        ((bf16*)out)[base + t + 256] = __float2bfloat16(o1);
    }
}

// ================================================================ launcher
extern "C" void kernel_launch(void* const* d_in, const int* in_sizes, int n_in,
                              void* d_out, int out_size, void* d_ws, size_t ws_size,
                              hipStream_t stream)
{
    const void* sraw = d_in[17];

    const size_t NQ = (size_t)MLd * Dd;          // 16,777,216 elements
    char* w = (char*)d_ws;
    size_t off = 0;
    auto alloc = [&](size_t bytes) { void* p = w + off; off += (bytes + 63) & ~size_t(63); return p; };
    bf16*  Qb   = (bf16*)alloc(NQ * 2);                       // 32 MiB
    bf16*  Kb   = (bf16*)alloc(NQ * 2);                       // 32 MiB (contiguous after Qb)
    bf16*  Vb   = (bf16*)alloc(NQ * 2);                       // 32 MiB (contiguous after Kb)
    bf16*  xc   = (bf16*)alloc(NQ * 2);                       // 32 MiB
    bf16*  WTq  = (bf16*)alloc(Dd * Dd * 2);                  // WTq/WTk/WTv contiguous
    bf16*  WTk  = (bf16*)alloc(Dd * Dd * 2);
    bf16*  WTv  = (bf16*)alloc(Dd * Dd * 2);
    bf16*  Woc  = (bf16*)alloc(Dd * Dd * 2);                  // untransposed
    bf16*  WT1f = (bf16*)alloc((size_t)Dd * DFFd * 2);        // [2048][512]
    bf16*  WT2f = (bf16*)alloc((size_t)DFFd * Dd * 2);        // [512][2048]
    bf16* bqc = (bf16*)alloc(Dd * 2);                         // bq/bk/bv contiguous
    bf16* bkc = (bf16*)alloc(Dd * 2);
    bf16* bvc = (bf16*)alloc(Dd * 2);
    bf16* boc = (bf16*)alloc(Dd * 2);
    bf16* g1c = (bf16*)alloc(Dd * 2);
    bf16* b1c = (bf16*)alloc(Dd * 2);
    bf16* b1fc= (bf16*)alloc(DFFd * 2);
    bf16* b2fc= (bf16*)alloc(Dd * 2);
    bf16* g2c = (bf16*)alloc(Dd * 2);
    bf16* b2c = (bf16*)alloc(Dd * 2);
    bf16*  pOb     = (bf16*)alloc((size_t)KSd * 64 * Ud * 64 * 2);   // 16 MiB
    float* Mv      = (float*)alloc((size_t)Bd * Hd * Ld * 4);        // 1 MiB
    float* ctxTop  = (float*)alloc((size_t)Bd * Hd * Ud * DHd * 4);  // 2 MiB
    float* meanV   = (float*)alloc(Bd * Hd * DHd * 4);
    float* baseOut = (float*)alloc(Bd * Dd * 4);
    int*   topIdx  = (int*)alloc(Bd * Hd * Ud * 4);
    int*   sidx    = (int*)alloc(128 * 4);
    int*   rowCnt  = (int*)alloc(MLd * 4);
    int*   rowEnt  = (int*)alloc(MLd * 8 * 4);
    int*   flags   = (int*)alloc(64);
    if (off > ws_size) return;

    // optional full-size FFN hidden buffer (128 MiB) if workspace allows
    bf16* h1full = nullptr;
    if (ws_size - off >= (size_t)MLd * DFFd * 2 + 64)
        h1full = (bf16*)alloc((size_t)MLd * DFFd * 2);

    // aliases (lifetimes disjoint, stream-serialized):
    bf16*  x1b  = Vb;                 // ln1 output (V dead)
    bf16*  h1b  = Qb;                 // FFN hidden chunk 16384x2048 spans Qb+Kb (both dead)
    bf16*  ffnb = xc;                 // FFN out (xc dead after ln1)
    float* pM = Mv;                   // Mv dead after topk
    float* pL = Mv + KSd * 64 * Ud;

    detect_kernel<<<1, 256, 0, stream>>>(d_in[0], flags);

    conv_kernel<<<((int)NQ + 255) / 256, 256, 0, stream>>>(d_in[0], xc, (int)NQ, flags);
    convT_kernel<<<dim3(Dd / 32, Dd / 32), 256, 0, stream>>>(d_in[1], WTq, Dd, Dd, flags);
    convT_kernel<<<dim3(Dd / 32, Dd / 32), 256, 0, stream>>>(d_in[3], WTk, Dd, Dd, flags);
    convT_kernel<<<dim3(Dd / 32, Dd / 32), 256, 0, stream>>>(d_in[5], WTv, Dd, Dd, flags);
    convT_kernel<<<dim3(DFFd / 32, Dd / 32), 256, 0, stream>>>(d_in[11], WT1f, Dd, DFFd, flags);
    convT_kernel<<<dim3(Dd / 32, DFFd / 32), 256, 0, stream>>>(d_in[13], WT2f, DFFd, Dd, flags);
    conv_kernel<<<(Dd * Dd + 255) / 256, 256, 0, stream>>>(d_in[7], Woc, Dd * Dd, flags);

    // batched small-parameter conversions + meanV zero (1 dispatch, 11 blocks)
    ConvBatch cb;
    const int srcIdx[10] = {2, 4, 6, 8, 9, 10, 12, 14, 15, 16};
    bf16* dsts[10] = {bqc, bkc, bvc, boc, g1c, b1c, b1fc, b2fc, g2c, b2c};
    for (int i = 0; i < 10; ++i) {
        cb.src[i] = d_in[srcIdx[i]]; cb.dst[i] = dsts[i];
        cb.n[i] = (i == 6) ? DFFd : Dd; cb.mode[i] = 0;
    }
    cb.src[10] = nullptr; cb.dst[10] = meanV; cb.n[10] = Bd * Hd * DHd; cb.mode[10] = 1;
    cb.src[11] = nullptr; cb.dst[11] = flags; cb.n[11] = 0; cb.mode[11] = 1;
    conv_batch_kernel<<<11, 256, 0, stream>>>(cb, flags);

    zero_kernel<<<(MLd + 255) / 256, 256, 0, stream>>>(rowCnt, MLd);
    idx_kernel<<<1, 128, 0, stream>>>(sraw, sidx);

    // merged QKV projection (Qb/Kb/Vb contiguous, WTq/k/v + bq/k/v contiguous)
    mfma_gemm<false, true><<<dim3(12, 256), 256, 0, stream>>>(xc, WTq, bqc, Qb, MLd, 3 * Dd, Dd);

    m_kernel<<<dim3(Ld / 128, Bd * Hd), 256, 0, stream>>>(Qb, Kb, sidx, Mv);
    topk_kernel<<<Bd * Hd, 256, 0, stream>>>(Mv, topIdx);
    rows_kernel<<<Bd * Hd, 128, 0, stream>>>(topIdx, rowCnt, rowEnt);
    meanv_kernel<<<dim3(Bd * Hd, Ld / 64), 256, 0, stream>>>(Vb, meanV);

    attn_kernel<<<dim3(Bd * Hd, KSd), 256, 0, stream>>>(Qb, Kb, Vb, topIdx, pOb, pM, pL);
    combine_kernel<<<Bd * Hd * 32, 256, 0, stream>>>(pOb, pM, pL, ctxTop);

    baseout_kernel<<<dim3(Bd, 4), 256, 0, stream>>>(meanV, Woc, boc, baseOut);

    ln1_kernel<<<MLd, 256, 0, stream>>>(xc, baseOut, rowCnt, rowEnt,
                                        ctxTop, meanV, Woc, g1c, b1c, x1b);

    // FFN: single full-width dispatches when workspace allows, else 2-chunk.
    if (h1full) {
        mfma_gemm<true , false><<<dim3(16, 256), 256, 0, stream>>>(x1b, WT1f, b1fc, h1full, MLd, DFFd, Dd);
        mfma_gemm<false, false><<<dim3(4, 256), 256, 0, stream>>>(h1full, WT2f, b2fc, ffnb, MLd, Dd, DFFd);
    } else {
        for (int c = 0; c < 2; ++c) {
            mfma_gemm<true , false><<<dim3(16, 128), 256, 0, stream>>>(
                x1b + (size_t)c * 16384 * 512, WT1f, b1fc, h1b, 16384, DFFd, Dd);
            mfma_gemm<false, false><<<dim3(4, 128), 256, 0, stream>>>(
                h1b, WT2f, b2fc, ffnb + (size_t)c * 16384 * 512, 16384, Dd, DFFd);
        }
    }

    ln2_kernel<<<MLd, 256, 0, stream>>>(x1b, ffnb, g2c, b2c, d_out, flags);
}